// Round 9
// baseline (3641.922 us; speedup 1.0000x reference)
//
#include <hip/hip_runtime.h>
#include <hip/hip_bf16.h>
#include <math.h>

// Problem constants
#define BB 4
#define SSEQ 8192
#define HIDDEN 768
#define NH 12
#define DDIM 64
#define KMB 16
#define NMB 512
#define NTOK ((size_t)BB * SSEQ)          // 32768
#define NELT (NTOK * HIDDEN)              // 25,165,824
#define WELT (768 * 768)

typedef short bf16x8 __attribute__((ext_vector_type(8)));
typedef float f32x4 __attribute__((ext_vector_type(4)));

union frag_u {
  bf16x8 v;
  unsigned u32[4];
  unsigned short u16[8];
};

__device__ __forceinline__ f32x4 mfma16(bf16x8 a, bf16x8 b, f32x4 c) {
  return __builtin_amdgcn_mfma_f32_16x16x32_bf16(a, b, c, 0, 0, 0);
}

// ---------------- helpers ----------------
__device__ __forceinline__ float wave_sum(float v) {
#pragma unroll
  for (int off = 32; off > 0; off >>= 1) v += __shfl_xor(v, off, 64);
  return v;
}

// DPP row_ror fold-add: v += rotate_within_row16(v, N). VALU-only cross-lane.
template <int CTRL>
__device__ __forceinline__ float dpp_add(float v) {
  union { float f; int i; } a, b;
  a.f = v;
  b.i = __builtin_amdgcn_update_dpp(0, a.i, CTRL, 0xF, 0xF, true);
  return v + b.f;
}
// full sum across each row of 16 lanes; every lane gets the total.
__device__ __forceinline__ float rsum16(float v) {
  v = dpp_add<0x121>(v);  // row_ror:1
  v = dpp_add<0x122>(v);  // row_ror:2
  v = dpp_add<0x124>(v);  // row_ror:4
  v = dpp_add<0x128>(v);  // row_ror:8
  return v;
}

// round-half-up bf16 (ties differ from RNE only on exact .5 ulp; negligible)
__device__ __forceinline__ unsigned short bf16hi(float x) {
  union { float f; unsigned u; } a; a.f = x;
  return (unsigned short)((a.u + 0x8000u) >> 16);
}
// pack two floats -> (bf16(f1)<<16)|bf16(f0) in 3 VALU ops via v_perm_b32
__device__ __forceinline__ unsigned pack_bf16(float f0, float f1) {
  union { float f; unsigned u; } a, b; a.f = f0; b.f = f1;
  return __builtin_amdgcn_perm(b.u + 0x8000u, a.u + 0x8000u, 0x07060302u);
}
__device__ __forceinline__ float bf2f(unsigned short s) {
  union { unsigned u; float f; } a; a.u = ((unsigned)s) << 16; return a.f;
}
__device__ __forceinline__ float gelu_tanh(float x) {
  float x3 = x * x * x;
  return 0.5f * x * (1.0f + tanhf(0.7978845608028654f * (x + 0.044715f * x3)));
}

__device__ __forceinline__ void glds16(const void* g, void* l) {
  __builtin_amdgcn_global_load_lds(
      (const __attribute__((address_space(1))) void*)g,
      (__attribute__((address_space(3))) void*)l, 16, 0, 0);
}

// ---------------- K0a: x (f32) -> xb (bf16) ----------------
__global__ __launch_bounds__(256) void cvt_x_kernel(
    const float* __restrict__ x, unsigned short* __restrict__ xb) {
  const size_t gid = (size_t)blockIdx.x * 256 + threadIdx.x;  // NELT/4
  const float4 v = *(const float4*)(x + gid * 4);
  uint2 r; r.x = pack_bf16(v.x, v.y); r.y = pack_bf16(v.z, v.w);
  *(uint2*)(xb + gid * 4) = r;
}

// ---------------- K0b: W (768x768 f32) -> W^T (768x768 bf16) ----------------
__global__ __launch_bounds__(256) void cvt_wT_kernel(
    const float* __restrict__ W, unsigned short* __restrict__ WT) {
  __shared__ float tile[32][33];
  const int tx = threadIdx.x & 31, ty = threadIdx.x >> 5;  // ty 0..7
  const int k0 = blockIdx.x * 32, n0 = blockIdx.y * 32;
#pragma unroll
  for (int r = 0; r < 4; ++r)
    tile[ty + 8 * r][tx] = W[(size_t)(k0 + ty + 8 * r) * 768 + n0 + tx];
  __syncthreads();
#pragma unroll
  for (int r = 0; r < 4; ++r)
    WT[(size_t)(n0 + ty + 8 * r) * 768 + k0 + tx] = bf16hi(tile[tx][ty + 8 * r]);
}

// ---------------- K1: MFMA GEMM  C[M,768] = A[M,768] @ BT[768,768]^T ------------
// m97 structure: 128x128 tile, BK=32, 256 thr (4 waves 2x2), global_load_lds w16.
// mode: 0 = bf16 out, 1 = bf16+gelu out, 2 = f32 out
__global__ __launch_bounds__(256) void gemm_mfma(
    const unsigned short* __restrict__ A, const unsigned short* __restrict__ BT,
    void* __restrict__ Cout, int mode) {
  __shared__ __align__(16) unsigned short Asl[128 * 32];
  __shared__ __align__(16) unsigned short Bsl[128 * 32];
  const int tid = threadIdx.x;
  const int wave = tid >> 6, lane = tid & 63;
  const int n16 = lane & 15, g16 = lane >> 4;
  const int wm = (wave >> 1) * 64, wn = (wave & 1) * 64;
  const int m0 = blockIdx.x * 128, n0 = blockIdx.y * 128;

  const int srow = tid >> 2;            // 0..63
  const int sseg = (tid & 3) * 8;       // k-element offset

  const unsigned short* aSrc0 = A + (size_t)(m0 + srow) * 768 + sseg;
  const unsigned short* aSrc1 = A + (size_t)(m0 + 64 + srow) * 768 + sseg;
  const unsigned short* bSrc0 = BT + (size_t)(n0 + srow) * 768 + sseg;
  const unsigned short* bSrc1 = BT + (size_t)(n0 + 64 + srow) * 768 + sseg;
  char* aDst0 = (char*)Asl + wave * 1024;
  char* aDst1 = (char*)Asl + 4096 + wave * 1024;
  char* bDst0 = (char*)Bsl + wave * 1024;
  char* bDst1 = (char*)Bsl + 4096 + wave * 1024;

  f32x4 acc[4][4];
#pragma unroll
  for (int i = 0; i < 4; ++i)
#pragma unroll
    for (int j = 0; j < 4; ++j) { acc[i][j][0] = 0.f; acc[i][j][1] = 0.f; acc[i][j][2] = 0.f; acc[i][j][3] = 0.f; }

  for (int k0 = 0; k0 < 768; k0 += 32) {
    __syncthreads();
    glds16(aSrc0 + k0, aDst0);
    glds16(aSrc1 + k0, aDst1);
    glds16(bSrc0 + k0, bDst0);
    glds16(bSrc1 + k0, bDst1);
    __syncthreads();
    bf16x8 af[4], bfr[4];
#pragma unroll
    for (int mf = 0; mf < 4; ++mf)
      af[mf] = *(const bf16x8*)(Asl + (wm + mf * 16 + n16) * 32 + g16 * 8);
#pragma unroll
    for (int nf = 0; nf < 4; ++nf)
      bfr[nf] = *(const bf16x8*)(Bsl + (wn + nf * 16 + n16) * 32 + g16 * 8);
#pragma unroll
    for (int mf = 0; mf < 4; ++mf)
#pragma unroll
      for (int nf = 0; nf < 4; ++nf)
        acc[mf][nf] = mfma16(af[mf], bfr[nf], acc[mf][nf]);
  }

  const int erow0 = m0 + wm + 4 * g16;
  const int ecol0 = n0 + wn + n16;
  if (mode == 2) {
    float* C = (float*)Cout;
#pragma unroll
    for (int mf = 0; mf < 4; ++mf)
#pragma unroll
      for (int nf = 0; nf < 4; ++nf)
#pragma unroll
        for (int r = 0; r < 4; ++r)
          C[(size_t)(erow0 + mf * 16 + r) * HIDDEN + ecol0 + nf * 16] = acc[mf][nf][r];
  } else if (mode == 1) {
    unsigned short* C = (unsigned short*)Cout;
#pragma unroll
    for (int mf = 0; mf < 4; ++mf)
#pragma unroll
      for (int nf = 0; nf < 4; ++nf)
#pragma unroll
        for (int r = 0; r < 4; ++r)
          C[(size_t)(erow0 + mf * 16 + r) * HIDDEN + ecol0 + nf * 16] = bf16hi(gelu_tanh(acc[mf][nf][r]));
  } else {
    unsigned short* C = (unsigned short*)Cout;
#pragma unroll
    for (int mf = 0; mf < 4; ++mf)
#pragma unroll
      for (int nf = 0; nf < 4; ++nf)
#pragma unroll
        for (int r = 0; r < 4; ++r)
          C[(size_t)(erow0 + mf * 16 + r) * HIDDEN + ecol0 + nf * 16] = bf16hi(acc[mf][nf][r]);
  }
}

// ---------------- K2: lrpre[b,h,s] = x[b,s,:]·lr_w[h,:] + lr_b[h] ----------------
__global__ __launch_bounds__(256) void lrpre_kernel(
    const float* __restrict__ x, const float* __restrict__ lrw,
    const float* __restrict__ lrb, float* __restrict__ lrpre) {
  const int g = threadIdx.x >> 6, l = threadIdx.x & 63;
  const int t = blockIdx.x * 4 + g;
  const float* xr = x + (size_t)t * HIDDEN;
  float xv[12];
#pragma unroll
  for (int j = 0; j < 12; ++j) xv[j] = xr[l + 64 * j];
  const int b = t >> 13, s = t & (SSEQ - 1);
  for (int h = 0; h < NH; ++h) {
    const float* wr = lrw + (size_t)h * HIDDEN;
    float a = 0.f;
#pragma unroll
    for (int j = 0; j < 12; ++j) a += xv[j] * wr[l + 64 * j];
    a = wave_sum(a);
    if (l == 0) lrpre[((size_t)b * NH + h) * SSEQ + s] = a + lrb[h];
  }
}

// ---------------- K3: conv (causal) + RoPE ----------------
__global__ __launch_bounds__(256) void convrope_kernel(
    const __hip_bfloat16* __restrict__ xqk,
    const float* __restrict__ cqw, const float* __restrict__ cqb,
    const float* __restrict__ ckw, const float* __restrict__ ckb,
    __hip_bfloat16* __restrict__ XQ, __hip_bfloat16* __restrict__ XK) {
  const size_t gid = (size_t)blockIdx.x * 256 + threadIdx.x;  // over NTOK*384
  const int p = (int)(gid % 384);
  const size_t bt = gid / 384;
  const int t = (int)(bt & (SSEQ - 1));
  const int c0 = 2 * p, c1 = c0 + 1;
  float q0 = cqb[c0], q1 = cqb[c1], k0v = ckb[c0], k1v = ckb[c1];
#pragma unroll
  for (int kk = 0; kk < 4; ++kk) {
    const int tp = t - 4 + kk;
    if (tp >= 0) {
      const size_t src = (bt - t + tp) * HIDDEN;
      const float x0 = __bfloat162float(xqk[src + c0]);
      const float x1 = __bfloat162float(xqk[src + c1]);
      q0  += cqw[kk * HIDDEN + c0] * x0;  q1  += cqw[kk * HIDDEN + c1] * x1;
      k0v += ckw[kk * HIDDEN + c0] * x0;  k1v += ckw[kk * HIDDEN + c1] * x1;
    }
  }
  const int f = p & 31;
  const float invf = expf(-(float)f * 0.28782313662425572f);  // ln(10000)/32
  const float ang = (float)t * invf;
  float sn, cs;
  sincosf(ang, &sn, &cs);
  const size_t o = bt * HIDDEN;
  XQ[o + c0] = __float2bfloat16(q0 * cs - q1 * sn);
  XQ[o + c1] = __float2bfloat16(q0 * sn + q1 * cs);
  XK[o + c0] = __float2bfloat16(k0v * cs - k1v * sn);
  XK[o + c1] = __float2bfloat16(k0v * sn + k1v * cs);
}

// ---------------- K4: MFMA TTT scan, 8 chains per block ----------------
// R9: __launch_bounds__(512, 1). Evidence: R7 (512,2) AND R8 (512) both gave
// VGPR_Count=128 + spills (scan 2970us vs R6's 1233 at 188 VGPR). HIP's 2nd
// arg is CUDA-style min BLOCKS per CU: 2 blocks x 8 waves = 4 waves/SIMD ->
// 128-VGPR cap; the default heuristic picks the same. (512,1) = 1 block/CU =
// 2 waves/SIMD -> 256-VGPR cap; natural 188 fits spill-free, and 2x188=376
// <= 512/SIMD keeps both chains resident for stall-fill.
// Per-chain math is bit-identical to the verified R6 kernel.
struct ScanBuf {
  uint2 qa[2][2], ka[2][2], va[2][2];
  float lr[4];
};

__global__ __launch_bounds__(512, 1) void scan_mfma_kernel(
    const __hip_bfloat16* __restrict__ XQg, const __hip_bfloat16* __restrict__ XKg,
    const __hip_bfloat16* __restrict__ XVg, const float* __restrict__ lrpre,
    const float* __restrict__ lti, const float* __restrict__ tnsg,
    const float* __restrict__ tnbg, const float* __restrict__ W1g,
    const float* __restrict__ b1g, __hip_bfloat16* __restrict__ Zg) {
  const int bh = blockIdx.x * 8 + (threadIdx.x >> 6);
  const int b = bh / NH, h = bh % NH;
  const int lane = threadIdx.x & 63;
  const int n = lane & 15, g16 = lane >> 4;
  const float inv64 = 1.0f / 64.0f;

  const unsigned short* XQb = (const unsigned short*)XQg + (size_t)b * SSEQ * HIDDEN + h * 64;
  const unsigned short* XKb = (const unsigned short*)XKg + (size_t)b * SSEQ * HIDDEN + h * 64;
  const unsigned short* XVb = (const unsigned short*)XVg + (size_t)b * SSEQ * HIDDEN + h * 64;
  unsigned short* Zb = (unsigned short*)Zg + (size_t)b * SSEQ * HIDDEN + h * 64;
  const float* lrp = lrpre + ((size_t)b * NH + h) * SSEQ;

  f32x4 W1acc[4][4];
#pragma unroll
  for (int db = 0; db < 4; ++db)
#pragma unroll
    for (int eb = 0; eb < 4; ++eb)
#pragma unroll
      for (int r = 0; r < 4; ++r)
        W1acc[db][eb][r] = W1g[(size_t)h * 4096 + (16 * db + 4 * g16 + r) * 64 + 16 * eb + n];

  float b1r[4], tnsr[4], tnbr[4];
#pragma unroll
  for (int eb = 0; eb < 4; ++eb) {
    const int e = h * 64 + 16 * eb + n;
    b1r[eb] = b1g[e]; tnsr[eb] = tnsg[e]; tnbr[eb] = tnbg[e];
  }
  const float tok_n = fmaxf(1.0f / (float)(n + 1) + lti[n], 0.0f);
  const float tok15 = __shfl(tok_n, 15, 64);

  // identity B-frags for the A-layout -> C-layout transpose MFMAs.
  // B[j][k] = 1 at k = 8*(j>>2)+(j&3) (id0) / +4 (id1), matching the A-frag's
  // k<->dim embedding so the composite is an exact dim-preserving transpose.
  frag_u id0, id1;
  {
    const unsigned short onebf = (g16 == (n >> 2)) ? (unsigned short)0x3F80 : (unsigned short)0;
    const unsigned vsh = ((unsigned)onebf) << (16 * (n & 1));
    const unsigned lo = ((n & 2) == 0) ? vsh : 0u;
    const unsigned hi = ((n & 2) != 0) ? vsh : 0u;
    id0.u32[0] = lo; id0.u32[1] = hi; id0.u32[2] = 0; id0.u32[3] = 0;
    id1.u32[0] = 0;  id1.u32[1] = 0;  id1.u32[2] = lo; id1.u32[3] = hi;
  }
  // all-ones A-frag: C[m][j] = sum_k B[j][k] for any sparse B embedding.
  frag_u onesA;
  onesA.u32[0] = 0x3F803F80u; onesA.u32[1] = 0x3F803F80u;
  onesA.u32[2] = 0x3F803F80u; onesA.u32[3] = 0x3F803F80u;

  int offA[2][2], offC[4][4];
#pragma unroll
  for (int c = 0; c < 2; ++c)
#pragma unroll
    for (int jg = 0; jg < 2; ++jg)
      offA[c][jg] = n * HIDDEN + 16 * (2 * c + jg) + 4 * g16;
#pragma unroll
  for (int blk = 0; blk < 4; ++blk)
#pragma unroll
    for (int r = 0; r < 4; ++r)
      offC[blk][r] = (4 * g16 + r) * HIDDEN + 16 * blk + n;

  auto load_mb = [&](ScanBuf& bf, int mb) {
    const size_t sb = (size_t)mb * (KMB * HIDDEN);
#pragma unroll
    for (int c = 0; c < 2; ++c)
#pragma unroll
      for (int jg = 0; jg < 2; ++jg) {
        bf.qa[c][jg] = *(const uint2*)(XQb + sb + offA[c][jg]);
        bf.ka[c][jg] = *(const uint2*)(XKb + sb + offA[c][jg]);
        bf.va[c][jg] = *(const uint2*)(XVb + sb + offA[c][jg]);
      }
    const float4 l4 = *(const float4*)(lrp + mb * KMB + 4 * g16);
    bf.lr[0] = l4.x; bf.lr[1] = l4.y; bf.lr[2] = l4.z; bf.lr[3] = l4.w;
  };

  auto compute_mb = [&](ScanBuf& bf, int mb) {
    const size_t sb = (size_t)mb * (KMB * HIDDEN);
    float etaj[4];
#pragma unroll
    for (int jj = 0; jj < 4; ++jj)
      etaj[jj] = 1.0f / (64.0f * (1.0f + __expf(-bf.lr[jj])));

    // W1 -> bf16 B-frags via packed perm cvt
    frag_u w1f[2][4];
#pragma unroll
    for (int c = 0; c < 2; ++c)
#pragma unroll
      for (int eb = 0; eb < 4; ++eb) {
        w1f[c][eb].u32[0] = pack_bf16(W1acc[2 * c][eb][0], W1acc[2 * c][eb][1]);
        w1f[c][eb].u32[1] = pack_bf16(W1acc[2 * c][eb][2], W1acc[2 * c][eb][3]);
        w1f[c][eb].u32[2] = pack_bf16(W1acc[2 * c + 1][eb][0], W1acc[2 * c + 1][eb][1]);
        w1f[c][eb].u32[3] = pack_bf16(W1acc[2 * c + 1][eb][2], W1acc[2 * c + 1][eb][3]);
      }
    frag_u kaf[2], qaf[2], vaf[2];
#pragma unroll
    for (int c = 0; c < 2; ++c) {
      kaf[c].u32[0] = bf.ka[c][0].x; kaf[c].u32[1] = bf.ka[c][0].y;
      kaf[c].u32[2] = bf.ka[c][1].x; kaf[c].u32[3] = bf.ka[c][1].y;
      qaf[c].u32[0] = bf.qa[c][0].x; qaf[c].u32[1] = bf.qa[c][0].y;
      qaf[c].u32[2] = bf.qa[c][1].x; qaf[c].u32[3] = bf.qa[c][1].y;
      vaf[c].u32[0] = bf.va[c][0].x; vaf[c].u32[1] = bf.va[c][0].y;
      vaf[c].u32[2] = bf.va[c][1].x; vaf[c].u32[3] = bf.va[c][1].y;
    }

    // A-layout -> C-layout transposes (exact).
    f32x4 z4; z4[0] = 0.f; z4[1] = 0.f; z4[2] = 0.f; z4[3] = 0.f;
    f32x4 qcf[4], kcf[4], vcf[4];
#pragma unroll
    for (int c = 0; c < 2; ++c) {
      qcf[2 * c]     = mfma16(qaf[c].v, id0.v, z4);
      qcf[2 * c + 1] = mfma16(qaf[c].v, id1.v, z4);
      kcf[2 * c]     = mfma16(kaf[c].v, id0.v, z4);
      kcf[2 * c + 1] = mfma16(kaf[c].v, id1.v, z4);
      vcf[2 * c]     = mfma16(vaf[c].v, id0.v, z4);
      vcf[2 * c + 1] = mfma16(vaf[c].v, id1.v, z4);
    }
    // ktf: K^T A-frags for the W1 update (exact repack of bf16 values).
    frag_u ktf[4];
#pragma unroll
    for (int mk = 0; mk < 4; ++mk) {
      ktf[mk].u32[0] = pack_bf16(kcf[mk][0], kcf[mk][1]);
      ktf[mk].u32[1] = pack_bf16(kcf[mk][2], kcf[mk][3]);
      ktf[mk].u32[2] = 0; ktf[mk].u32[3] = 0;
    }

    f32x4 zk[4], zq[4];
#pragma unroll
    for (int eb = 0; eb < 4; ++eb) {
      f32x4 init; init[0] = b1r[eb]; init[1] = b1r[eb]; init[2] = b1r[eb]; init[3] = b1r[eb];
      zk[eb] = init; zq[eb] = init;
    }
#pragma unroll
    for (int c = 0; c < 2; ++c)
#pragma unroll
      for (int eb = 0; eb < 4; ++eb) {
        zk[eb] = mfma16(kaf[c].v, w1f[c][eb].v, zk[eb]);
        zq[eb] = mfma16(qaf[c].v, w1f[c][eb].v, zq[eb]);
      }
    f32x4 st_; st_[0] = 0.f; st_[1] = 0.f; st_[2] = 0.f; st_[3] = 0.f;
    st_ = mfma16(kaf[0].v, qaf[0].v, st_);
    st_ = mfma16(kaf[1].v, qaf[1].v, st_);

    float s1[4], s2[4];
#pragma unroll
    for (int r = 0; r < 4; ++r) {
      s1[r] = zk[0][r] + zk[1][r] + zk[2][r] + zk[3][r];
      s2[r] = zk[0][r] * zk[0][r] + zk[1][r] * zk[1][r] + zk[2][r] * zk[2][r] + zk[3][r] * zk[3][r];
    }
#pragma unroll
    for (int r = 0; r < 4; ++r) { s1[r] = rsum16(s1[r]); s2[r] = rsum16(s2[r]); }
    float mr[4], rstd[4];
#pragma unroll
    for (int r = 0; r < 4; ++r) {
      mr[r] = s1[r] * inv64;
      rstd[r] = rsqrtf(s2[r] * inv64 - mr[r] * mr[r] + 1e-5f);
    }
    float xh[4][4], gx[4][4], t1[4] = {0.f, 0.f, 0.f, 0.f}, t2[4] = {0.f, 0.f, 0.f, 0.f};
#pragma unroll
    for (int eb = 0; eb < 4; ++eb)
#pragma unroll
      for (int r = 0; r < 4; ++r) {
        const float xh_ = (zk[eb][r] - mr[r]) * rstd[r];
        const float tg = vcf[eb][r] - kcf[eb][r];
        const float gx_ = (xh_ * tnsr[eb] + tnbr[eb] - tg) * tnsr[eb];
        xh[eb][r] = xh_; gx[eb][r] = gx_;
        t1[r] += gx_; t2[r] += gx_ * xh_;
      }
#pragma unroll
    for (int r = 0; r < 4; ++r) { t1[r] = rsum16(t1[r]); t2[r] = rsum16(t2[r]); }
    float g_[4][4];
#pragma unroll
    for (int eb = 0; eb < 4; ++eb)
#pragma unroll
      for (int r = 0; r < 4; ++r)
        g_[eb][r] = (gx[eb][r] - t1[r] * inv64 - xh[eb][r] * (t2[r] * inv64)) * rstd[r];

    frag_u gbf[4];
#pragma unroll
    for (int eb = 0; eb < 4; ++eb) {
      gbf[eb].u32[0] = pack_bf16(g_[eb][0], g_[eb][1]);
      gbf[eb].u32[1] = pack_bf16(g_[eb][2], g_[eb][3]);
      gbf[eb].u32[2] = 0; gbf[eb].u32[3] = 0;
    }
    frag_u coef;
    {
      float cf[4];
#pragma unroll
      for (int jj = 0; jj < 4; ++jj) {
        const int j = 4 * g16 + jj;
        cf[jj] = (j <= n) ? -tok_n * etaj[jj] * (1.0f + st_[jj]) : 0.0f;
      }
      coef.u32[0] = pack_bf16(cf[0], cf[1]);
      coef.u32[1] = pack_bf16(cf[2], cf[3]);
      coef.u32[2] = 0; coef.u32[3] = 0;
    }
    f32x4 zbv[4];
#pragma unroll
    for (int eb = 0; eb < 4; ++eb)
      zbv[eb] = mfma16(coef.v, gbf[eb].v, zq[eb]);

#pragma unroll
    for (int r = 0; r < 4; ++r) {
      s1[r] = zbv[0][r] + zbv[1][r] + zbv[2][r] + zbv[3][r];
      s2[r] = zbv[0][r] * zbv[0][r] + zbv[1][r] * zbv[1][r] + zbv[2][r] * zbv[2][r] + zbv[3][r] * zbv[3][r];
    }
#pragma unroll
    for (int r = 0; r < 4; ++r) { s1[r] = rsum16(s1[r]); s2[r] = rsum16(s2[r]); }
#pragma unroll
    for (int r = 0; r < 4; ++r) {
      mr[r] = s1[r] * inv64;
      rstd[r] = rsqrtf(s2[r] * inv64 - mr[r] * mr[r] + 1e-5f);
    }
#pragma unroll
    for (int eb = 0; eb < 4; ++eb)
#pragma unroll
      for (int r = 0; r < 4; ++r) {
        const float o = qcf[eb][r] + (zbv[eb][r] - mr[r]) * rstd[r] * tnsr[eb] + tnbr[eb];
        Zb[sb + offC[eb][r]] = bf16hi(o);
      }

    float lgv[4][4];
    frag_u lgf[4];
#pragma unroll
    for (int eb = 0; eb < 4; ++eb) {
#pragma unroll
      for (int jj = 0; jj < 4; ++jj) lgv[eb][jj] = -tok15 * etaj[jj] * g_[eb][jj];
      lgf[eb].u32[0] = pack_bf16(lgv[eb][0], lgv[eb][1]);
      lgf[eb].u32[1] = pack_bf16(lgv[eb][2], lgv[eb][3]);
      lgf[eb].u32[2] = 0; lgf[eb].u32[3] = 0;
    }
#pragma unroll
    for (int mk = 0; mk < 4; ++mk)
#pragma unroll
      for (int eb = 0; eb < 4; ++eb)
        W1acc[mk][eb] = mfma16(ktf[mk].v, lgf[eb].v, W1acc[mk][eb]);
    // b1 update: token-sum of lgf via ones-A MFMA (every output row identical).
#pragma unroll
    for (int eb = 0; eb < 4; ++eb) {
      f32x4 bs = mfma16(onesA.v, lgf[eb].v, z4);
      b1r[eb] += bs[0];
    }
  };

  ScanBuf A, B;
  load_mb(A, 0);
  for (int mb = 0; mb < NMB; mb += 2) {
    load_mb(B, mb + 1);
    compute_mb(A, mb);
    if (mb + 2 < NMB) load_mb(A, mb + 2);
    compute_mb(B, mb + 1);
  }
}

// ---------------- K5: per-token mean/rstd over 768 ----------------
__global__ __launch_bounds__(256) void stats_kernel(
    const __hip_bfloat16* __restrict__ Z, float* __restrict__ st) {
  const int g = threadIdx.x >> 6, l = threadIdx.x & 63;
  const int t = blockIdx.x * 4 + g;
  const __hip_bfloat16* zr = Z + (size_t)t * HIDDEN;
  float zv[12];
  float s_ = 0.f;
#pragma unroll
  for (int j = 0; j < 12; ++j) { zv[j] = __bfloat162float(zr[l + 64 * j]); s_ += zv[j]; }
  s_ = wave_sum(s_);
  const float m = s_ * (1.0f / 768.0f);
  float v_ = 0.f;
#pragma unroll
  for (int j = 0; j < 12; ++j) { const float d = zv[j] - m; v_ += d * d; }
  v_ = wave_sum(v_) * (1.0f / 768.0f);
  if (l == 0) { st[2 * t] = m; st[2 * t + 1] = rsqrtf(v_ + 1e-5f); }
}

// ---------------- K5b: aout = ((Z-mu)*rstd*pns + pnb)*gate  (bf16) ----------------
__global__ __launch_bounds__(256) void fuse_epi_kernel(
    const unsigned short* __restrict__ Zb, const unsigned short* __restrict__ gateb,
    const float* __restrict__ st, const float* __restrict__ pns,
    const float* __restrict__ pnb, unsigned short* __restrict__ aout) {
  const int gid = blockIdx.x * 256 + threadIdx.x;  // NELT/4 threads
  const int t = gid / 192;
  const int c = (gid - t * 192) * 4;
  const float mu = st[2 * t], rstd = st[2 * t + 1];
  const size_t base = (size_t)t * HIDDEN + c;
  const uint2 z2 = *(const uint2*)(Zb + base);
  const uint2 g2 = *(const uint2*)(gateb + base);
  const float4 p4 = *(const float4*)(pns + c);
  const float4 q4 = *(const float4*)(pnb + c);
  const float o0 = ((bf2f((unsigned short)(z2.x & 0xffff)) - mu) * rstd * p4.x + q4.x) * bf2f((unsigned short)(g2.x & 0xffff));
  const float o1 = ((bf2f((unsigned short)(z2.x >> 16)) - mu) * rstd * p4.y + q4.y) * bf2f((unsigned short)(g2.x >> 16));
  const float o2 = ((bf2f((unsigned short)(z2.y & 0xffff)) - mu) * rstd * p4.z + q4.z) * bf2f((unsigned short)(g2.y & 0xffff));
  const float o3 = ((bf2f((unsigned short)(z2.y >> 16)) - mu) * rstd * p4.w + q4.w) * bf2f((unsigned short)(g2.y >> 16));
  uint2 r; r.x = pack_bf16(o0, o1); r.y = pack_bf16(o2, o3);
  *(uint2*)(aout + base) = r;
}

// ---------------- launch ----------------
extern "C" void kernel_launch(void* const* d_in, const int* in_sizes, int n_in,
                              void* d_out, int out_size, void* d_ws, size_t ws_size,
                              hipStream_t stream) {
  const float* x   = (const float*)d_in[0];
  const float* wq  = (const float*)d_in[1];
  const float* wv  = (const float*)d_in[2];
  const float* wo  = (const float*)d_in[3];
  const float* wg  = (const float*)d_in[4];
  const float* cqw = (const float*)d_in[5];
  const float* cqb = (const float*)d_in[6];
  const float* ckw = (const float*)d_in[7];
  const float* ckb = (const float*)d_in[8];
  const float* lrw = (const float*)d_in[9];
  const float* lrb = (const float*)d_in[10];
  const float* lti = (const float*)d_in[11];
  const float* tns = (const float*)d_in[12];
  const float* tnb = (const float*)d_in[13];
  const float* pns = (const float*)d_in[14];
  const float* pnb = (const float*)d_in[15];
  const float* W1g = (const float*)d_in[16];
  const float* b1g = (const float*)d_in[17];
  float* out = (float*)d_out;

  // ws layout (bf16 slots, with aliasing): total ~309 MB
  unsigned short* zbuf = (unsigned short*)d_ws;    // slot0: xb (pre-scan) / zb (post-scan)
  unsigned short* xqk  = zbuf + NELT;              // slot1: xqk / aout
  unsigned short* xv   = xqk + NELT;
  unsigned short* gate = xv + NELT;
  unsigned short* xq   = gate + NELT;
  unsigned short* xk   = xq + NELT;
  unsigned short* wqT  = xk + NELT;
  unsigned short* wvT  = wqT + WELT;
  unsigned short* wgT  = wvT + WELT;
  unsigned short* woT  = wgT + WELT;
  float* lrpre = (float*)(woT + WELT);
  float* st    = lrpre + (size_t)BB * NH * SSEQ;
  unsigned short* xb   = zbuf;
  unsigned short* aout = xqk;

  const dim3 wtGrid(24, 24);
  cvt_x_kernel<<<(unsigned)(NELT / 4 / 256), 256, 0, stream>>>(x, xb);
  cvt_wT_kernel<<<wtGrid, 256, 0, stream>>>(wq, wqT);
  cvt_wT_kernel<<<wtGrid, 256, 0, stream>>>(wv, wvT);
  cvt_wT_kernel<<<wtGrid, 256, 0, stream>>>(wg, wgT);
  cvt_wT_kernel<<<wtGrid, 256, 0, stream>>>(wo, woT);

  const dim3 gemmGrid((unsigned)(NTOK / 128), HIDDEN / 128);
  gemm_mfma<<<gemmGrid, 256, 0, stream>>>(xb, wqT, (void*)xqk, 0);
  gemm_mfma<<<gemmGrid, 256, 0, stream>>>(xb, wvT, (void*)xv, 0);
  gemm_mfma<<<gemmGrid, 256, 0, stream>>>(xb, wgT, (void*)gate, 1);
  lrpre_kernel<<<(unsigned)(NTOK / 4), 256, 0, stream>>>(x, lrw, lrb, lrpre);
  convrope_kernel<<<(unsigned)(NTOK * 384 / 256), 256, 0, stream>>>(
      (const __hip_bfloat16*)xqk, cqw, cqb, ckw, ckb,
      (__hip_bfloat16*)xq, (__hip_bfloat16*)xk);
  scan_mfma_kernel<<<6, 512, 0, stream>>>(
      (const __hip_bfloat16*)xq, (const __hip_bfloat16*)xk,
      (const __hip_bfloat16*)xv, lrpre, lti, tns, tnb, W1g, b1g,
      (__hip_bfloat16*)zbuf);
  stats_kernel<<<(unsigned)(NTOK / 4), 256, 0, stream>>>((const __hip_bfloat16*)zbuf, st);
  fuse_epi_kernel<<<(unsigned)(NELT / 4 / 256), 256, 0, stream>>>(zbuf, gate, st, pns, pnb, aout);
  gemm_mfma<<<gemmGrid, 256, 0, stream>>>(aout, woT, (void*)out, 2);
}

// Round 10
// 1996.593 us; speedup vs baseline: 1.8241x; 1.8241x over previous
//
#include <hip/hip_runtime.h>
#include <hip/hip_bf16.h>
#include <math.h>

// Problem constants
#define BB 4
#define SSEQ 8192
#define HIDDEN 768
#define NH 12
#define DDIM 64
#define KMB 16
#define NMB 512
#define NTOK ((size_t)BB * SSEQ)          // 32768
#define NELT (NTOK * HIDDEN)              // 25,165,824
#define WELT (768 * 768)

typedef short bf16x8 __attribute__((ext_vector_type(8)));
typedef float f32x4 __attribute__((ext_vector_type(4)));

union frag_u {
  bf16x8 v;
  unsigned u32[4];
  unsigned short u16[8];
};

__device__ __forceinline__ f32x4 mfma16(bf16x8 a, bf16x8 b, f32x4 c) {
  return __builtin_amdgcn_mfma_f32_16x16x32_bf16(a, b, c, 0, 0, 0);
}

// ---------------- helpers ----------------
__device__ __forceinline__ float wave_sum(float v) {
#pragma unroll
  for (int off = 32; off > 0; off >>= 1) v += __shfl_xor(v, off, 64);
  return v;
}

// DPP row_ror fold-add: v += rotate_within_row16(v, N). VALU-only cross-lane.
template <int CTRL>
__device__ __forceinline__ float dpp_add(float v) {
  union { float f; int i; } a, b;
  a.f = v;
  b.i = __builtin_amdgcn_update_dpp(0, a.i, CTRL, 0xF, 0xF, true);
  return v + b.f;
}
// full sum across each row of 16 lanes; every lane gets the total.
__device__ __forceinline__ float rsum16(float v) {
  v = dpp_add<0x121>(v);  // row_ror:1
  v = dpp_add<0x122>(v);  // row_ror:2
  v = dpp_add<0x124>(v);  // row_ror:4
  v = dpp_add<0x128>(v);  // row_ror:8
  return v;
}

// round-half-up bf16 (ties differ from RNE only on exact .5 ulp; negligible)
__device__ __forceinline__ unsigned short bf16hi(float x) {
  union { float f; unsigned u; } a; a.f = x;
  return (unsigned short)((a.u + 0x8000u) >> 16);
}
// pack two floats -> (bf16(f1)<<16)|bf16(f0) in 3 VALU ops via v_perm_b32
__device__ __forceinline__ unsigned pack_bf16(float f0, float f1) {
  union { float f; unsigned u; } a, b; a.f = f0; b.f = f1;
  return __builtin_amdgcn_perm(b.u + 0x8000u, a.u + 0x8000u, 0x07060302u);
}
__device__ __forceinline__ float bf2f(unsigned short s) {
  union { unsigned u; float f; } a; a.u = ((unsigned)s) << 16; return a.f;
}
__device__ __forceinline__ float gelu_tanh(float x) {
  float x3 = x * x * x;
  return 0.5f * x * (1.0f + tanhf(0.7978845608028654f * (x + 0.044715f * x3)));
}

__device__ __forceinline__ void glds16(const void* g, void* l) {
  __builtin_amdgcn_global_load_lds(
      (const __attribute__((address_space(1))) void*)g,
      (__attribute__((address_space(3))) void*)l, 16, 0, 0);
}

// ---------------- K0a: x (f32) -> xb (bf16) ----------------
__global__ __launch_bounds__(256) void cvt_x_kernel(
    const float* __restrict__ x, unsigned short* __restrict__ xb) {
  const size_t gid = (size_t)blockIdx.x * 256 + threadIdx.x;  // NELT/4
  const float4 v = *(const float4*)(x + gid * 4);
  uint2 r; r.x = pack_bf16(v.x, v.y); r.y = pack_bf16(v.z, v.w);
  *(uint2*)(xb + gid * 4) = r;
}

// ---------------- K0b: W (768x768 f32) -> W^T (768x768 bf16) ----------------
__global__ __launch_bounds__(256) void cvt_wT_kernel(
    const float* __restrict__ W, unsigned short* __restrict__ WT) {
  __shared__ float tile[32][33];
  const int tx = threadIdx.x & 31, ty = threadIdx.x >> 5;  // ty 0..7
  const int k0 = blockIdx.x * 32, n0 = blockIdx.y * 32;
#pragma unroll
  for (int r = 0; r < 4; ++r)
    tile[ty + 8 * r][tx] = W[(size_t)(k0 + ty + 8 * r) * 768 + n0 + tx];
  __syncthreads();
#pragma unroll
  for (int r = 0; r < 4; ++r)
    WT[(size_t)(n0 + ty + 8 * r) * 768 + k0 + tx] = bf16hi(tile[tx][ty + 8 * r]);
}

// ---------------- K1: MFMA GEMM  C[M,768] = A[M,768] @ BT[768,768]^T ------------
// m97 structure: 128x128 tile, BK=32, 256 thr (4 waves 2x2), global_load_lds w16.
// mode: 0 = bf16 out, 1 = bf16+gelu out, 2 = f32 out
__global__ __launch_bounds__(256) void gemm_mfma(
    const unsigned short* __restrict__ A, const unsigned short* __restrict__ BT,
    void* __restrict__ Cout, int mode) {
  __shared__ __align__(16) unsigned short Asl[128 * 32];
  __shared__ __align__(16) unsigned short Bsl[128 * 32];
  const int tid = threadIdx.x;
  const int wave = tid >> 6, lane = tid & 63;
  const int n16 = lane & 15, g16 = lane >> 4;
  const int wm = (wave >> 1) * 64, wn = (wave & 1) * 64;
  const int m0 = blockIdx.x * 128, n0 = blockIdx.y * 128;

  const int srow = tid >> 2;            // 0..63
  const int sseg = (tid & 3) * 8;       // k-element offset

  const unsigned short* aSrc0 = A + (size_t)(m0 + srow) * 768 + sseg;
  const unsigned short* aSrc1 = A + (size_t)(m0 + 64 + srow) * 768 + sseg;
  const unsigned short* bSrc0 = BT + (size_t)(n0 + srow) * 768 + sseg;
  const unsigned short* bSrc1 = BT + (size_t)(n0 + 64 + srow) * 768 + sseg;
  char* aDst0 = (char*)Asl + wave * 1024;
  char* aDst1 = (char*)Asl + 4096 + wave * 1024;
  char* bDst0 = (char*)Bsl + wave * 1024;
  char* bDst1 = (char*)Bsl + 4096 + wave * 1024;

  f32x4 acc[4][4];
#pragma unroll
  for (int i = 0; i < 4; ++i)
#pragma unroll
    for (int j = 0; j < 4; ++j) { acc[i][j][0] = 0.f; acc[i][j][1] = 0.f; acc[i][j][2] = 0.f; acc[i][j][3] = 0.f; }

  for (int k0 = 0; k0 < 768; k0 += 32) {
    __syncthreads();
    glds16(aSrc0 + k0, aDst0);
    glds16(aSrc1 + k0, aDst1);
    glds16(bSrc0 + k0, bDst0);
    glds16(bSrc1 + k0, bDst1);
    __syncthreads();
    bf16x8 af[4], bfr[4];
#pragma unroll
    for (int mf = 0; mf < 4; ++mf)
      af[mf] = *(const bf16x8*)(Asl + (wm + mf * 16 + n16) * 32 + g16 * 8);
#pragma unroll
    for (int nf = 0; nf < 4; ++nf)
      bfr[nf] = *(const bf16x8*)(Bsl + (wn + nf * 16 + n16) * 32 + g16 * 8);
#pragma unroll
    for (int mf = 0; mf < 4; ++mf)
#pragma unroll
      for (int nf = 0; nf < 4; ++nf)
        acc[mf][nf] = mfma16(af[mf], bfr[nf], acc[mf][nf]);
  }

  const int erow0 = m0 + wm + 4 * g16;
  const int ecol0 = n0 + wn + n16;
  if (mode == 2) {
    float* C = (float*)Cout;
#pragma unroll
    for (int mf = 0; mf < 4; ++mf)
#pragma unroll
      for (int nf = 0; nf < 4; ++nf)
#pragma unroll
        for (int r = 0; r < 4; ++r)
          C[(size_t)(erow0 + mf * 16 + r) * HIDDEN + ecol0 + nf * 16] = acc[mf][nf][r];
  } else if (mode == 1) {
    unsigned short* C = (unsigned short*)Cout;
#pragma unroll
    for (int mf = 0; mf < 4; ++mf)
#pragma unroll
      for (int nf = 0; nf < 4; ++nf)
#pragma unroll
        for (int r = 0; r < 4; ++r)
          C[(size_t)(erow0 + mf * 16 + r) * HIDDEN + ecol0 + nf * 16] = bf16hi(gelu_tanh(acc[mf][nf][r]));
  } else {
    unsigned short* C = (unsigned short*)Cout;
#pragma unroll
    for (int mf = 0; mf < 4; ++mf)
#pragma unroll
      for (int nf = 0; nf < 4; ++nf)
#pragma unroll
        for (int r = 0; r < 4; ++r)
          C[(size_t)(erow0 + mf * 16 + r) * HIDDEN + ecol0 + nf * 16] = bf16hi(acc[mf][nf][r]);
  }
}

// ---------------- K2: lrpre[b,h,s] = x[b,s,:]·lr_w[h,:] + lr_b[h] ----------------
__global__ __launch_bounds__(256) void lrpre_kernel(
    const float* __restrict__ x, const float* __restrict__ lrw,
    const float* __restrict__ lrb, float* __restrict__ lrpre) {
  const int g = threadIdx.x >> 6, l = threadIdx.x & 63;
  const int t = blockIdx.x * 4 + g;
  const float* xr = x + (size_t)t * HIDDEN;
  float xv[12];
#pragma unroll
  for (int j = 0; j < 12; ++j) xv[j] = xr[l + 64 * j];
  const int b = t >> 13, s = t & (SSEQ - 1);
  for (int h = 0; h < NH; ++h) {
    const float* wr = lrw + (size_t)h * HIDDEN;
    float a = 0.f;
#pragma unroll
    for (int j = 0; j < 12; ++j) a += xv[j] * wr[l + 64 * j];
    a = wave_sum(a);
    if (l == 0) lrpre[((size_t)b * NH + h) * SSEQ + s] = a + lrb[h];
  }
}

// ---------------- K3: conv (causal) + RoPE ----------------
__global__ __launch_bounds__(256) void convrope_kernel(
    const __hip_bfloat16* __restrict__ xqk,
    const float* __restrict__ cqw, const float* __restrict__ cqb,
    const float* __restrict__ ckw, const float* __restrict__ ckb,
    __hip_bfloat16* __restrict__ XQ, __hip_bfloat16* __restrict__ XK) {
  const size_t gid = (size_t)blockIdx.x * 256 + threadIdx.x;  // over NTOK*384
  const int p = (int)(gid % 384);
  const size_t bt = gid / 384;
  const int t = (int)(bt & (SSEQ - 1));
  const int c0 = 2 * p, c1 = c0 + 1;
  float q0 = cqb[c0], q1 = cqb[c1], k0v = ckb[c0], k1v = ckb[c1];
#pragma unroll
  for (int kk = 0; kk < 4; ++kk) {
    const int tp = t - 4 + kk;
    if (tp >= 0) {
      const size_t src = (bt - t + tp) * HIDDEN;
      const float x0 = __bfloat162float(xqk[src + c0]);
      const float x1 = __bfloat162float(xqk[src + c1]);
      q0  += cqw[kk * HIDDEN + c0] * x0;  q1  += cqw[kk * HIDDEN + c1] * x1;
      k0v += ckw[kk * HIDDEN + c0] * x0;  k1v += ckw[kk * HIDDEN + c1] * x1;
    }
  }
  const int f = p & 31;
  const float invf = expf(-(float)f * 0.28782313662425572f);  // ln(10000)/32
  const float ang = (float)t * invf;
  float sn, cs;
  sincosf(ang, &sn, &cs);
  const size_t o = bt * HIDDEN;
  XQ[o + c0] = __float2bfloat16(q0 * cs - q1 * sn);
  XQ[o + c1] = __float2bfloat16(q0 * sn + q1 * cs);
  XK[o + c0] = __float2bfloat16(k0v * cs - k1v * sn);
  XK[o + c1] = __float2bfloat16(k0v * sn + k1v * cs);
}

// ---------------- K4: MFMA TTT scan, 2 waves per chain (eb-split) ----------------
// R10: R6-9 evidence says the scan wave is per-SIMD ISSUE-bound (~78% VALU +
// ~15% MFMA on the active SIMD), so co-residency cannot help (R7-9: 0.83x per
// SIMD). Instead split each chain across 2 waves by output-dim blocks: wave w
// owns eb {2w, 2w+1}. Per-wave VALU/MFMA roughly halves; the only coupling is
// 3 LN-stat reductions per mb, done as partial-rsum16 + one LDS exchange each
// (4 lanes write 8 floats, barrier, broadcast read + add). 48 blocks x 128 thr
// -> 96 active SIMDs. Reassociation of the stat sums is f32 noise (same class
// as the accepted rsum16 change). Runtime frag indices (qaf[w], kcfg[2w+e])
// are materialized via a wave-uniform branch (rule #20: no dynamic vec index).
struct ScanBuf {
  uint2 qa[2][2], ka[2][2], va[2][2];
  float lr[4];
};

__global__ __launch_bounds__(128) void scan_mfma_kernel(
    const __hip_bfloat16* __restrict__ XQg, const __hip_bfloat16* __restrict__ XKg,
    const __hip_bfloat16* __restrict__ XVg, const float* __restrict__ lrpre,
    const float* __restrict__ lti, const float* __restrict__ tnsg,
    const float* __restrict__ tnbg, const float* __restrict__ W1g,
    const float* __restrict__ b1g, __hip_bfloat16* __restrict__ Zg) {
  const int bh = blockIdx.x;
  const int b = bh / NH, h = bh % NH;
  const int w = threadIdx.x >> 6;      // wave 0/1: owns eb {2w, 2w+1}
  const int lane = threadIdx.x & 63;
  const int n = lane & 15, g16 = lane >> 4;
  const float inv64 = 1.0f / 64.0f;

  __shared__ __align__(16) float ex[3][2][4][8];  // [slot][wave][g16][s1x4|s2x4]

  const unsigned short* XQb = (const unsigned short*)XQg + (size_t)b * SSEQ * HIDDEN + h * 64;
  const unsigned short* XKb = (const unsigned short*)XKg + (size_t)b * SSEQ * HIDDEN + h * 64;
  const unsigned short* XVb = (const unsigned short*)XVg + (size_t)b * SSEQ * HIDDEN + h * 64;
  unsigned short* Zb = (unsigned short*)Zg + (size_t)b * SSEQ * HIDDEN + h * 64;
  const float* lrp = lrpre + ((size_t)b * NH + h) * SSEQ;

  // own half of W1: [input-dim block mk][own output block e]
  f32x4 W1acc[4][2];
#pragma unroll
  for (int mk = 0; mk < 4; ++mk)
#pragma unroll
    for (int e = 0; e < 2; ++e)
#pragma unroll
      for (int r = 0; r < 4; ++r)
        W1acc[mk][e][r] = W1g[(size_t)h * 4096 + (16 * mk + 4 * g16 + r) * 64 + 16 * (2 * w + e) + n];

  float b1r[2], tnsr[2], tnbr[2];
#pragma unroll
  for (int e = 0; e < 2; ++e) {
    const int eg = h * 64 + 16 * (2 * w + e) + n;
    b1r[e] = b1g[eg]; tnsr[e] = tnsg[eg]; tnbr[e] = tnbg[eg];
  }
  const float tok_n = fmaxf(1.0f / (float)(n + 1) + lti[n], 0.0f);
  const float tok15 = __shfl(tok_n, 15, 64);

  // identity B-frags for the A-layout -> C-layout transpose MFMAs (see R4/R5).
  frag_u id0, id1;
  {
    const unsigned short onebf = (g16 == (n >> 2)) ? (unsigned short)0x3F80 : (unsigned short)0;
    const unsigned vsh = ((unsigned)onebf) << (16 * (n & 1));
    const unsigned lo = ((n & 2) == 0) ? vsh : 0u;
    const unsigned hi = ((n & 2) != 0) ? vsh : 0u;
    id0.u32[0] = lo; id0.u32[1] = hi; id0.u32[2] = 0; id0.u32[3] = 0;
    id1.u32[0] = 0;  id1.u32[1] = 0;  id1.u32[2] = lo; id1.u32[3] = hi;
  }
  frag_u onesA;
  onesA.u32[0] = 0x3F803F80u; onesA.u32[1] = 0x3F803F80u;
  onesA.u32[2] = 0x3F803F80u; onesA.u32[3] = 0x3F803F80u;

  int offA[2][2], offCl[2][4];
#pragma unroll
  for (int c = 0; c < 2; ++c)
#pragma unroll
    for (int jg = 0; jg < 2; ++jg)
      offA[c][jg] = n * HIDDEN + 16 * (2 * c + jg) + 4 * g16;
#pragma unroll
  for (int e = 0; e < 2; ++e)
#pragma unroll
    for (int r = 0; r < 4; ++r)
      offCl[e][r] = (4 * g16 + r) * HIDDEN + 16 * (2 * w + e) + n;

  auto load_mb = [&](ScanBuf& bf, int mb) {
    const size_t sb = (size_t)mb * (KMB * HIDDEN);
#pragma unroll
    for (int c = 0; c < 2; ++c)
#pragma unroll
      for (int jg = 0; jg < 2; ++jg) {
        bf.qa[c][jg] = *(const uint2*)(XQb + sb + offA[c][jg]);
        bf.ka[c][jg] = *(const uint2*)(XKb + sb + offA[c][jg]);
        bf.va[c][jg] = *(const uint2*)(XVb + sb + offA[c][jg]);
      }
    const float4 l4 = *(const float4*)(lrp + mb * KMB + 4 * g16);
    bf.lr[0] = l4.x; bf.lr[1] = l4.y; bf.lr[2] = l4.z; bf.lr[3] = l4.w;
  };

  // cross-wave stat exchange: partial row-sums -> combined (both waves identical)
  auto xchg = [&](int slot, float s1[4], float s2[4]) {
    if (n == 0) {
      float4 a; a.x = s1[0]; a.y = s1[1]; a.z = s1[2]; a.w = s1[3];
      float4 bq; bq.x = s2[0]; bq.y = s2[1]; bq.z = s2[2]; bq.w = s2[3];
      *(float4*)&ex[slot][w][g16][0] = a;
      *(float4*)&ex[slot][w][g16][4] = bq;
    }
    __syncthreads();
#pragma unroll
    for (int r = 0; r < 4; ++r) {
      s1[r] += ex[slot][w ^ 1][g16][r];
      s2[r] += ex[slot][w ^ 1][g16][4 + r];
    }
  };

  auto compute_mb = [&](ScanBuf& bf, int mb) {
    const size_t sb = (size_t)mb * (KMB * HIDDEN);
    float etaj[4];
#pragma unroll
    for (int jj = 0; jj < 4; ++jj)
      etaj[jj] = 1.0f / (64.0f * (1.0f + __expf(-bf.lr[jj])));

    // own half of W1 -> bf16 B-frags
    frag_u w1f[2][2];
#pragma unroll
    for (int c = 0; c < 2; ++c)
#pragma unroll
      for (int e = 0; e < 2; ++e) {
        w1f[c][e].u32[0] = pack_bf16(W1acc[2 * c][e][0], W1acc[2 * c][e][1]);
        w1f[c][e].u32[1] = pack_bf16(W1acc[2 * c][e][2], W1acc[2 * c][e][3]);
        w1f[c][e].u32[2] = pack_bf16(W1acc[2 * c + 1][e][0], W1acc[2 * c + 1][e][1]);
        w1f[c][e].u32[3] = pack_bf16(W1acc[2 * c + 1][e][2], W1acc[2 * c + 1][e][3]);
      }
    frag_u kaf[2], qaf[2], vaf[2];
#pragma unroll
    for (int c = 0; c < 2; ++c) {
      kaf[c].u32[0] = bf.ka[c][0].x; kaf[c].u32[1] = bf.ka[c][0].y;
      kaf[c].u32[2] = bf.ka[c][1].x; kaf[c].u32[3] = bf.ka[c][1].y;
      qaf[c].u32[0] = bf.qa[c][0].x; qaf[c].u32[1] = bf.qa[c][0].y;
      qaf[c].u32[2] = bf.qa[c][1].x; qaf[c].u32[3] = bf.qa[c][1].y;
      vaf[c].u32[0] = bf.va[c][0].x; vaf[c].u32[1] = bf.va[c][0].y;
      vaf[c].u32[2] = bf.va[c][1].x; vaf[c].u32[3] = bf.va[c][1].y;
    }

    f32x4 z4; z4[0] = 0.f; z4[1] = 0.f; z4[2] = 0.f; z4[3] = 0.f;
    // K^T needed in full (W1 update uses all mk); Q/V transposes only own ebs.
    f32x4 kcfg[4];
#pragma unroll
    for (int c = 0; c < 2; ++c) {
      kcfg[2 * c]     = mfma16(kaf[c].v, id0.v, z4);
      kcfg[2 * c + 1] = mfma16(kaf[c].v, id1.v, z4);
    }
    // wave-uniform selection (avoid dynamic vector indexing -> scratch)
    frag_u qafw, vafw;
    f32x4 kown[2];
    if (w == 0) {
      qafw = qaf[0]; vafw = vaf[0]; kown[0] = kcfg[0]; kown[1] = kcfg[1];
    } else {
      qafw = qaf[1]; vafw = vaf[1]; kown[0] = kcfg[2]; kown[1] = kcfg[3];
    }
    f32x4 qcf[2], vcf[2];
    qcf[0] = mfma16(qafw.v, id0.v, z4); qcf[1] = mfma16(qafw.v, id1.v, z4);
    vcf[0] = mfma16(vafw.v, id0.v, z4); vcf[1] = mfma16(vafw.v, id1.v, z4);

    // ktf: K^T A-frags for the W1 update (exact repack of bf16 values).
    frag_u ktf[4];
#pragma unroll
    for (int mk = 0; mk < 4; ++mk) {
      ktf[mk].u32[0] = pack_bf16(kcfg[mk][0], kcfg[mk][1]);
      ktf[mk].u32[1] = pack_bf16(kcfg[mk][2], kcfg[mk][3]);
      ktf[mk].u32[2] = 0; ktf[mk].u32[3] = 0;
    }

    f32x4 zk[2], zq[2];
#pragma unroll
    for (int e = 0; e < 2; ++e) {
      f32x4 init; init[0] = b1r[e]; init[1] = b1r[e]; init[2] = b1r[e]; init[3] = b1r[e];
      zk[e] = init; zq[e] = init;
    }
#pragma unroll
    for (int c = 0; c < 2; ++c)
#pragma unroll
      for (int e = 0; e < 2; ++e) {
        zk[e] = mfma16(kaf[c].v, w1f[c][e].v, zk[e]);
        zq[e] = mfma16(qaf[c].v, w1f[c][e].v, zq[e]);
      }
    f32x4 st_; st_[0] = 0.f; st_[1] = 0.f; st_[2] = 0.f; st_[3] = 0.f;
    st_ = mfma16(kaf[0].v, qaf[0].v, st_);
    st_ = mfma16(kaf[1].v, qaf[1].v, st_);

    float s1[4], s2[4];
#pragma unroll
    for (int r = 0; r < 4; ++r) {
      s1[r] = zk[0][r] + zk[1][r];
      s2[r] = zk[0][r] * zk[0][r] + zk[1][r] * zk[1][r];
    }
#pragma unroll
    for (int r = 0; r < 4; ++r) { s1[r] = rsum16(s1[r]); s2[r] = rsum16(s2[r]); }
    xchg(0, s1, s2);
    float mr[4], rstd[4];
#pragma unroll
    for (int r = 0; r < 4; ++r) {
      mr[r] = s1[r] * inv64;
      rstd[r] = rsqrtf(s2[r] * inv64 - mr[r] * mr[r] + 1e-5f);
    }
    float xh[2][4], gx[2][4], t1[4] = {0.f, 0.f, 0.f, 0.f}, t2[4] = {0.f, 0.f, 0.f, 0.f};
#pragma unroll
    for (int e = 0; e < 2; ++e)
#pragma unroll
      for (int r = 0; r < 4; ++r) {
        const float xh_ = (zk[e][r] - mr[r]) * rstd[r];
        const float tg = vcf[e][r] - kown[e][r];
        const float gx_ = (xh_ * tnsr[e] + tnbr[e] - tg) * tnsr[e];
        xh[e][r] = xh_; gx[e][r] = gx_;
        t1[r] += gx_; t2[r] += gx_ * xh_;
      }
#pragma unroll
    for (int r = 0; r < 4; ++r) { t1[r] = rsum16(t1[r]); t2[r] = rsum16(t2[r]); }
    xchg(1, t1, t2);
    float g_[2][4];
#pragma unroll
    for (int e = 0; e < 2; ++e)
#pragma unroll
      for (int r = 0; r < 4; ++r)
        g_[e][r] = (gx[e][r] - t1[r] * inv64 - xh[e][r] * (t2[r] * inv64)) * rstd[r];

    frag_u gbf[2];
#pragma unroll
    for (int e = 0; e < 2; ++e) {
      gbf[e].u32[0] = pack_bf16(g_[e][0], g_[e][1]);
      gbf[e].u32[1] = pack_bf16(g_[e][2], g_[e][3]);
      gbf[e].u32[2] = 0; gbf[e].u32[3] = 0;
    }
    frag_u coef;
    {
      float cf[4];
#pragma unroll
      for (int jj = 0; jj < 4; ++jj) {
        const int j = 4 * g16 + jj;
        cf[jj] = (j <= n) ? -tok_n * etaj[jj] * (1.0f + st_[jj]) : 0.0f;
      }
      coef.u32[0] = pack_bf16(cf[0], cf[1]);
      coef.u32[1] = pack_bf16(cf[2], cf[3]);
      coef.u32[2] = 0; coef.u32[3] = 0;
    }
    f32x4 zbv[2];
#pragma unroll
    for (int e = 0; e < 2; ++e)
      zbv[e] = mfma16(coef.v, gbf[e].v, zq[e]);

#pragma unroll
    for (int r = 0; r < 4; ++r) {
      s1[r] = zbv[0][r] + zbv[1][r];
      s2[r] = zbv[0][r] * zbv[0][r] + zbv[1][r] * zbv[1][r];
    }
#pragma unroll
    for (int r = 0; r < 4; ++r) { s1[r] = rsum16(s1[r]); s2[r] = rsum16(s2[r]); }
    xchg(2, s1, s2);
#pragma unroll
    for (int r = 0; r < 4; ++r) {
      mr[r] = s1[r] * inv64;
      rstd[r] = rsqrtf(s2[r] * inv64 - mr[r] * mr[r] + 1e-5f);
    }
#pragma unroll
    for (int e = 0; e < 2; ++e)
#pragma unroll
      for (int r = 0; r < 4; ++r) {
        const float o = qcf[e][r] + (zbv[e][r] - mr[r]) * rstd[r] * tnsr[e] + tnbr[e];
        Zb[sb + offCl[e][r]] = bf16hi(o);
      }

    float lgv[2][4];
    frag_u lgf[2];
#pragma unroll
    for (int e = 0; e < 2; ++e) {
#pragma unroll
      for (int jj = 0; jj < 4; ++jj) lgv[e][jj] = -tok15 * etaj[jj] * g_[e][jj];
      lgf[e].u32[0] = pack_bf16(lgv[e][0], lgv[e][1]);
      lgf[e].u32[1] = pack_bf16(lgv[e][2], lgv[e][3]);
      lgf[e].u32[2] = 0; lgf[e].u32[3] = 0;
    }
#pragma unroll
    for (int mk = 0; mk < 4; ++mk)
#pragma unroll
      for (int e = 0; e < 2; ++e)
        W1acc[mk][e] = mfma16(ktf[mk].v, lgf[e].v, W1acc[mk][e]);
    // b1 update: token-sum of lgf via ones-A MFMA (every output row identical).
#pragma unroll
    for (int e = 0; e < 2; ++e) {
      f32x4 bs = mfma16(onesA.v, lgf[e].v, z4);
      b1r[e] += bs[0];
    }
  };

  ScanBuf A, B;
  load_mb(A, 0);
  for (int mb = 0; mb < NMB; mb += 2) {
    load_mb(B, mb + 1);
    compute_mb(A, mb);
    if (mb + 2 < NMB) load_mb(A, mb + 2);
    compute_mb(B, mb + 1);
  }
}

// ---------------- K5: per-token mean/rstd over 768 ----------------
__global__ __launch_bounds__(256) void stats_kernel(
    const __hip_bfloat16* __restrict__ Z, float* __restrict__ st) {
  const int g = threadIdx.x >> 6, l = threadIdx.x & 63;
  const int t = blockIdx.x * 4 + g;
  const __hip_bfloat16* zr = Z + (size_t)t * HIDDEN;
  float zv[12];
  float s_ = 0.f;
#pragma unroll
  for (int j = 0; j < 12; ++j) { zv[j] = __bfloat162float(zr[l + 64 * j]); s_ += zv[j]; }
  s_ = wave_sum(s_);
  const float m = s_ * (1.0f / 768.0f);
  float v_ = 0.f;
#pragma unroll
  for (int j = 0; j < 12; ++j) { const float d = zv[j] - m; v_ += d * d; }
  v_ = wave_sum(v_) * (1.0f / 768.0f);
  if (l == 0) { st[2 * t] = m; st[2 * t + 1] = rsqrtf(v_ + 1e-5f); }
}

// ---------------- K5b: aout = ((Z-mu)*rstd*pns + pnb)*gate  (bf16) ----------------
__global__ __launch_bounds__(256) void fuse_epi_kernel(
    const unsigned short* __restrict__ Zb, const unsigned short* __restrict__ gateb,
    const float* __restrict__ st, const float* __restrict__ pns,
    const float* __restrict__ pnb, unsigned short* __restrict__ aout) {
  const int gid = blockIdx.x * 256 + threadIdx.x;  // NELT/4 threads
  const int t = gid / 192;
  const int c = (gid - t * 192) * 4;
  const float mu = st[2 * t], rstd = st[2 * t + 1];
  const size_t base = (size_t)t * HIDDEN + c;
  const uint2 z2 = *(const uint2*)(Zb + base);
  const uint2 g2 = *(const uint2*)(gateb + base);
  const float4 p4 = *(const float4*)(pns + c);
  const float4 q4 = *(const float4*)(pnb + c);
  const float o0 = ((bf2f((unsigned short)(z2.x & 0xffff)) - mu) * rstd * p4.x + q4.x) * bf2f((unsigned short)(g2.x & 0xffff));
  const float o1 = ((bf2f((unsigned short)(z2.x >> 16)) - mu) * rstd * p4.y + q4.y) * bf2f((unsigned short)(g2.x >> 16));
  const float o2 = ((bf2f((unsigned short)(z2.y & 0xffff)) - mu) * rstd * p4.z + q4.z) * bf2f((unsigned short)(g2.y & 0xffff));
  const float o3 = ((bf2f((unsigned short)(z2.y >> 16)) - mu) * rstd * p4.w + q4.w) * bf2f((unsigned short)(g2.y >> 16));
  uint2 r; r.x = pack_bf16(o0, o1); r.y = pack_bf16(o2, o3);
  *(uint2*)(aout + base) = r;
}

// ---------------- launch ----------------
extern "C" void kernel_launch(void* const* d_in, const int* in_sizes, int n_in,
                              void* d_out, int out_size, void* d_ws, size_t ws_size,
                              hipStream_t stream) {
  const float* x   = (const float*)d_in[0];
  const float* wq  = (const float*)d_in[1];
  const float* wv  = (const float*)d_in[2];
  const float* wo  = (const float*)d_in[3];
  const float* wg  = (const float*)d_in[4];
  const float* cqw = (const float*)d_in[5];
  const float* cqb = (const float*)d_in[6];
  const float* ckw = (const float*)d_in[7];
  const float* ckb = (const float*)d_in[8];
  const float* lrw = (const float*)d_in[9];
  const float* lrb = (const float*)d_in[10];
  const float* lti = (const float*)d_in[11];
  const float* tns = (const float*)d_in[12];
  const float* tnb = (const float*)d_in[13];
  const float* pns = (const float*)d_in[14];
  const float* pnb = (const float*)d_in[15];
  const float* W1g = (const float*)d_in[16];
  const float* b1g = (const float*)d_in[17];
  float* out = (float*)d_out;

  // ws layout (bf16 slots, with aliasing): total ~309 MB
  unsigned short* zbuf = (unsigned short*)d_ws;    // slot0: xb (pre-scan) / zb (post-scan)
  unsigned short* xqk  = zbuf + NELT;              // slot1: xqk / aout
  unsigned short* xv   = xqk + NELT;
  unsigned short* gate = xv + NELT;
  unsigned short* xq   = gate + NELT;
  unsigned short* xk   = xq + NELT;
  unsigned short* wqT  = xk + NELT;
  unsigned short* wvT  = wqT + WELT;
  unsigned short* wgT  = wvT + WELT;
  unsigned short* woT  = wgT + WELT;
  float* lrpre = (float*)(woT + WELT);
  float* st    = lrpre + (size_t)BB * NH * SSEQ;
  unsigned short* xb   = zbuf;
  unsigned short* aout = xqk;

  const dim3 wtGrid(24, 24);
  cvt_x_kernel<<<(unsigned)(NELT / 4 / 256), 256, 0, stream>>>(x, xb);
  cvt_wT_kernel<<<wtGrid, 256, 0, stream>>>(wq, wqT);
  cvt_wT_kernel<<<wtGrid, 256, 0, stream>>>(wv, wvT);
  cvt_wT_kernel<<<wtGrid, 256, 0, stream>>>(wg, wgT);
  cvt_wT_kernel<<<wtGrid, 256, 0, stream>>>(wo, woT);

  const dim3 gemmGrid((unsigned)(NTOK / 128), HIDDEN / 128);
  gemm_mfma<<<gemmGrid, 256, 0, stream>>>(xb, wqT, (void*)xqk, 0);
  gemm_mfma<<<gemmGrid, 256, 0, stream>>>(xb, wvT, (void*)xv, 0);
  gemm_mfma<<<gemmGrid, 256, 0, stream>>>(xb, wgT, (void*)gate, 1);
  lrpre_kernel<<<(unsigned)(NTOK / 4), 256, 0, stream>>>(x, lrw, lrb, lrpre);
  convrope_kernel<<<(unsigned)(NTOK * 384 / 256), 256, 0, stream>>>(
      (const __hip_bfloat16*)xqk, cqw, cqb, ckw, ckb,
      (__hip_bfloat16*)xq, (__hip_bfloat16*)xk);
  scan_mfma_kernel<<<BB * NH, 128, 0, stream>>>(
      (const __hip_bfloat16*)xq, (const __hip_bfloat16*)xk,
      (const __hip_bfloat16*)xv, lrpre, lti, tns, tnb, W1g, b1g,
      (__hip_bfloat16*)zbuf);
  stats_kernel<<<(unsigned)(NTOK / 4), 256, 0, stream>>>((const __hip_bfloat16*)zbuf, st);
  fuse_epi_kernel<<<(unsigned)(NELT / 4 / 256), 256, 0, stream>>>(zbuf, gate, st, pns, pnb, aout);
  gemm_mfma<<<gemmGrid, 256, 0, stream>>>(aout, woT, (void*)out, 2);
}

// Round 11
// 1789.211 us; speedup vs baseline: 2.0355x; 1.1159x over previous
//
#include <hip/hip_runtime.h>
#include <hip/hip_bf16.h>
#include <math.h>

// Problem constants
#define BB 4
#define SSEQ 8192
#define HIDDEN 768
#define NH 12
#define DDIM 64
#define KMB 16
#define NMB 512
#define NTOK ((size_t)BB * SSEQ)          // 32768
#define NELT (NTOK * HIDDEN)              // 25,165,824
#define WELT (768 * 768)

typedef short bf16x8 __attribute__((ext_vector_type(8)));
typedef float f32x4 __attribute__((ext_vector_type(4)));

union frag_u {
  bf16x8 v;
  unsigned u32[4];
  unsigned short u16[8];
};

__device__ __forceinline__ f32x4 mfma16(bf16x8 a, bf16x8 b, f32x4 c) {
  return __builtin_amdgcn_mfma_f32_16x16x32_bf16(a, b, c, 0, 0, 0);
}

// ---------------- helpers ----------------
__device__ __forceinline__ float wave_sum(float v) {
#pragma unroll
  for (int off = 32; off > 0; off >>= 1) v += __shfl_xor(v, off, 64);
  return v;
}

// DPP row_ror fold-add: v += rotate_within_row16(v, N). VALU-only cross-lane.
template <int CTRL>
__device__ __forceinline__ float dpp_add(float v) {
  union { float f; int i; } a, b;
  a.f = v;
  b.i = __builtin_amdgcn_update_dpp(0, a.i, CTRL, 0xF, 0xF, true);
  return v + b.f;
}
// full sum across each row of 16 lanes; every lane gets the total.
__device__ __forceinline__ float rsum16(float v) {
  v = dpp_add<0x121>(v);  // row_ror:1
  v = dpp_add<0x122>(v);  // row_ror:2
  v = dpp_add<0x124>(v);  // row_ror:4
  v = dpp_add<0x128>(v);  // row_ror:8
  return v;
}

// round-half-up bf16 (ties differ from RNE only on exact .5 ulp; negligible)
__device__ __forceinline__ unsigned short bf16hi(float x) {
  union { float f; unsigned u; } a; a.f = x;
  return (unsigned short)((a.u + 0x8000u) >> 16);
}
// pack two floats -> (bf16(f1)<<16)|bf16(f0) in 3 VALU ops via v_perm_b32
__device__ __forceinline__ unsigned pack_bf16(float f0, float f1) {
  union { float f; unsigned u; } a, b; a.f = f0; b.f = f1;
  return __builtin_amdgcn_perm(b.u + 0x8000u, a.u + 0x8000u, 0x07060302u);
}
__device__ __forceinline__ float bf2f(unsigned short s) {
  union { unsigned u; float f; } a; a.u = ((unsigned)s) << 16; return a.f;
}
__device__ __forceinline__ float gelu_tanh(float x) {
  float x3 = x * x * x;
  return 0.5f * x * (1.0f + tanhf(0.7978845608028654f * (x + 0.044715f * x3)));
}

__device__ __forceinline__ void glds16(const void* g, void* l) {
  __builtin_amdgcn_global_load_lds(
      (const __attribute__((address_space(1))) void*)g,
      (__attribute__((address_space(3))) void*)l, 16, 0, 0);
}

// ---------------- K0a: x (f32) -> xb (bf16) ----------------
__global__ __launch_bounds__(256) void cvt_x_kernel(
    const float* __restrict__ x, unsigned short* __restrict__ xb) {
  const size_t gid = (size_t)blockIdx.x * 256 + threadIdx.x;  // NELT/4
  const float4 v = *(const float4*)(x + gid * 4);
  uint2 r; r.x = pack_bf16(v.x, v.y); r.y = pack_bf16(v.z, v.w);
  *(uint2*)(xb + gid * 4) = r;
}

// ---------------- K0b: W (768x768 f32) -> W^T (768x768 bf16) ----------------
__global__ __launch_bounds__(256) void cvt_wT_kernel(
    const float* __restrict__ W, unsigned short* __restrict__ WT) {
  __shared__ float tile[32][33];
  const int tx = threadIdx.x & 31, ty = threadIdx.x >> 5;  // ty 0..7
  const int k0 = blockIdx.x * 32, n0 = blockIdx.y * 32;
#pragma unroll
  for (int r = 0; r < 4; ++r)
    tile[ty + 8 * r][tx] = W[(size_t)(k0 + ty + 8 * r) * 768 + n0 + tx];
  __syncthreads();
#pragma unroll
  for (int r = 0; r < 4; ++r)
    WT[(size_t)(n0 + ty + 8 * r) * 768 + k0 + tx] = bf16hi(tile[tx][ty + 8 * r]);
}

// ---------------- K1: MFMA GEMM  C[M,768] = A[M,768] @ BT[768,768]^T ------------
// m97 structure: 128x128 tile, BK=32, 256 thr (4 waves 2x2), global_load_lds w16.
// mode: 0 = bf16 out, 1 = bf16+gelu out, 2 = f32 out
__global__ __launch_bounds__(256) void gemm_mfma(
    const unsigned short* __restrict__ A, const unsigned short* __restrict__ BT,
    void* __restrict__ Cout, int mode) {
  __shared__ __align__(16) unsigned short Asl[128 * 32];
  __shared__ __align__(16) unsigned short Bsl[128 * 32];
  const int tid = threadIdx.x;
  const int wave = tid >> 6, lane = tid & 63;
  const int n16 = lane & 15, g16 = lane >> 4;
  const int wm = (wave >> 1) * 64, wn = (wave & 1) * 64;
  const int m0 = blockIdx.x * 128, n0 = blockIdx.y * 128;

  const int srow = tid >> 2;            // 0..63
  const int sseg = (tid & 3) * 8;       // k-element offset

  const unsigned short* aSrc0 = A + (size_t)(m0 + srow) * 768 + sseg;
  const unsigned short* aSrc1 = A + (size_t)(m0 + 64 + srow) * 768 + sseg;
  const unsigned short* bSrc0 = BT + (size_t)(n0 + srow) * 768 + sseg;
  const unsigned short* bSrc1 = BT + (size_t)(n0 + 64 + srow) * 768 + sseg;
  char* aDst0 = (char*)Asl + wave * 1024;
  char* aDst1 = (char*)Asl + 4096 + wave * 1024;
  char* bDst0 = (char*)Bsl + wave * 1024;
  char* bDst1 = (char*)Bsl + 4096 + wave * 1024;

  f32x4 acc[4][4];
#pragma unroll
  for (int i = 0; i < 4; ++i)
#pragma unroll
    for (int j = 0; j < 4; ++j) { acc[i][j][0] = 0.f; acc[i][j][1] = 0.f; acc[i][j][2] = 0.f; acc[i][j][3] = 0.f; }

  for (int k0 = 0; k0 < 768; k0 += 32) {
    __syncthreads();
    glds16(aSrc0 + k0, aDst0);
    glds16(aSrc1 + k0, aDst1);
    glds16(bSrc0 + k0, bDst0);
    glds16(bSrc1 + k0, bDst1);
    __syncthreads();
    bf16x8 af[4], bfr[4];
#pragma unroll
    for (int mf = 0; mf < 4; ++mf)
      af[mf] = *(const bf16x8*)(Asl + (wm + mf * 16 + n16) * 32 + g16 * 8);
#pragma unroll
    for (int nf = 0; nf < 4; ++nf)
      bfr[nf] = *(const bf16x8*)(Bsl + (wn + nf * 16 + n16) * 32 + g16 * 8);
#pragma unroll
    for (int mf = 0; mf < 4; ++mf)
#pragma unroll
      for (int nf = 0; nf < 4; ++nf)
        acc[mf][nf] = mfma16(af[mf], bfr[nf], acc[mf][nf]);
  }

  const int erow0 = m0 + wm + 4 * g16;
  const int ecol0 = n0 + wn + n16;
  if (mode == 2) {
    float* C = (float*)Cout;
#pragma unroll
    for (int mf = 0; mf < 4; ++mf)
#pragma unroll
      for (int nf = 0; nf < 4; ++nf)
#pragma unroll
        for (int r = 0; r < 4; ++r)
          C[(size_t)(erow0 + mf * 16 + r) * HIDDEN + ecol0 + nf * 16] = acc[mf][nf][r];
  } else if (mode == 1) {
    unsigned short* C = (unsigned short*)Cout;
#pragma unroll
    for (int mf = 0; mf < 4; ++mf)
#pragma unroll
      for (int nf = 0; nf < 4; ++nf)
#pragma unroll
        for (int r = 0; r < 4; ++r)
          C[(size_t)(erow0 + mf * 16 + r) * HIDDEN + ecol0 + nf * 16] = bf16hi(gelu_tanh(acc[mf][nf][r]));
  } else {
    unsigned short* C = (unsigned short*)Cout;
#pragma unroll
    for (int mf = 0; mf < 4; ++mf)
#pragma unroll
      for (int nf = 0; nf < 4; ++nf)
#pragma unroll
        for (int r = 0; r < 4; ++r)
          C[(size_t)(erow0 + mf * 16 + r) * HIDDEN + ecol0 + nf * 16] = bf16hi(acc[mf][nf][r]);
  }
}

// ---------------- K2: lrpre[b,h,s] = x[b,s,:]·lr_w[h,:] + lr_b[h] ----------------
__global__ __launch_bounds__(256) void lrpre_kernel(
    const float* __restrict__ x, const float* __restrict__ lrw,
    const float* __restrict__ lrb, float* __restrict__ lrpre) {
  const int g = threadIdx.x >> 6, l = threadIdx.x & 63;
  const int t = blockIdx.x * 4 + g;
  const float* xr = x + (size_t)t * HIDDEN;
  float xv[12];
#pragma unroll
  for (int j = 0; j < 12; ++j) xv[j] = xr[l + 64 * j];
  const int b = t >> 13, s = t & (SSEQ - 1);
  for (int h = 0; h < NH; ++h) {
    const float* wr = lrw + (size_t)h * HIDDEN;
    float a = 0.f;
#pragma unroll
    for (int j = 0; j < 12; ++j) a += xv[j] * wr[l + 64 * j];
    a = wave_sum(a);
    if (l == 0) lrpre[((size_t)b * NH + h) * SSEQ + s] = a + lrb[h];
  }
}

// ---------------- K3: conv (causal) + RoPE ----------------
__global__ __launch_bounds__(256) void convrope_kernel(
    const __hip_bfloat16* __restrict__ xqk,
    const float* __restrict__ cqw, const float* __restrict__ cqb,
    const float* __restrict__ ckw, const float* __restrict__ ckb,
    __hip_bfloat16* __restrict__ XQ, __hip_bfloat16* __restrict__ XK) {
  const size_t gid = (size_t)blockIdx.x * 256 + threadIdx.x;  // over NTOK*384
  const int p = (int)(gid % 384);
  const size_t bt = gid / 384;
  const int t = (int)(bt & (SSEQ - 1));
  const int c0 = 2 * p, c1 = c0 + 1;
  float q0 = cqb[c0], q1 = cqb[c1], k0v = ckb[c0], k1v = ckb[c1];
#pragma unroll
  for (int kk = 0; kk < 4; ++kk) {
    const int tp = t - 4 + kk;
    if (tp >= 0) {
      const size_t src = (bt - t + tp) * HIDDEN;
      const float x0 = __bfloat162float(xqk[src + c0]);
      const float x1 = __bfloat162float(xqk[src + c1]);
      q0  += cqw[kk * HIDDEN + c0] * x0;  q1  += cqw[kk * HIDDEN + c1] * x1;
      k0v += ckw[kk * HIDDEN + c0] * x0;  k1v += ckw[kk * HIDDEN + c1] * x1;
    }
  }
  const int f = p & 31;
  const float invf = expf(-(float)f * 0.28782313662425572f);  // ln(10000)/32
  const float ang = (float)t * invf;
  float sn, cs;
  sincosf(ang, &sn, &cs);
  const size_t o = bt * HIDDEN;
  XQ[o + c0] = __float2bfloat16(q0 * cs - q1 * sn);
  XQ[o + c1] = __float2bfloat16(q0 * sn + q1 * cs);
  XK[o + c0] = __float2bfloat16(k0v * cs - k1v * sn);
  XK[o + c1] = __float2bfloat16(k0v * sn + k1v * cs);
}

// ---------------- K4: FUSED scan (blocks 0..47) + gate GEMM (blocks 48..1583) ----
// R11: the R6 single-wave scan occupies only 48 CUs for ~1.25ms while 208 CUs
// idle. The gate GEMM (A=xb, BT=wgT -> gate) has no dependency on the scan, so
// it rides along in the same dispatch on the remaining blocks. Scan waves run
// at s_setprio(1) so co-resident GEMM waves don't steal their issue slots
// (R7-9 lesson: the scan is issue-bound). Alias fix: scan output Z moved to
// the xqk slot (dead after convrope) so the GEMM can read xb concurrently.
// Scan math is bit-identical to the verified R6 kernel (1233us, absmax .03125).
struct ScanBuf {
  uint2 qa[2][2], ka[2][2], va[2][2];
  float lr[4];
};

__global__ __launch_bounds__(256) void fused_scan_gate(
    const __hip_bfloat16* __restrict__ XQg, const __hip_bfloat16* __restrict__ XKg,
    const __hip_bfloat16* __restrict__ XVg, const float* __restrict__ lrpre,
    const float* __restrict__ lti, const float* __restrict__ tnsg,
    const float* __restrict__ tnbg, const float* __restrict__ W1g,
    const float* __restrict__ b1g, __hip_bfloat16* __restrict__ Zg,
    const unsigned short* __restrict__ A, const unsigned short* __restrict__ BT,
    unsigned short* __restrict__ Cgate) {
  if (blockIdx.x >= 48) {
    // ---------------- gate GEMM body (m97 structure, gelu epilogue) ----------
    __shared__ __align__(16) unsigned short Asl[128 * 32];
    __shared__ __align__(16) unsigned short Bsl[128 * 32];
    const int bid = blockIdx.x - 48;          // 0..1535
    const int tid = threadIdx.x;
    const int wave = tid >> 6, lane = tid & 63;
    const int n16 = lane & 15, g16 = lane >> 4;
    const int wm = (wave >> 1) * 64, wn = (wave & 1) * 64;
    const int m0 = (bid & 255) * 128, n0 = (bid >> 8) * 128;

    const int srow = tid >> 2;
    const int sseg = (tid & 3) * 8;

    const unsigned short* aSrc0 = A + (size_t)(m0 + srow) * 768 + sseg;
    const unsigned short* aSrc1 = A + (size_t)(m0 + 64 + srow) * 768 + sseg;
    const unsigned short* bSrc0 = BT + (size_t)(n0 + srow) * 768 + sseg;
    const unsigned short* bSrc1 = BT + (size_t)(n0 + 64 + srow) * 768 + sseg;
    char* aDst0 = (char*)Asl + wave * 1024;
    char* aDst1 = (char*)Asl + 4096 + wave * 1024;
    char* bDst0 = (char*)Bsl + wave * 1024;
    char* bDst1 = (char*)Bsl + 4096 + wave * 1024;

    f32x4 acc[4][4];
#pragma unroll
    for (int i = 0; i < 4; ++i)
#pragma unroll
      for (int j = 0; j < 4; ++j) { acc[i][j][0] = 0.f; acc[i][j][1] = 0.f; acc[i][j][2] = 0.f; acc[i][j][3] = 0.f; }

    for (int k0 = 0; k0 < 768; k0 += 32) {
      __syncthreads();
      glds16(aSrc0 + k0, aDst0);
      glds16(aSrc1 + k0, aDst1);
      glds16(bSrc0 + k0, bDst0);
      glds16(bSrc1 + k0, bDst1);
      __syncthreads();
      bf16x8 af[4], bfr[4];
#pragma unroll
      for (int mf = 0; mf < 4; ++mf)
        af[mf] = *(const bf16x8*)(Asl + (wm + mf * 16 + n16) * 32 + g16 * 8);
#pragma unroll
      for (int nf = 0; nf < 4; ++nf)
        bfr[nf] = *(const bf16x8*)(Bsl + (wn + nf * 16 + n16) * 32 + g16 * 8);
#pragma unroll
      for (int mf = 0; mf < 4; ++mf)
#pragma unroll
        for (int nf = 0; nf < 4; ++nf)
          acc[mf][nf] = mfma16(af[mf], bfr[nf], acc[mf][nf]);
    }

    const int erow0 = m0 + wm + 4 * g16;
    const int ecol0 = n0 + wn + n16;
#pragma unroll
    for (int mf = 0; mf < 4; ++mf)
#pragma unroll
      for (int nf = 0; nf < 4; ++nf)
#pragma unroll
        for (int r = 0; r < 4; ++r)
          Cgate[(size_t)(erow0 + mf * 16 + r) * HIDDEN + ecol0 + nf * 16] = bf16hi(gelu_tanh(acc[mf][nf][r]));
    return;
  }

  // ---------------- scan body (R6, 1 wave; threads >= 64 exit) --------------
  if (threadIdx.x >= 64) return;
  __builtin_amdgcn_s_setprio(1);

  const int bh = blockIdx.x;
  const int b = bh / NH, h = bh % NH;
  const int lane = threadIdx.x;
  const int n = lane & 15, g16 = lane >> 4;
  const float inv64 = 1.0f / 64.0f;

  const unsigned short* XQb = (const unsigned short*)XQg + (size_t)b * SSEQ * HIDDEN + h * 64;
  const unsigned short* XKb = (const unsigned short*)XKg + (size_t)b * SSEQ * HIDDEN + h * 64;
  const unsigned short* XVb = (const unsigned short*)XVg + (size_t)b * SSEQ * HIDDEN + h * 64;
  unsigned short* Zb = (unsigned short*)Zg + (size_t)b * SSEQ * HIDDEN + h * 64;
  const float* lrp = lrpre + ((size_t)b * NH + h) * SSEQ;

  f32x4 W1acc[4][4];
#pragma unroll
  for (int db = 0; db < 4; ++db)
#pragma unroll
    for (int eb = 0; eb < 4; ++eb)
#pragma unroll
      for (int r = 0; r < 4; ++r)
        W1acc[db][eb][r] = W1g[(size_t)h * 4096 + (16 * db + 4 * g16 + r) * 64 + 16 * eb + n];

  float b1r[4], tnsr[4], tnbr[4];
#pragma unroll
  for (int eb = 0; eb < 4; ++eb) {
    const int e = h * 64 + 16 * eb + n;
    b1r[eb] = b1g[e]; tnsr[eb] = tnsg[e]; tnbr[eb] = tnbg[e];
  }
  const float tok_n = fmaxf(1.0f / (float)(n + 1) + lti[n], 0.0f);
  const float tok15 = __shfl(tok_n, 15, 64);

  // identity B-frags for the A-layout -> C-layout transpose MFMAs (see R4/R5).
  frag_u id0, id1;
  {
    const unsigned short onebf = (g16 == (n >> 2)) ? (unsigned short)0x3F80 : (unsigned short)0;
    const unsigned vsh = ((unsigned)onebf) << (16 * (n & 1));
    const unsigned lo = ((n & 2) == 0) ? vsh : 0u;
    const unsigned hi = ((n & 2) != 0) ? vsh : 0u;
    id0.u32[0] = lo; id0.u32[1] = hi; id0.u32[2] = 0; id0.u32[3] = 0;
    id1.u32[0] = 0;  id1.u32[1] = 0;  id1.u32[2] = lo; id1.u32[3] = hi;
  }
  frag_u onesA;
  onesA.u32[0] = 0x3F803F80u; onesA.u32[1] = 0x3F803F80u;
  onesA.u32[2] = 0x3F803F80u; onesA.u32[3] = 0x3F803F80u;

  int offA[2][2], offC[4][4];
#pragma unroll
  for (int c = 0; c < 2; ++c)
#pragma unroll
    for (int jg = 0; jg < 2; ++jg)
      offA[c][jg] = n * HIDDEN + 16 * (2 * c + jg) + 4 * g16;
#pragma unroll
  for (int blk = 0; blk < 4; ++blk)
#pragma unroll
    for (int r = 0; r < 4; ++r)
      offC[blk][r] = (4 * g16 + r) * HIDDEN + 16 * blk + n;

  auto load_mb = [&](ScanBuf& bf, int mb) {
    const size_t sb = (size_t)mb * (KMB * HIDDEN);
#pragma unroll
    for (int c = 0; c < 2; ++c)
#pragma unroll
      for (int jg = 0; jg < 2; ++jg) {
        bf.qa[c][jg] = *(const uint2*)(XQb + sb + offA[c][jg]);
        bf.ka[c][jg] = *(const uint2*)(XKb + sb + offA[c][jg]);
        bf.va[c][jg] = *(const uint2*)(XVb + sb + offA[c][jg]);
      }
    const float4 l4 = *(const float4*)(lrp + mb * KMB + 4 * g16);
    bf.lr[0] = l4.x; bf.lr[1] = l4.y; bf.lr[2] = l4.z; bf.lr[3] = l4.w;
  };

  auto compute_mb = [&](ScanBuf& bf, int mb) {
    const size_t sb = (size_t)mb * (KMB * HIDDEN);
    float etaj[4];
#pragma unroll
    for (int jj = 0; jj < 4; ++jj)
      etaj[jj] = 1.0f / (64.0f * (1.0f + __expf(-bf.lr[jj])));

    // W1 -> bf16 B-frags via packed perm cvt
    frag_u w1f[2][4];
#pragma unroll
    for (int c = 0; c < 2; ++c)
#pragma unroll
      for (int eb = 0; eb < 4; ++eb) {
        w1f[c][eb].u32[0] = pack_bf16(W1acc[2 * c][eb][0], W1acc[2 * c][eb][1]);
        w1f[c][eb].u32[1] = pack_bf16(W1acc[2 * c][eb][2], W1acc[2 * c][eb][3]);
        w1f[c][eb].u32[2] = pack_bf16(W1acc[2 * c + 1][eb][0], W1acc[2 * c + 1][eb][1]);
        w1f[c][eb].u32[3] = pack_bf16(W1acc[2 * c + 1][eb][2], W1acc[2 * c + 1][eb][3]);
      }
    frag_u kaf[2], qaf[2], vaf[2];
#pragma unroll
    for (int c = 0; c < 2; ++c) {
      kaf[c].u32[0] = bf.ka[c][0].x; kaf[c].u32[1] = bf.ka[c][0].y;
      kaf[c].u32[2] = bf.ka[c][1].x; kaf[c].u32[3] = bf.ka[c][1].y;
      qaf[c].u32[0] = bf.qa[c][0].x; qaf[c].u32[1] = bf.qa[c][0].y;
      qaf[c].u32[2] = bf.qa[c][1].x; qaf[c].u32[3] = bf.qa[c][1].y;
      vaf[c].u32[0] = bf.va[c][0].x; vaf[c].u32[1] = bf.va[c][0].y;
      vaf[c].u32[2] = bf.va[c][1].x; vaf[c].u32[3] = bf.va[c][1].y;
    }

    // A-layout -> C-layout transposes (exact).
    f32x4 z4; z4[0] = 0.f; z4[1] = 0.f; z4[2] = 0.f; z4[3] = 0.f;
    f32x4 qcf[4], kcf[4], vcf[4];
#pragma unroll
    for (int c = 0; c < 2; ++c) {
      qcf[2 * c]     = mfma16(qaf[c].v, id0.v, z4);
      qcf[2 * c + 1] = mfma16(qaf[c].v, id1.v, z4);
      kcf[2 * c]     = mfma16(kaf[c].v, id0.v, z4);
      kcf[2 * c + 1] = mfma16(kaf[c].v, id1.v, z4);
      vcf[2 * c]     = mfma16(vaf[c].v, id0.v, z4);
      vcf[2 * c + 1] = mfma16(vaf[c].v, id1.v, z4);
    }
    // ktf: K^T A-frags for the W1 update (exact repack of bf16 values).
    frag_u ktf[4];
#pragma unroll
    for (int mk = 0; mk < 4; ++mk) {
      ktf[mk].u32[0] = pack_bf16(kcf[mk][0], kcf[mk][1]);
      ktf[mk].u32[1] = pack_bf16(kcf[mk][2], kcf[mk][3]);
      ktf[mk].u32[2] = 0; ktf[mk].u32[3] = 0;
    }

    f32x4 zk[4], zq[4];
#pragma unroll
    for (int eb = 0; eb < 4; ++eb) {
      f32x4 init; init[0] = b1r[eb]; init[1] = b1r[eb]; init[2] = b1r[eb]; init[3] = b1r[eb];
      zk[eb] = init; zq[eb] = init;
    }
#pragma unroll
    for (int c = 0; c < 2; ++c)
#pragma unroll
      for (int eb = 0; eb < 4; ++eb) {
        zk[eb] = mfma16(kaf[c].v, w1f[c][eb].v, zk[eb]);
        zq[eb] = mfma16(qaf[c].v, w1f[c][eb].v, zq[eb]);
      }
    f32x4 st_; st_[0] = 0.f; st_[1] = 0.f; st_[2] = 0.f; st_[3] = 0.f;
    st_ = mfma16(kaf[0].v, qaf[0].v, st_);
    st_ = mfma16(kaf[1].v, qaf[1].v, st_);

    float s1[4], s2[4];
#pragma unroll
    for (int r = 0; r < 4; ++r) {
      s1[r] = zk[0][r] + zk[1][r] + zk[2][r] + zk[3][r];
      s2[r] = zk[0][r] * zk[0][r] + zk[1][r] * zk[1][r] + zk[2][r] * zk[2][r] + zk[3][r] * zk[3][r];
    }
#pragma unroll
    for (int r = 0; r < 4; ++r) { s1[r] = rsum16(s1[r]); s2[r] = rsum16(s2[r]); }
    float mr[4], rstd[4];
#pragma unroll
    for (int r = 0; r < 4; ++r) {
      mr[r] = s1[r] * inv64;
      rstd[r] = rsqrtf(s2[r] * inv64 - mr[r] * mr[r] + 1e-5f);
    }
    float xh[4][4], gx[4][4], t1[4] = {0.f, 0.f, 0.f, 0.f}, t2[4] = {0.f, 0.f, 0.f, 0.f};
#pragma unroll
    for (int eb = 0; eb < 4; ++eb)
#pragma unroll
      for (int r = 0; r < 4; ++r) {
        const float xh_ = (zk[eb][r] - mr[r]) * rstd[r];
        const float tg = vcf[eb][r] - kcf[eb][r];
        const float gx_ = (xh_ * tnsr[eb] + tnbr[eb] - tg) * tnsr[eb];
        xh[eb][r] = xh_; gx[eb][r] = gx_;
        t1[r] += gx_; t2[r] += gx_ * xh_;
      }
#pragma unroll
    for (int r = 0; r < 4; ++r) { t1[r] = rsum16(t1[r]); t2[r] = rsum16(t2[r]); }
    float g_[4][4];
#pragma unroll
    for (int eb = 0; eb < 4; ++eb)
#pragma unroll
      for (int r = 0; r < 4; ++r)
        g_[eb][r] = (gx[eb][r] - t1[r] * inv64 - xh[eb][r] * (t2[r] * inv64)) * rstd[r];

    frag_u gbf[4];
#pragma unroll
    for (int eb = 0; eb < 4; ++eb) {
      gbf[eb].u32[0] = pack_bf16(g_[eb][0], g_[eb][1]);
      gbf[eb].u32[1] = pack_bf16(g_[eb][2], g_[eb][3]);
      gbf[eb].u32[2] = 0; gbf[eb].u32[3] = 0;
    }
    frag_u coef;
    {
      float cf[4];
#pragma unroll
      for (int jj = 0; jj < 4; ++jj) {
        const int j = 4 * g16 + jj;
        cf[jj] = (j <= n) ? -tok_n * etaj[jj] * (1.0f + st_[jj]) : 0.0f;
      }
      coef.u32[0] = pack_bf16(cf[0], cf[1]);
      coef.u32[1] = pack_bf16(cf[2], cf[3]);
      coef.u32[2] = 0; coef.u32[3] = 0;
    }
    f32x4 zbv[4];
#pragma unroll
    for (int eb = 0; eb < 4; ++eb)
      zbv[eb] = mfma16(coef.v, gbf[eb].v, zq[eb]);

#pragma unroll
    for (int r = 0; r < 4; ++r) {
      s1[r] = zbv[0][r] + zbv[1][r] + zbv[2][r] + zbv[3][r];
      s2[r] = zbv[0][r] * zbv[0][r] + zbv[1][r] * zbv[1][r] + zbv[2][r] * zbv[2][r] + zbv[3][r] * zbv[3][r];
    }
#pragma unroll
    for (int r = 0; r < 4; ++r) { s1[r] = rsum16(s1[r]); s2[r] = rsum16(s2[r]); }
#pragma unroll
    for (int r = 0; r < 4; ++r) {
      mr[r] = s1[r] * inv64;
      rstd[r] = rsqrtf(s2[r] * inv64 - mr[r] * mr[r] + 1e-5f);
    }
#pragma unroll
    for (int eb = 0; eb < 4; ++eb)
#pragma unroll
      for (int r = 0; r < 4; ++r) {
        const float o = qcf[eb][r] + (zbv[eb][r] - mr[r]) * rstd[r] * tnsr[eb] + tnbr[eb];
        Zb[sb + offC[eb][r]] = bf16hi(o);
      }

    float lgv[4][4];
    frag_u lgf[4];
#pragma unroll
    for (int eb = 0; eb < 4; ++eb) {
#pragma unroll
      for (int jj = 0; jj < 4; ++jj) lgv[eb][jj] = -tok15 * etaj[jj] * g_[eb][jj];
      lgf[eb].u32[0] = pack_bf16(lgv[eb][0], lgv[eb][1]);
      lgf[eb].u32[1] = pack_bf16(lgv[eb][2], lgv[eb][3]);
      lgf[eb].u32[2] = 0; lgf[eb].u32[3] = 0;
    }
#pragma unroll
    for (int mk = 0; mk < 4; ++mk)
#pragma unroll
      for (int eb = 0; eb < 4; ++eb)
        W1acc[mk][eb] = mfma16(ktf[mk].v, lgf[eb].v, W1acc[mk][eb]);
    // b1 update: token-sum of lgf via ones-A MFMA (every output row identical).
#pragma unroll
    for (int eb = 0; eb < 4; ++eb) {
      f32x4 bs = mfma16(onesA.v, lgf[eb].v, z4);
      b1r[eb] += bs[0];
    }
  };

  ScanBuf Abuf, Bbuf;
  load_mb(Abuf, 0);
  for (int mb = 0; mb < NMB; mb += 2) {
    load_mb(Bbuf, mb + 1);
    compute_mb(Abuf, mb);
    if (mb + 2 < NMB) load_mb(Abuf, mb + 2);
    compute_mb(Bbuf, mb + 1);
  }
  __builtin_amdgcn_s_setprio(0);
}

// ---------------- K5: per-token mean/rstd over 768 ----------------
__global__ __launch_bounds__(256) void stats_kernel(
    const __hip_bfloat16* __restrict__ Z, float* __restrict__ st) {
  const int g = threadIdx.x >> 6, l = threadIdx.x & 63;
  const int t = blockIdx.x * 4 + g;
  const __hip_bfloat16* zr = Z + (size_t)t * HIDDEN;
  float zv[12];
  float s_ = 0.f;
#pragma unroll
  for (int j = 0; j < 12; ++j) { zv[j] = __bfloat162float(zr[l + 64 * j]); s_ += zv[j]; }
  s_ = wave_sum(s_);
  const float m = s_ * (1.0f / 768.0f);
  float v_ = 0.f;
#pragma unroll
  for (int j = 0; j < 12; ++j) { const float d = zv[j] - m; v_ += d * d; }
  v_ = wave_sum(v_) * (1.0f / 768.0f);
  if (l == 0) { st[2 * t] = m; st[2 * t + 1] = rsqrtf(v_ + 1e-5f); }
}

// ---------------- K5b: aout = ((Z-mu)*rstd*pns + pnb)*gate  (bf16) ----------------
__global__ __launch_bounds__(256) void fuse_epi_kernel(
    const unsigned short* __restrict__ Zb, const unsigned short* __restrict__ gateb,
    const float* __restrict__ st, const float* __restrict__ pns,
    const float* __restrict__ pnb, unsigned short* __restrict__ aout) {
  const int gid = blockIdx.x * 256 + threadIdx.x;  // NELT/4 threads
  const int t = gid / 192;
  const int c = (gid - t * 192) * 4;
  const float mu = st[2 * t], rstd = st[2 * t + 1];
  const size_t base = (size_t)t * HIDDEN + c;
  const uint2 z2 = *(const uint2*)(Zb + base);
  const uint2 g2 = *(const uint2*)(gateb + base);
  const float4 p4 = *(const float4*)(pns + c);
  const float4 q4 = *(const float4*)(pnb + c);
  const float o0 = ((bf2f((unsigned short)(z2.x & 0xffff)) - mu) * rstd * p4.x + q4.x) * bf2f((unsigned short)(g2.x & 0xffff));
  const float o1 = ((bf2f((unsigned short)(z2.x >> 16)) - mu) * rstd * p4.y + q4.y) * bf2f((unsigned short)(g2.x >> 16));
  const float o2 = ((bf2f((unsigned short)(z2.y & 0xffff)) - mu) * rstd * p4.z + q4.z) * bf2f((unsigned short)(g2.y & 0xffff));
  const float o3 = ((bf2f((unsigned short)(z2.y >> 16)) - mu) * rstd * p4.w + q4.w) * bf2f((unsigned short)(g2.y >> 16));
  uint2 r; r.x = pack_bf16(o0, o1); r.y = pack_bf16(o2, o3);
  *(uint2*)(aout + base) = r;
}

// ---------------- launch ----------------
extern "C" void kernel_launch(void* const* d_in, const int* in_sizes, int n_in,
                              void* d_out, int out_size, void* d_ws, size_t ws_size,
                              hipStream_t stream) {
  const float* x   = (const float*)d_in[0];
  const float* wq  = (const float*)d_in[1];
  const float* wv  = (const float*)d_in[2];
  const float* wo  = (const float*)d_in[3];
  const float* wg  = (const float*)d_in[4];
  const float* cqw = (const float*)d_in[5];
  const float* cqb = (const float*)d_in[6];
  const float* ckw = (const float*)d_in[7];
  const float* ckb = (const float*)d_in[8];
  const float* lrw = (const float*)d_in[9];
  const float* lrb = (const float*)d_in[10];
  const float* lti = (const float*)d_in[11];
  const float* tns = (const float*)d_in[12];
  const float* tnb = (const float*)d_in[13];
  const float* pns = (const float*)d_in[14];
  const float* pnb = (const float*)d_in[15];
  const float* W1g = (const float*)d_in[16];
  const float* b1g = (const float*)d_in[17];
  float* out = (float*)d_out;

  // ws layout (bf16 slots, with aliasing): total ~309 MB
  // slot0: xb (input to GEMMs, incl. the in-fused gate GEMM) / aout (post-stats)
  // slot1: xqk (conv input, dead after convrope) / Z (scan output)
  unsigned short* zbuf = (unsigned short*)d_ws;
  unsigned short* xqk  = zbuf + NELT;
  unsigned short* xv   = xqk + NELT;
  unsigned short* gate = xv + NELT;
  unsigned short* xq   = gate + NELT;
  unsigned short* xk   = xq + NELT;
  unsigned short* wqT  = xk + NELT;
  unsigned short* wvT  = wqT + WELT;
  unsigned short* wgT  = wvT + WELT;
  unsigned short* woT  = wgT + WELT;
  float* lrpre = (float*)(woT + WELT);
  float* st    = lrpre + (size_t)BB * NH * SSEQ;
  unsigned short* xb   = zbuf;   // slot0 pre-scan
  unsigned short* zOut = xqk;    // slot1 post-convrope
  unsigned short* aout = zbuf;   // slot0 post-scan

  const dim3 wtGrid(24, 24);
  cvt_x_kernel<<<(unsigned)(NELT / 4 / 256), 256, 0, stream>>>(x, xb);
  cvt_wT_kernel<<<wtGrid, 256, 0, stream>>>(wq, wqT);
  cvt_wT_kernel<<<wtGrid, 256, 0, stream>>>(wv, wvT);
  cvt_wT_kernel<<<wtGrid, 256, 0, stream>>>(wg, wgT);
  cvt_wT_kernel<<<wtGrid, 256, 0, stream>>>(wo, woT);

  const dim3 gemmGrid((unsigned)(NTOK / 128), HIDDEN / 128);
  gemm_mfma<<<gemmGrid, 256, 0, stream>>>(xb, wqT, (void*)xqk, 0);
  gemm_mfma<<<gemmGrid, 256, 0, stream>>>(xb, wvT, (void*)xv, 0);
  lrpre_kernel<<<(unsigned)(NTOK / 4), 256, 0, stream>>>(x, lrw, lrb, lrpre);
  convrope_kernel<<<(unsigned)(NTOK * 384 / 256), 256, 0, stream>>>(
      (const __hip_bfloat16*)xqk, cqw, cqb, ckw, ckb,
      (__hip_bfloat16*)xq, (__hip_bfloat16*)xk);
  fused_scan_gate<<<48 + 1536, 256, 0, stream>>>(
      (const __hip_bfloat16*)xq, (const __hip_bfloat16*)xk,
      (const __hip_bfloat16*)xv, lrpre, lti, tns, tnb, W1g, b1g,
      (__hip_bfloat16*)zOut, xb, wgT, gate);
  stats_kernel<<<(unsigned)(NTOK / 4), 256, 0, stream>>>((const __hip_bfloat16*)zOut, st);
  fuse_epi_kernel<<<(unsigned)(NELT / 4 / 256), 256, 0, stream>>>(zOut, gate, st, pns, pnb, aout);
  gemm_mfma<<<gemmGrid, 256, 0, stream>>>(aout, woT, (void*)out, 2);
}

// Round 13
// 1780.126 us; speedup vs baseline: 2.0459x; 1.0051x over previous
//
#include <hip/hip_runtime.h>
#include <hip/hip_bf16.h>
#include <math.h>

// Problem constants
#define BB 4
#define SSEQ 8192
#define HIDDEN 768
#define NH 12
#define DDIM 64
#define KMB 16
#define NMB 512
#define NTOK ((size_t)BB * SSEQ)          // 32768
#define NELT (NTOK * HIDDEN)              // 25,165,824
#define WELT (768 * 768)

typedef short bf16x8 __attribute__((ext_vector_type(8)));
typedef float f32x4 __attribute__((ext_vector_type(4)));

union frag_u {
  bf16x8 v;
  unsigned u32[4];
  unsigned short u16[8];
};

__device__ __forceinline__ f32x4 mfma16(bf16x8 a, bf16x8 b, f32x4 c) {
  return __builtin_amdgcn_mfma_f32_16x16x32_bf16(a, b, c, 0, 0, 0);
}

// ---------------- helpers ----------------
__device__ __forceinline__ float wave_sum(float v) {
#pragma unroll
  for (int off = 32; off > 0; off >>= 1) v += __shfl_xor(v, off, 64);
  return v;
}

// DPP row_ror fold-add: v += rotate_within_row16(v, N). VALU-only cross-lane.
template <int CTRL>
__device__ __forceinline__ float dpp_add(float v) {
  union { float f; int i; } a, b;
  a.f = v;
  b.i = __builtin_amdgcn_update_dpp(0, a.i, CTRL, 0xF, 0xF, true);
  return v + b.f;
}
// full sum across each row of 16 lanes; every lane gets the total.
__device__ __forceinline__ float rsum16(float v) {
  v = dpp_add<0x121>(v);  // row_ror:1
  v = dpp_add<0x122>(v);  // row_ror:2
  v = dpp_add<0x124>(v);  // row_ror:4
  v = dpp_add<0x128>(v);  // row_ror:8
  return v;
}

// round-half-up bf16 (ties differ from RNE only on exact .5 ulp; negligible)
__device__ __forceinline__ unsigned short bf16hi(float x) {
  union { float f; unsigned u; } a; a.f = x;
  return (unsigned short)((a.u + 0x8000u) >> 16);
}
// pack two floats -> (bf16(f1)<<16)|bf16(f0) in 3 VALU ops via v_perm_b32
__device__ __forceinline__ unsigned pack_bf16(float f0, float f1) {
  union { float f; unsigned u; } a, b; a.f = f0; b.f = f1;
  return __builtin_amdgcn_perm(b.u + 0x8000u, a.u + 0x8000u, 0x07060302u);
}
__device__ __forceinline__ float bf2f(unsigned short s) {
  union { unsigned u; float f; } a; a.u = ((unsigned)s) << 16; return a.f;
}
__device__ __forceinline__ float gelu_tanh(float x) {
  float x3 = x * x * x;
  return 0.5f * x * (1.0f + tanhf(0.7978845608028654f * (x + 0.044715f * x3)));
}

__device__ __forceinline__ void glds16(const void* g, void* l) {
  __builtin_amdgcn_global_load_lds(
      (const __attribute__((address_space(1))) void*)g,
      (__attribute__((address_space(3))) void*)l, 16, 0, 0);
}

// ---------------- K0a: x (f32) -> xb (bf16) ----------------
__global__ __launch_bounds__(256) void cvt_x_kernel(
    const float* __restrict__ x, unsigned short* __restrict__ xb) {
  const size_t gid = (size_t)blockIdx.x * 256 + threadIdx.x;  // NELT/4
  const float4 v = *(const float4*)(x + gid * 4);
  uint2 r; r.x = pack_bf16(v.x, v.y); r.y = pack_bf16(v.z, v.w);
  *(uint2*)(xb + gid * 4) = r;
}

// ---------------- K0b: W (768x768 f32) -> W^T (768x768 bf16) ----------------
__global__ __launch_bounds__(256) void cvt_wT_kernel(
    const float* __restrict__ W, unsigned short* __restrict__ WT) {
  __shared__ float tile[32][33];
  const int tx = threadIdx.x & 31, ty = threadIdx.x >> 5;  // ty 0..7
  const int k0 = blockIdx.x * 32, n0 = blockIdx.y * 32;
#pragma unroll
  for (int r = 0; r < 4; ++r)
    tile[ty + 8 * r][tx] = W[(size_t)(k0 + ty + 8 * r) * 768 + n0 + tx];
  __syncthreads();
#pragma unroll
  for (int r = 0; r < 4; ++r)
    WT[(size_t)(n0 + ty + 8 * r) * 768 + k0 + tx] = bf16hi(tile[tx][ty + 8 * r]);
}

// ---------------- K1: MFMA GEMM  C[M,768] = A[M,768] @ BT[768,768]^T ------------
// m97 structure: 128x128 tile, BK=32, 256 thr (4 waves 2x2), global_load_lds w16.
// mode: 0 = bf16 out, 1 = bf16+gelu out, 2 = f32 out
__global__ __launch_bounds__(256) void gemm_mfma(
    const unsigned short* __restrict__ A, const unsigned short* __restrict__ BT,
    void* __restrict__ Cout, int mode) {
  __shared__ __align__(16) unsigned short Asl[128 * 32];
  __shared__ __align__(16) unsigned short Bsl[128 * 32];
  const int tid = threadIdx.x;
  const int wave = tid >> 6, lane = tid & 63;
  const int n16 = lane & 15, g16 = lane >> 4;
  const int wm = (wave >> 1) * 64, wn = (wave & 1) * 64;
  const int m0 = blockIdx.x * 128, n0 = blockIdx.y * 128;

  const int srow = tid >> 2;            // 0..63
  const int sseg = (tid & 3) * 8;       // k-element offset

  const unsigned short* aSrc0 = A + (size_t)(m0 + srow) * 768 + sseg;
  const unsigned short* aSrc1 = A + (size_t)(m0 + 64 + srow) * 768 + sseg;
  const unsigned short* bSrc0 = BT + (size_t)(n0 + srow) * 768 + sseg;
  const unsigned short* bSrc1 = BT + (size_t)(n0 + 64 + srow) * 768 + sseg;
  char* aDst0 = (char*)Asl + wave * 1024;
  char* aDst1 = (char*)Asl + 4096 + wave * 1024;
  char* bDst0 = (char*)Bsl + wave * 1024;
  char* bDst1 = (char*)Bsl + 4096 + wave * 1024;

  f32x4 acc[4][4];
#pragma unroll
  for (int i = 0; i < 4; ++i)
#pragma unroll
    for (int j = 0; j < 4; ++j) { acc[i][j][0] = 0.f; acc[i][j][1] = 0.f; acc[i][j][2] = 0.f; acc[i][j][3] = 0.f; }

  for (int k0 = 0; k0 < 768; k0 += 32) {
    __syncthreads();
    glds16(aSrc0 + k0, aDst0);
    glds16(aSrc1 + k0, aDst1);
    glds16(bSrc0 + k0, bDst0);
    glds16(bSrc1 + k0, bDst1);
    __syncthreads();
    bf16x8 af[4], bfr[4];
#pragma unroll
    for (int mf = 0; mf < 4; ++mf)
      af[mf] = *(const bf16x8*)(Asl + (wm + mf * 16 + n16) * 32 + g16 * 8);
#pragma unroll
    for (int nf = 0; nf < 4; ++nf)
      bfr[nf] = *(const bf16x8*)(Bsl + (wn + nf * 16 + n16) * 32 + g16 * 8);
#pragma unroll
    for (int mf = 0; mf < 4; ++mf)
#pragma unroll
      for (int nf = 0; nf < 4; ++nf)
        acc[mf][nf] = mfma16(af[mf], bfr[nf], acc[mf][nf]);
  }

  const int erow0 = m0 + wm + 4 * g16;
  const int ecol0 = n0 + wn + n16;
  if (mode == 2) {
    float* C = (float*)Cout;
#pragma unroll
    for (int mf = 0; mf < 4; ++mf)
#pragma unroll
      for (int nf = 0; nf < 4; ++nf)
#pragma unroll
        for (int r = 0; r < 4; ++r)
          C[(size_t)(erow0 + mf * 16 + r) * HIDDEN + ecol0 + nf * 16] = acc[mf][nf][r];
  } else if (mode == 1) {
    unsigned short* C = (unsigned short*)Cout;
#pragma unroll
    for (int mf = 0; mf < 4; ++mf)
#pragma unroll
      for (int nf = 0; nf < 4; ++nf)
#pragma unroll
        for (int r = 0; r < 4; ++r)
          C[(size_t)(erow0 + mf * 16 + r) * HIDDEN + ecol0 + nf * 16] = bf16hi(gelu_tanh(acc[mf][nf][r]));
  } else {
    unsigned short* C = (unsigned short*)Cout;
#pragma unroll
    for (int mf = 0; mf < 4; ++mf)
#pragma unroll
      for (int nf = 0; nf < 4; ++nf)
#pragma unroll
        for (int r = 0; r < 4; ++r)
          C[(size_t)(erow0 + mf * 16 + r) * HIDDEN + ecol0 + nf * 16] = bf16hi(acc[mf][nf][r]);
  }
}

// ---------------- K2: lrpre[b,h,s] = x[b,s,:]·lr_w[h,:] + lr_b[h] ----------------
__global__ __launch_bounds__(256) void lrpre_kernel(
    const float* __restrict__ x, const float* __restrict__ lrw,
    const float* __restrict__ lrb, float* __restrict__ lrpre) {
  const int g = threadIdx.x >> 6, l = threadIdx.x & 63;
  const int t = blockIdx.x * 4 + g;
  const float* xr = x + (size_t)t * HIDDEN;
  float xv[12];
#pragma unroll
  for (int j = 0; j < 12; ++j) xv[j] = xr[l + 64 * j];
  const int b = t >> 13, s = t & (SSEQ - 1);
  for (int h = 0; h < NH; ++h) {
    const float* wr = lrw + (size_t)h * HIDDEN;
    float a = 0.f;
#pragma unroll
    for (int j = 0; j < 12; ++j) a += xv[j] * wr[l + 64 * j];
    a = wave_sum(a);
    if (l == 0) lrpre[((size_t)b * NH + h) * SSEQ + s] = a + lrb[h];
  }
}

// ---------------- K3: conv (causal) + RoPE ----------------
__global__ __launch_bounds__(256) void convrope_kernel(
    const __hip_bfloat16* __restrict__ xqk,
    const float* __restrict__ cqw, const float* __restrict__ cqb,
    const float* __restrict__ ckw, const float* __restrict__ ckb,
    __hip_bfloat16* __restrict__ XQ, __hip_bfloat16* __restrict__ XK) {
  const size_t gid = (size_t)blockIdx.x * 256 + threadIdx.x;  // over NTOK*384
  const int p = (int)(gid % 384);
  const size_t bt = gid / 384;
  const int t = (int)(bt & (SSEQ - 1));
  const int c0 = 2 * p, c1 = c0 + 1;
  float q0 = cqb[c0], q1 = cqb[c1], k0v = ckb[c0], k1v = ckb[c1];
#pragma unroll
  for (int kk = 0; kk < 4; ++kk) {
    const int tp = t - 4 + kk;
    if (tp >= 0) {
      const size_t src = (bt - t + tp) * HIDDEN;
      const float x0 = __bfloat162float(xqk[src + c0]);
      const float x1 = __bfloat162float(xqk[src + c1]);
      q0  += cqw[kk * HIDDEN + c0] * x0;  q1  += cqw[kk * HIDDEN + c1] * x1;
      k0v += ckw[kk * HIDDEN + c0] * x0;  k1v += ckw[kk * HIDDEN + c1] * x1;
    }
  }
  const int f = p & 31;
  const float invf = expf(-(float)f * 0.28782313662425572f);  // ln(10000)/32
  const float ang = (float)t * invf;
  float sn, cs;
  sincosf(ang, &sn, &cs);
  const size_t o = bt * HIDDEN;
  XQ[o + c0] = __float2bfloat16(q0 * cs - q1 * sn);
  XQ[o + c1] = __float2bfloat16(q0 * sn + q1 * cs);
  XK[o + c0] = __float2bfloat16(k0v * cs - k1v * sn);
  XK[o + c1] = __float2bfloat16(k0v * sn + k1v * cs);
}

// ---------------- K4: FUSED scan (blocks 0..47) + gate GEMM (blocks 48..1583) ----
// R11 structure (verified: 1212us fused, total 1789us, absmax .03125).
// R13: reverted R12's v_cvt_pk_bf16_f32 experiment (produced NaN through the
// 512-step W1 recurrence -> packs are back to the verified add+add+perm form).
// Kept: stats+epi fusion (pure reorganization, separate kernel below).
struct ScanBuf {
  uint2 qa[2][2], ka[2][2], va[2][2];
  float lr[4];
};

__global__ __launch_bounds__(256) void fused_scan_gate(
    const __hip_bfloat16* __restrict__ XQg, const __hip_bfloat16* __restrict__ XKg,
    const __hip_bfloat16* __restrict__ XVg, const float* __restrict__ lrpre,
    const float* __restrict__ lti, const float* __restrict__ tnsg,
    const float* __restrict__ tnbg, const float* __restrict__ W1g,
    const float* __restrict__ b1g, __hip_bfloat16* __restrict__ Zg,
    const unsigned short* __restrict__ A, const unsigned short* __restrict__ BT,
    unsigned short* __restrict__ Cgate) {
  if (blockIdx.x >= 48) {
    // ---------------- gate GEMM body (m97 structure, gelu epilogue) ----------
    __shared__ __align__(16) unsigned short Asl[128 * 32];
    __shared__ __align__(16) unsigned short Bsl[128 * 32];
    const int bid = blockIdx.x - 48;          // 0..1535
    const int tid = threadIdx.x;
    const int wave = tid >> 6, lane = tid & 63;
    const int n16 = lane & 15, g16 = lane >> 4;
    const int wm = (wave >> 1) * 64, wn = (wave & 1) * 64;
    const int m0 = (bid & 255) * 128, n0 = (bid >> 8) * 128;

    const int srow = tid >> 2;
    const int sseg = (tid & 3) * 8;

    const unsigned short* aSrc0 = A + (size_t)(m0 + srow) * 768 + sseg;
    const unsigned short* aSrc1 = A + (size_t)(m0 + 64 + srow) * 768 + sseg;
    const unsigned short* bSrc0 = BT + (size_t)(n0 + srow) * 768 + sseg;
    const unsigned short* bSrc1 = BT + (size_t)(n0 + 64 + srow) * 768 + sseg;
    char* aDst0 = (char*)Asl + wave * 1024;
    char* aDst1 = (char*)Asl + 4096 + wave * 1024;
    char* bDst0 = (char*)Bsl + wave * 1024;
    char* bDst1 = (char*)Bsl + 4096 + wave * 1024;

    f32x4 acc[4][4];
#pragma unroll
    for (int i = 0; i < 4; ++i)
#pragma unroll
      for (int j = 0; j < 4; ++j) { acc[i][j][0] = 0.f; acc[i][j][1] = 0.f; acc[i][j][2] = 0.f; acc[i][j][3] = 0.f; }

    for (int k0 = 0; k0 < 768; k0 += 32) {
      __syncthreads();
      glds16(aSrc0 + k0, aDst0);
      glds16(aSrc1 + k0, aDst1);
      glds16(bSrc0 + k0, bDst0);
      glds16(bSrc1 + k0, bDst1);
      __syncthreads();
      bf16x8 af[4], bfr[4];
#pragma unroll
      for (int mf = 0; mf < 4; ++mf)
        af[mf] = *(const bf16x8*)(Asl + (wm + mf * 16 + n16) * 32 + g16 * 8);
#pragma unroll
      for (int nf = 0; nf < 4; ++nf)
        bfr[nf] = *(const bf16x8*)(Bsl + (wn + nf * 16 + n16) * 32 + g16 * 8);
#pragma unroll
      for (int mf = 0; mf < 4; ++mf)
#pragma unroll
        for (int nf = 0; nf < 4; ++nf)
          acc[mf][nf] = mfma16(af[mf], bfr[nf], acc[mf][nf]);
    }

    const int erow0 = m0 + wm + 4 * g16;
    const int ecol0 = n0 + wn + n16;
#pragma unroll
    for (int mf = 0; mf < 4; ++mf)
#pragma unroll
      for (int nf = 0; nf < 4; ++nf)
#pragma unroll
        for (int r = 0; r < 4; ++r)
          Cgate[(size_t)(erow0 + mf * 16 + r) * HIDDEN + ecol0 + nf * 16] = bf16hi(gelu_tanh(acc[mf][nf][r]));
    return;
  }

  // ---------------- scan body (R6, 1 wave; threads >= 64 exit) --------------
  if (threadIdx.x >= 64) return;
  __builtin_amdgcn_s_setprio(1);

  const int bh = blockIdx.x;
  const int b = bh / NH, h = bh % NH;
  const int lane = threadIdx.x;
  const int n = lane & 15, g16 = lane >> 4;
  const float inv64 = 1.0f / 64.0f;

  const unsigned short* XQb = (const unsigned short*)XQg + (size_t)b * SSEQ * HIDDEN + h * 64;
  const unsigned short* XKb = (const unsigned short*)XKg + (size_t)b * SSEQ * HIDDEN + h * 64;
  const unsigned short* XVb = (const unsigned short*)XVg + (size_t)b * SSEQ * HIDDEN + h * 64;
  unsigned short* Zb = (unsigned short*)Zg + (size_t)b * SSEQ * HIDDEN + h * 64;
  const float* lrp = lrpre + ((size_t)b * NH + h) * SSEQ;

  f32x4 W1acc[4][4];
#pragma unroll
  for (int db = 0; db < 4; ++db)
#pragma unroll
    for (int eb = 0; eb < 4; ++eb)
#pragma unroll
      for (int r = 0; r < 4; ++r)
        W1acc[db][eb][r] = W1g[(size_t)h * 4096 + (16 * db + 4 * g16 + r) * 64 + 16 * eb + n];

  float b1r[4], tnsr[4], tnbr[4];
#pragma unroll
  for (int eb = 0; eb < 4; ++eb) {
    const int e = h * 64 + 16 * eb + n;
    b1r[eb] = b1g[e]; tnsr[eb] = tnsg[e]; tnbr[eb] = tnbg[e];
  }
  const float tok_n = fmaxf(1.0f / (float)(n + 1) + lti[n], 0.0f);
  const float tok15 = __shfl(tok_n, 15, 64);

  // identity B-frags for the A-layout -> C-layout transpose MFMAs (see R4/R5).
  frag_u id0, id1;
  {
    const unsigned short onebf = (g16 == (n >> 2)) ? (unsigned short)0x3F80 : (unsigned short)0;
    const unsigned vsh = ((unsigned)onebf) << (16 * (n & 1));
    const unsigned lo = ((n & 2) == 0) ? vsh : 0u;
    const unsigned hi = ((n & 2) != 0) ? vsh : 0u;
    id0.u32[0] = lo; id0.u32[1] = hi; id0.u32[2] = 0; id0.u32[3] = 0;
    id1.u32[0] = 0;  id1.u32[1] = 0;  id1.u32[2] = lo; id1.u32[3] = hi;
  }
  frag_u onesA;
  onesA.u32[0] = 0x3F803F80u; onesA.u32[1] = 0x3F803F80u;
  onesA.u32[2] = 0x3F803F80u; onesA.u32[3] = 0x3F803F80u;

  int offA[2][2], offC[4][4];
#pragma unroll
  for (int c = 0; c < 2; ++c)
#pragma unroll
    for (int jg = 0; jg < 2; ++jg)
      offA[c][jg] = n * HIDDEN + 16 * (2 * c + jg) + 4 * g16;
#pragma unroll
  for (int blk = 0; blk < 4; ++blk)
#pragma unroll
    for (int r = 0; r < 4; ++r)
      offC[blk][r] = (4 * g16 + r) * HIDDEN + 16 * blk + n;

  auto load_mb = [&](ScanBuf& bf, int mb) {
    const size_t sb = (size_t)mb * (KMB * HIDDEN);
#pragma unroll
    for (int c = 0; c < 2; ++c)
#pragma unroll
      for (int jg = 0; jg < 2; ++jg) {
        bf.qa[c][jg] = *(const uint2*)(XQb + sb + offA[c][jg]);
        bf.ka[c][jg] = *(const uint2*)(XKb + sb + offA[c][jg]);
        bf.va[c][jg] = *(const uint2*)(XVb + sb + offA[c][jg]);
      }
    const float4 l4 = *(const float4*)(lrp + mb * KMB + 4 * g16);
    bf.lr[0] = l4.x; bf.lr[1] = l4.y; bf.lr[2] = l4.z; bf.lr[3] = l4.w;
  };

  auto compute_mb = [&](ScanBuf& bf, int mb) {
    const size_t sb = (size_t)mb * (KMB * HIDDEN);
    float etaj[4];
#pragma unroll
    for (int jj = 0; jj < 4; ++jj)
      etaj[jj] = 1.0f / (64.0f * (1.0f + __expf(-bf.lr[jj])));

    // W1 -> bf16 B-frags via packed perm cvt
    frag_u w1f[2][4];
#pragma unroll
    for (int c = 0; c < 2; ++c)
#pragma unroll
      for (int eb = 0; eb < 4; ++eb) {
        w1f[c][eb].u32[0] = pack_bf16(W1acc[2 * c][eb][0], W1acc[2 * c][eb][1]);
        w1f[c][eb].u32[1] = pack_bf16(W1acc[2 * c][eb][2], W1acc[2 * c][eb][3]);
        w1f[c][eb].u32[2] = pack_bf16(W1acc[2 * c + 1][eb][0], W1acc[2 * c + 1][eb][1]);
        w1f[c][eb].u32[3] = pack_bf16(W1acc[2 * c + 1][eb][2], W1acc[2 * c + 1][eb][3]);
      }
    frag_u kaf[2], qaf[2], vaf[2];
#pragma unroll
    for (int c = 0; c < 2; ++c) {
      kaf[c].u32[0] = bf.ka[c][0].x; kaf[c].u32[1] = bf.ka[c][0].y;
      kaf[c].u32[2] = bf.ka[c][1].x; kaf[c].u32[3] = bf.ka[c][1].y;
      qaf[c].u32[0] = bf.qa[c][0].x; qaf[c].u32[1] = bf.qa[c][0].y;
      qaf[c].u32[2] = bf.qa[c][1].x; qaf[c].u32[3] = bf.qa[c][1].y;
      vaf[c].u32[0] = bf.va[c][0].x; vaf[c].u32[1] = bf.va[c][0].y;
      vaf[c].u32[2] = bf.va[c][1].x; vaf[c].u32[3] = bf.va[c][1].y;
    }

    // A-layout -> C-layout transposes (exact).
    f32x4 z4; z4[0] = 0.f; z4[1] = 0.f; z4[2] = 0.f; z4[3] = 0.f;
    f32x4 qcf[4], kcf[4], vcf[4];
#pragma unroll
    for (int c = 0; c < 2; ++c) {
      qcf[2 * c]     = mfma16(qaf[c].v, id0.v, z4);
      qcf[2 * c + 1] = mfma16(qaf[c].v, id1.v, z4);
      kcf[2 * c]     = mfma16(kaf[c].v, id0.v, z4);
      kcf[2 * c + 1] = mfma16(kaf[c].v, id1.v, z4);
      vcf[2 * c]     = mfma16(vaf[c].v, id0.v, z4);
      vcf[2 * c + 1] = mfma16(vaf[c].v, id1.v, z4);
    }
    // ktf: K^T A-frags for the W1 update (exact repack of bf16 values).
    frag_u ktf[4];
#pragma unroll
    for (int mk = 0; mk < 4; ++mk) {
      ktf[mk].u32[0] = pack_bf16(kcf[mk][0], kcf[mk][1]);
      ktf[mk].u32[1] = pack_bf16(kcf[mk][2], kcf[mk][3]);
      ktf[mk].u32[2] = 0; ktf[mk].u32[3] = 0;
    }

    f32x4 zk[4], zq[4];
#pragma unroll
    for (int eb = 0; eb < 4; ++eb) {
      f32x4 init; init[0] = b1r[eb]; init[1] = b1r[eb]; init[2] = b1r[eb]; init[3] = b1r[eb];
      zk[eb] = init; zq[eb] = init;
    }
#pragma unroll
    for (int c = 0; c < 2; ++c)
#pragma unroll
      for (int eb = 0; eb < 4; ++eb) {
        zk[eb] = mfma16(kaf[c].v, w1f[c][eb].v, zk[eb]);
        zq[eb] = mfma16(qaf[c].v, w1f[c][eb].v, zq[eb]);
      }
    f32x4 st_; st_[0] = 0.f; st_[1] = 0.f; st_[2] = 0.f; st_[3] = 0.f;
    st_ = mfma16(kaf[0].v, qaf[0].v, st_);
    st_ = mfma16(kaf[1].v, qaf[1].v, st_);

    float s1[4], s2[4];
#pragma unroll
    for (int r = 0; r < 4; ++r) {
      s1[r] = zk[0][r] + zk[1][r] + zk[2][r] + zk[3][r];
      s2[r] = zk[0][r] * zk[0][r] + zk[1][r] * zk[1][r] + zk[2][r] * zk[2][r] + zk[3][r] * zk[3][r];
    }
#pragma unroll
    for (int r = 0; r < 4; ++r) { s1[r] = rsum16(s1[r]); s2[r] = rsum16(s2[r]); }
    float mr[4], rstd[4];
#pragma unroll
    for (int r = 0; r < 4; ++r) {
      mr[r] = s1[r] * inv64;
      rstd[r] = rsqrtf(s2[r] * inv64 - mr[r] * mr[r] + 1e-5f);
    }
    float xh[4][4], gx[4][4], t1[4] = {0.f, 0.f, 0.f, 0.f}, t2[4] = {0.f, 0.f, 0.f, 0.f};
#pragma unroll
    for (int eb = 0; eb < 4; ++eb)
#pragma unroll
      for (int r = 0; r < 4; ++r) {
        const float xh_ = (zk[eb][r] - mr[r]) * rstd[r];
        const float tg = vcf[eb][r] - kcf[eb][r];
        const float gx_ = (xh_ * tnsr[eb] + tnbr[eb] - tg) * tnsr[eb];
        xh[eb][r] = xh_; gx[eb][r] = gx_;
        t1[r] += gx_; t2[r] += gx_ * xh_;
      }
#pragma unroll
    for (int r = 0; r < 4; ++r) { t1[r] = rsum16(t1[r]); t2[r] = rsum16(t2[r]); }
    float g_[4][4];
#pragma unroll
    for (int eb = 0; eb < 4; ++eb)
#pragma unroll
      for (int r = 0; r < 4; ++r)
        g_[eb][r] = (gx[eb][r] - t1[r] * inv64 - xh[eb][r] * (t2[r] * inv64)) * rstd[r];

    frag_u gbf[4];
#pragma unroll
    for (int eb = 0; eb < 4; ++eb) {
      gbf[eb].u32[0] = pack_bf16(g_[eb][0], g_[eb][1]);
      gbf[eb].u32[1] = pack_bf16(g_[eb][2], g_[eb][3]);
      gbf[eb].u32[2] = 0; gbf[eb].u32[3] = 0;
    }
    frag_u coef;
    {
      float cf[4];
#pragma unroll
      for (int jj = 0; jj < 4; ++jj) {
        const int j = 4 * g16 + jj;
        cf[jj] = (j <= n) ? -tok_n * etaj[jj] * (1.0f + st_[jj]) : 0.0f;
      }
      coef.u32[0] = pack_bf16(cf[0], cf[1]);
      coef.u32[1] = pack_bf16(cf[2], cf[3]);
      coef.u32[2] = 0; coef.u32[3] = 0;
    }
    f32x4 zbv[4];
#pragma unroll
    for (int eb = 0; eb < 4; ++eb)
      zbv[eb] = mfma16(coef.v, gbf[eb].v, zq[eb]);

#pragma unroll
    for (int r = 0; r < 4; ++r) {
      s1[r] = zbv[0][r] + zbv[1][r] + zbv[2][r] + zbv[3][r];
      s2[r] = zbv[0][r] * zbv[0][r] + zbv[1][r] * zbv[1][r] + zbv[2][r] * zbv[2][r] + zbv[3][r] * zbv[3][r];
    }
#pragma unroll
    for (int r = 0; r < 4; ++r) { s1[r] = rsum16(s1[r]); s2[r] = rsum16(s2[r]); }
#pragma unroll
    for (int r = 0; r < 4; ++r) {
      mr[r] = s1[r] * inv64;
      rstd[r] = rsqrtf(s2[r] * inv64 - mr[r] * mr[r] + 1e-5f);
    }
#pragma unroll
    for (int eb = 0; eb < 4; ++eb)
#pragma unroll
      for (int r = 0; r < 4; ++r) {
        const float o = qcf[eb][r] + (zbv[eb][r] - mr[r]) * rstd[r] * tnsr[eb] + tnbr[eb];
        Zb[sb + offC[eb][r]] = bf16hi(o);
      }

    float lgv[4][4];
    frag_u lgf[4];
#pragma unroll
    for (int eb = 0; eb < 4; ++eb) {
#pragma unroll
      for (int jj = 0; jj < 4; ++jj) lgv[eb][jj] = -tok15 * etaj[jj] * g_[eb][jj];
      lgf[eb].u32[0] = pack_bf16(lgv[eb][0], lgv[eb][1]);
      lgf[eb].u32[1] = pack_bf16(lgv[eb][2], lgv[eb][3]);
      lgf[eb].u32[2] = 0; lgf[eb].u32[3] = 0;
    }
#pragma unroll
    for (int mk = 0; mk < 4; ++mk)
#pragma unroll
      for (int eb = 0; eb < 4; ++eb)
        W1acc[mk][eb] = mfma16(ktf[mk].v, lgf[eb].v, W1acc[mk][eb]);
    // b1 update: token-sum of lgf via ones-A MFMA (every output row identical).
#pragma unroll
    for (int eb = 0; eb < 4; ++eb) {
      f32x4 bs = mfma16(onesA.v, lgf[eb].v, z4);
      b1r[eb] += bs[0];
    }
  };

  ScanBuf Abuf, Bbuf;
  load_mb(Abuf, 0);
  for (int mb = 0; mb < NMB; mb += 2) {
    load_mb(Bbuf, mb + 1);
    compute_mb(Abuf, mb);
    if (mb + 2 < NMB) load_mb(Abuf, mb + 2);
    compute_mb(Bbuf, mb + 1);
  }
  __builtin_amdgcn_s_setprio(0);
}

// ---------------- K5: fused per-token LN stats + epilogue ----------------
// aout = ((Z - mu) * rstd * pns + pnb) * gate, one pass over Z.
__global__ __launch_bounds__(256) void stats_epi_kernel(
    const unsigned short* __restrict__ Zb, const unsigned short* __restrict__ gateb,
    const float* __restrict__ pns, const float* __restrict__ pnb,
    unsigned short* __restrict__ aout) {
  const int g = threadIdx.x >> 6, l = threadIdx.x & 63;
  const int t = blockIdx.x * 4 + g;
  const size_t base = (size_t)t * HIDDEN;
  // each lane: 3 x uint2 loads = 12 bf16, cols l*4 + 256*j
  uint2 z2[3];
  float zv[12];
  float s_ = 0.f;
#pragma unroll
  for (int j = 0; j < 3; ++j) {
    const int c = l * 4 + 256 * j;
    z2[j] = *(const uint2*)(Zb + base + c);
    zv[4 * j + 0] = bf2f((unsigned short)(z2[j].x & 0xffff));
    zv[4 * j + 1] = bf2f((unsigned short)(z2[j].x >> 16));
    zv[4 * j + 2] = bf2f((unsigned short)(z2[j].y & 0xffff));
    zv[4 * j + 3] = bf2f((unsigned short)(z2[j].y >> 16));
    s_ += zv[4 * j] + zv[4 * j + 1] + zv[4 * j + 2] + zv[4 * j + 3];
  }
  s_ = wave_sum(s_);
  const float m = s_ * (1.0f / 768.0f);
  float v_ = 0.f;
#pragma unroll
  for (int k = 0; k < 12; ++k) { const float d = zv[k] - m; v_ += d * d; }
  v_ = wave_sum(v_) * (1.0f / 768.0f);
  const float rstd = rsqrtf(v_ + 1e-5f);
#pragma unroll
  for (int j = 0; j < 3; ++j) {
    const int c = l * 4 + 256 * j;
    const uint2 g2 = *(const uint2*)(gateb + base + c);
    const float4 p4 = *(const float4*)(pns + c);
    const float4 q4 = *(const float4*)(pnb + c);
    const float o0 = ((zv[4 * j + 0] - m) * rstd * p4.x + q4.x) * bf2f((unsigned short)(g2.x & 0xffff));
    const float o1 = ((zv[4 * j + 1] - m) * rstd * p4.y + q4.y) * bf2f((unsigned short)(g2.x >> 16));
    const float o2 = ((zv[4 * j + 2] - m) * rstd * p4.z + q4.z) * bf2f((unsigned short)(g2.y & 0xffff));
    const float o3 = ((zv[4 * j + 3] - m) * rstd * p4.w + q4.w) * bf2f((unsigned short)(g2.y >> 16));
    uint2 r; r.x = pack_bf16(o0, o1); r.y = pack_bf16(o2, o3);
    *(uint2*)(aout + base + c) = r;
  }
}

// ---------------- launch ----------------
extern "C" void kernel_launch(void* const* d_in, const int* in_sizes, int n_in,
                              void* d_out, int out_size, void* d_ws, size_t ws_size,
                              hipStream_t stream) {
  const float* x   = (const float*)d_in[0];
  const float* wq  = (const float*)d_in[1];
  const float* wv  = (const float*)d_in[2];
  const float* wo  = (const float*)d_in[3];
  const float* wg  = (const float*)d_in[4];
  const float* cqw = (const float*)d_in[5];
  const float* cqb = (const float*)d_in[6];
  const float* ckw = (const float*)d_in[7];
  const float* ckb = (const float*)d_in[8];
  const float* lrw = (const float*)d_in[9];
  const float* lrb = (const float*)d_in[10];
  const float* lti = (const float*)d_in[11];
  const float* tns = (const float*)d_in[12];
  const float* tnb = (const float*)d_in[13];
  const float* pns = (const float*)d_in[14];
  const float* pnb = (const float*)d_in[15];
  const float* W1g = (const float*)d_in[16];
  const float* b1g = (const float*)d_in[17];
  float* out = (float*)d_out;

  // ws layout (bf16 slots, with aliasing): total ~309 MB
  // slot0: xb (input to GEMMs, incl. the in-fused gate GEMM) / aout (post-epi)
  // slot1: xqk (conv input, dead after convrope) / Z (scan output)
  unsigned short* zbuf = (unsigned short*)d_ws;
  unsigned short* xqk  = zbuf + NELT;
  unsigned short* xv   = xqk + NELT;
  unsigned short* gate = xv + NELT;
  unsigned short* xq   = gate + NELT;
  unsigned short* xk   = xq + NELT;
  unsigned short* wqT  = xk + NELT;
  unsigned short* wvT  = wqT + WELT;
  unsigned short* wgT  = wvT + WELT;
  unsigned short* woT  = wgT + WELT;
  float* lrpre = (float*)(woT + WELT);
  unsigned short* xb   = zbuf;   // slot0 pre-scan
  unsigned short* zOut = xqk;    // slot1 post-convrope
  unsigned short* aout = zbuf;   // slot0 post-scan

  const dim3 wtGrid(24, 24);
  cvt_x_kernel<<<(unsigned)(NELT / 4 / 256), 256, 0, stream>>>(x, xb);
  cvt_wT_kernel<<<wtGrid, 256, 0, stream>>>(wq, wqT);
  cvt_wT_kernel<<<wtGrid, 256, 0, stream>>>(wv, wvT);
  cvt_wT_kernel<<<wtGrid, 256, 0, stream>>>(wg, wgT);
  cvt_wT_kernel<<<wtGrid, 256, 0, stream>>>(wo, woT);

  const dim3 gemmGrid((unsigned)(NTOK / 128), HIDDEN / 128);
  gemm_mfma<<<gemmGrid, 256, 0, stream>>>(xb, wqT, (void*)xqk, 0);
  gemm_mfma<<<gemmGrid, 256, 0, stream>>>(xb, wvT, (void*)xv, 0);
  lrpre_kernel<<<(unsigned)(NTOK / 4), 256, 0, stream>>>(x, lrw, lrb, lrpre);
  convrope_kernel<<<(unsigned)(NTOK * 384 / 256), 256, 0, stream>>>(
      (const __hip_bfloat16*)xqk, cqw, cqb, ckw, ckb,
      (__hip_bfloat16*)xq, (__hip_bfloat16*)xk);
  fused_scan_gate<<<48 + 1536, 256, 0, stream>>>(
      (const __hip_bfloat16*)xq, (const __hip_bfloat16*)xk,
      (const __hip_bfloat16*)xv, lrpre, lti, tns, tnb, W1g, b1g,
      (__hip_bfloat16*)zOut, xb, wgT, gate);
  stats_epi_kernel<<<(unsigned)(NTOK / 4), 256, 0, stream>>>(zOut, gate, pns, pnb, aout);
  gemm_mfma<<<gemmGrid, 256, 0, stream>>>(aout, woT, (void*)out, 2);
}

// Round 14
// 1714.035 us; speedup vs baseline: 2.1248x; 1.0386x over previous
//
#include <hip/hip_runtime.h>
#include <hip/hip_bf16.h>
#include <math.h>

// Problem constants
#define BB 4
#define SSEQ 8192
#define HIDDEN 768
#define NH 12
#define DDIM 64
#define KMB 16
#define NMB 512
#define NTOK ((size_t)BB * SSEQ)          // 32768
#define NELT (NTOK * HIDDEN)              // 25,165,824
#define WELT (768 * 768)

typedef short bf16x8 __attribute__((ext_vector_type(8)));
typedef float f32x4 __attribute__((ext_vector_type(4)));

union frag_u {
  bf16x8 v;
  unsigned u32[4];
  unsigned short u16[8];
};

__device__ __forceinline__ f32x4 mfma16(bf16x8 a, bf16x8 b, f32x4 c) {
  return __builtin_amdgcn_mfma_f32_16x16x32_bf16(a, b, c, 0, 0, 0);
}

// ---------------- helpers ----------------
__device__ __forceinline__ float wave_sum(float v) {
#pragma unroll
  for (int off = 32; off > 0; off >>= 1) v += __shfl_xor(v, off, 64);
  return v;
}

// DPP row_ror fold-add: v += rotate_within_row16(v, N). VALU-only cross-lane.
template <int CTRL>
__device__ __forceinline__ float dpp_add(float v) {
  union { float f; int i; } a, b;
  a.f = v;
  b.i = __builtin_amdgcn_update_dpp(0, a.i, CTRL, 0xF, 0xF, true);
  return v + b.f;
}
// full sum across each row of 16 lanes; every lane gets the total.
__device__ __forceinline__ float rsum16(float v) {
  v = dpp_add<0x121>(v);  // row_ror:1
  v = dpp_add<0x122>(v);  // row_ror:2
  v = dpp_add<0x124>(v);  // row_ror:4
  v = dpp_add<0x128>(v);  // row_ror:8
  return v;
}

// round-half-up bf16 (ties differ from RNE only on exact .5 ulp; negligible)
__device__ __forceinline__ unsigned short bf16hi(float x) {
  union { float f; unsigned u; } a; a.f = x;
  return (unsigned short)((a.u + 0x8000u) >> 16);
}
// pack two floats -> (bf16(f1)<<16)|bf16(f0) in 3 VALU ops via v_perm_b32
__device__ __forceinline__ unsigned pack_bf16(float f0, float f1) {
  union { float f; unsigned u; } a, b; a.f = f0; b.f = f1;
  return __builtin_amdgcn_perm(b.u + 0x8000u, a.u + 0x8000u, 0x07060302u);
}
__device__ __forceinline__ float bf2f(unsigned short s) {
  union { unsigned u; float f; } a; a.u = ((unsigned)s) << 16; return a.f;
}
__device__ __forceinline__ float gelu_tanh(float x) {
  float x3 = x * x * x;
  return 0.5f * x * (1.0f + tanhf(0.7978845608028654f * (x + 0.044715f * x3)));
}

__device__ __forceinline__ void glds16(const void* g, void* l) {
  __builtin_amdgcn_global_load_lds(
      (const __attribute__((address_space(1))) void*)g,
      (__attribute__((address_space(3))) void*)l, 16, 0, 0);
}

// ---------------- K0a: fused x->xb (bf16) + lrpre ----------------
// One pass over x (f32): emits bf16 xb AND lrpre[b,h,s] = x.lr_w[h] + lr_b[h].
// Wave g owns token t = blockIdx*4+g; lane l owns cols l+64j, j=0..11.
__global__ __launch_bounds__(256) void cvtx_lrpre_kernel(
    const float* __restrict__ x, const float* __restrict__ lrw,
    const float* __restrict__ lrb, unsigned short* __restrict__ xb,
    float* __restrict__ lrpre) {
  const int g = threadIdx.x >> 6, l = threadIdx.x & 63;
  const int t = blockIdx.x * 4 + g;
  const float* xr = x + (size_t)t * HIDDEN;
  unsigned short* xw = xb + (size_t)t * HIDDEN;
  float xv[12];
#pragma unroll
  for (int j = 0; j < 12; ++j) xv[j] = xr[l + 64 * j];
#pragma unroll
  for (int j = 0; j < 12; ++j) xw[l + 64 * j] = bf16hi(xv[j]);
  const int b = t >> 13, s = t & (SSEQ - 1);
  for (int h = 0; h < NH; ++h) {
    const float* wr = lrw + (size_t)h * HIDDEN;
    float a = 0.f;
#pragma unroll
    for (int j = 0; j < 12; ++j) a += xv[j] * wr[l + 64 * j];
    a = wave_sum(a);
    if (l == 0) lrpre[((size_t)b * NH + h) * SSEQ + s] = a + lrb[h];
  }
}

// ---------------- K0b: 4x W (768x768 f32) -> W^T (bf16), one dispatch --------
__global__ __launch_bounds__(256) void cvt_wT4_kernel(
    const float* __restrict__ W0, const float* __restrict__ W1,
    const float* __restrict__ W2, const float* __restrict__ W3,
    unsigned short* __restrict__ D0, unsigned short* __restrict__ D1,
    unsigned short* __restrict__ D2, unsigned short* __restrict__ D3) {
  const float* W; unsigned short* WT;
  if (blockIdx.z == 0)      { W = W0; WT = D0; }
  else if (blockIdx.z == 1) { W = W1; WT = D1; }
  else if (blockIdx.z == 2) { W = W2; WT = D2; }
  else                      { W = W3; WT = D3; }
  __shared__ float tile[32][33];
  const int tx = threadIdx.x & 31, ty = threadIdx.x >> 5;  // ty 0..7
  const int k0 = blockIdx.x * 32, n0 = blockIdx.y * 32;
#pragma unroll
  for (int r = 0; r < 4; ++r)
    tile[ty + 8 * r][tx] = W[(size_t)(k0 + ty + 8 * r) * 768 + n0 + tx];
  __syncthreads();
#pragma unroll
  for (int r = 0; r < 4; ++r)
    WT[(size_t)(n0 + ty + 8 * r) * 768 + k0 + tx] = bf16hi(tile[tx][ty + 8 * r]);
}

// ---------------- K1: MFMA GEMM  C[M,768] = A[M,768] @ BT[768,768]^T ------------
// m97 structure: 128x128 tile, BK=32, 256 thr (4 waves 2x2), global_load_lds w16.
// mode: 0 = bf16 out, 1 = bf16+gelu out, 2 = f32 out
__global__ __launch_bounds__(256) void gemm_mfma(
    const unsigned short* __restrict__ A, const unsigned short* __restrict__ BT,
    void* __restrict__ Cout, int mode) {
  __shared__ __align__(16) unsigned short Asl[128 * 32];
  __shared__ __align__(16) unsigned short Bsl[128 * 32];
  const int tid = threadIdx.x;
  const int wave = tid >> 6, lane = tid & 63;
  const int n16 = lane & 15, g16 = lane >> 4;
  const int wm = (wave >> 1) * 64, wn = (wave & 1) * 64;
  const int m0 = blockIdx.x * 128, n0 = blockIdx.y * 128;

  const int srow = tid >> 2;            // 0..63
  const int sseg = (tid & 3) * 8;       // k-element offset

  const unsigned short* aSrc0 = A + (size_t)(m0 + srow) * 768 + sseg;
  const unsigned short* aSrc1 = A + (size_t)(m0 + 64 + srow) * 768 + sseg;
  const unsigned short* bSrc0 = BT + (size_t)(n0 + srow) * 768 + sseg;
  const unsigned short* bSrc1 = BT + (size_t)(n0 + 64 + srow) * 768 + sseg;
  char* aDst0 = (char*)Asl + wave * 1024;
  char* aDst1 = (char*)Asl + 4096 + wave * 1024;
  char* bDst0 = (char*)Bsl + wave * 1024;
  char* bDst1 = (char*)Bsl + 4096 + wave * 1024;

  f32x4 acc[4][4];
#pragma unroll
  for (int i = 0; i < 4; ++i)
#pragma unroll
    for (int j = 0; j < 4; ++j) { acc[i][j][0] = 0.f; acc[i][j][1] = 0.f; acc[i][j][2] = 0.f; acc[i][j][3] = 0.f; }

  for (int k0 = 0; k0 < 768; k0 += 32) {
    __syncthreads();
    glds16(aSrc0 + k0, aDst0);
    glds16(aSrc1 + k0, aDst1);
    glds16(bSrc0 + k0, bDst0);
    glds16(bSrc1 + k0, bDst1);
    __syncthreads();
    bf16x8 af[4], bfr[4];
#pragma unroll
    for (int mf = 0; mf < 4; ++mf)
      af[mf] = *(const bf16x8*)(Asl + (wm + mf * 16 + n16) * 32 + g16 * 8);
#pragma unroll
    for (int nf = 0; nf < 4; ++nf)
      bfr[nf] = *(const bf16x8*)(Bsl + (wn + nf * 16 + n16) * 32 + g16 * 8);
#pragma unroll
    for (int mf = 0; mf < 4; ++mf)
#pragma unroll
      for (int nf = 0; nf < 4; ++nf)
        acc[mf][nf] = mfma16(af[mf], bfr[nf], acc[mf][nf]);
  }

  const int erow0 = m0 + wm + 4 * g16;
  const int ecol0 = n0 + wn + n16;
  if (mode == 2) {
    float* C = (float*)Cout;
#pragma unroll
    for (int mf = 0; mf < 4; ++mf)
#pragma unroll
      for (int nf = 0; nf < 4; ++nf)
#pragma unroll
        for (int r = 0; r < 4; ++r)
          C[(size_t)(erow0 + mf * 16 + r) * HIDDEN + ecol0 + nf * 16] = acc[mf][nf][r];
  } else if (mode == 1) {
    unsigned short* C = (unsigned short*)Cout;
#pragma unroll
    for (int mf = 0; mf < 4; ++mf)
#pragma unroll
      for (int nf = 0; nf < 4; ++nf)
#pragma unroll
        for (int r = 0; r < 4; ++r)
          C[(size_t)(erow0 + mf * 16 + r) * HIDDEN + ecol0 + nf * 16] = bf16hi(gelu_tanh(acc[mf][nf][r]));
  } else {
    unsigned short* C = (unsigned short*)Cout;
#pragma unroll
    for (int mf = 0; mf < 4; ++mf)
#pragma unroll
      for (int nf = 0; nf < 4; ++nf)
#pragma unroll
        for (int r = 0; r < 4; ++r)
          C[(size_t)(erow0 + mf * 16 + r) * HIDDEN + ecol0 + nf * 16] = bf16hi(acc[mf][nf][r]);
  }
}

// ---------------- K1b: dual GEMM (xqk + xv in one dispatch, z selects) --------
__global__ __launch_bounds__(256) void gemm_dual(
    const unsigned short* __restrict__ A,
    const unsigned short* __restrict__ BT0, const unsigned short* __restrict__ BT1,
    unsigned short* __restrict__ C0, unsigned short* __restrict__ C1) {
  const unsigned short* BT; unsigned short* C;
  if (blockIdx.z == 0) { BT = BT0; C = C0; } else { BT = BT1; C = C1; }
  __shared__ __align__(16) unsigned short Asl[128 * 32];
  __shared__ __align__(16) unsigned short Bsl[128 * 32];
  const int tid = threadIdx.x;
  const int wave = tid >> 6, lane = tid & 63;
  const int n16 = lane & 15, g16 = lane >> 4;
  const int wm = (wave >> 1) * 64, wn = (wave & 1) * 64;
  const int m0 = blockIdx.x * 128, n0 = blockIdx.y * 128;

  const int srow = tid >> 2;
  const int sseg = (tid & 3) * 8;

  const unsigned short* aSrc0 = A + (size_t)(m0 + srow) * 768 + sseg;
  const unsigned short* aSrc1 = A + (size_t)(m0 + 64 + srow) * 768 + sseg;
  const unsigned short* bSrc0 = BT + (size_t)(n0 + srow) * 768 + sseg;
  const unsigned short* bSrc1 = BT + (size_t)(n0 + 64 + srow) * 768 + sseg;
  char* aDst0 = (char*)Asl + wave * 1024;
  char* aDst1 = (char*)Asl + 4096 + wave * 1024;
  char* bDst0 = (char*)Bsl + wave * 1024;
  char* bDst1 = (char*)Bsl + 4096 + wave * 1024;

  f32x4 acc[4][4];
#pragma unroll
  for (int i = 0; i < 4; ++i)
#pragma unroll
    for (int j = 0; j < 4; ++j) { acc[i][j][0] = 0.f; acc[i][j][1] = 0.f; acc[i][j][2] = 0.f; acc[i][j][3] = 0.f; }

  for (int k0 = 0; k0 < 768; k0 += 32) {
    __syncthreads();
    glds16(aSrc0 + k0, aDst0);
    glds16(aSrc1 + k0, aDst1);
    glds16(bSrc0 + k0, bDst0);
    glds16(bSrc1 + k0, bDst1);
    __syncthreads();
    bf16x8 af[4], bfr[4];
#pragma unroll
    for (int mf = 0; mf < 4; ++mf)
      af[mf] = *(const bf16x8*)(Asl + (wm + mf * 16 + n16) * 32 + g16 * 8);
#pragma unroll
    for (int nf = 0; nf < 4; ++nf)
      bfr[nf] = *(const bf16x8*)(Bsl + (wn + nf * 16 + n16) * 32 + g16 * 8);
#pragma unroll
    for (int mf = 0; mf < 4; ++mf)
#pragma unroll
      for (int nf = 0; nf < 4; ++nf)
        acc[mf][nf] = mfma16(af[mf], bfr[nf], acc[mf][nf]);
  }

  const int erow0 = m0 + wm + 4 * g16;
  const int ecol0 = n0 + wn + n16;
#pragma unroll
  for (int mf = 0; mf < 4; ++mf)
#pragma unroll
    for (int nf = 0; nf < 4; ++nf)
#pragma unroll
      for (int r = 0; r < 4; ++r)
        C[(size_t)(erow0 + mf * 16 + r) * HIDDEN + ecol0 + nf * 16] = bf16hi(acc[mf][nf][r]);
}

// ---------------- K3: conv (causal) + RoPE ----------------
__global__ __launch_bounds__(256) void convrope_kernel(
    const __hip_bfloat16* __restrict__ xqk,
    const float* __restrict__ cqw, const float* __restrict__ cqb,
    const float* __restrict__ ckw, const float* __restrict__ ckb,
    __hip_bfloat16* __restrict__ XQ, __hip_bfloat16* __restrict__ XK) {
  const size_t gid = (size_t)blockIdx.x * 256 + threadIdx.x;  // over NTOK*384
  const int p = (int)(gid % 384);
  const size_t bt = gid / 384;
  const int t = (int)(bt & (SSEQ - 1));
  const int c0 = 2 * p, c1 = c0 + 1;
  float q0 = cqb[c0], q1 = cqb[c1], k0v = ckb[c0], k1v = ckb[c1];
#pragma unroll
  for (int kk = 0; kk < 4; ++kk) {
    const int tp = t - 4 + kk;
    if (tp >= 0) {
      const size_t src = (bt - t + tp) * HIDDEN;
      const float x0 = __bfloat162float(xqk[src + c0]);
      const float x1 = __bfloat162float(xqk[src + c1]);
      q0  += cqw[kk * HIDDEN + c0] * x0;  q1  += cqw[kk * HIDDEN + c1] * x1;
      k0v += ckw[kk * HIDDEN + c0] * x0;  k1v += ckw[kk * HIDDEN + c1] * x1;
    }
  }
  const int f = p & 31;
  const float invf = expf(-(float)f * 0.28782313662425572f);  // ln(10000)/32
  const float ang = (float)t * invf;
  float sn, cs;
  sincosf(ang, &sn, &cs);
  const size_t o = bt * HIDDEN;
  XQ[o + c0] = __float2bfloat16(q0 * cs - q1 * sn);
  XQ[o + c1] = __float2bfloat16(q0 * sn + q1 * cs);
  XK[o + c0] = __float2bfloat16(k0v * cs - k1v * sn);
  XK[o + c1] = __float2bfloat16(k0v * sn + k1v * cs);
}

// ---------------- K4: FUSED scan (blocks 0..47) + gate GEMM (blocks 48..1583) ----
// R13 verified: 1216us fused, total 1780us, absmax .03125. Unchanged in R14.
struct ScanBuf {
  uint2 qa[2][2], ka[2][2], va[2][2];
  float lr[4];
};

__global__ __launch_bounds__(256) void fused_scan_gate(
    const __hip_bfloat16* __restrict__ XQg, const __hip_bfloat16* __restrict__ XKg,
    const __hip_bfloat16* __restrict__ XVg, const float* __restrict__ lrpre,
    const float* __restrict__ lti, const float* __restrict__ tnsg,
    const float* __restrict__ tnbg, const float* __restrict__ W1g,
    const float* __restrict__ b1g, __hip_bfloat16* __restrict__ Zg,
    const unsigned short* __restrict__ A, const unsigned short* __restrict__ BT,
    unsigned short* __restrict__ Cgate) {
  if (blockIdx.x >= 48) {
    // ---------------- gate GEMM body (m97 structure, gelu epilogue) ----------
    __shared__ __align__(16) unsigned short Asl[128 * 32];
    __shared__ __align__(16) unsigned short Bsl[128 * 32];
    const int bid = blockIdx.x - 48;          // 0..1535
    const int tid = threadIdx.x;
    const int wave = tid >> 6, lane = tid & 63;
    const int n16 = lane & 15, g16 = lane >> 4;
    const int wm = (wave >> 1) * 64, wn = (wave & 1) * 64;
    const int m0 = (bid & 255) * 128, n0 = (bid >> 8) * 128;

    const int srow = tid >> 2;
    const int sseg = (tid & 3) * 8;

    const unsigned short* aSrc0 = A + (size_t)(m0 + srow) * 768 + sseg;
    const unsigned short* aSrc1 = A + (size_t)(m0 + 64 + srow) * 768 + sseg;
    const unsigned short* bSrc0 = BT + (size_t)(n0 + srow) * 768 + sseg;
    const unsigned short* bSrc1 = BT + (size_t)(n0 + 64 + srow) * 768 + sseg;
    char* aDst0 = (char*)Asl + wave * 1024;
    char* aDst1 = (char*)Asl + 4096 + wave * 1024;
    char* bDst0 = (char*)Bsl + wave * 1024;
    char* bDst1 = (char*)Bsl + 4096 + wave * 1024;

    f32x4 acc[4][4];
#pragma unroll
    for (int i = 0; i < 4; ++i)
#pragma unroll
      for (int j = 0; j < 4; ++j) { acc[i][j][0] = 0.f; acc[i][j][1] = 0.f; acc[i][j][2] = 0.f; acc[i][j][3] = 0.f; }

    for (int k0 = 0; k0 < 768; k0 += 32) {
      __syncthreads();
      glds16(aSrc0 + k0, aDst0);
      glds16(aSrc1 + k0, aDst1);
      glds16(bSrc0 + k0, bDst0);
      glds16(bSrc1 + k0, bDst1);
      __syncthreads();
      bf16x8 af[4], bfr[4];
#pragma unroll
      for (int mf = 0; mf < 4; ++mf)
        af[mf] = *(const bf16x8*)(Asl + (wm + mf * 16 + n16) * 32 + g16 * 8);
#pragma unroll
      for (int nf = 0; nf < 4; ++nf)
        bfr[nf] = *(const bf16x8*)(Bsl + (wn + nf * 16 + n16) * 32 + g16 * 8);
#pragma unroll
      for (int mf = 0; mf < 4; ++mf)
#pragma unroll
        for (int nf = 0; nf < 4; ++nf)
          acc[mf][nf] = mfma16(af[mf], bfr[nf], acc[mf][nf]);
    }

    const int erow0 = m0 + wm + 4 * g16;
    const int ecol0 = n0 + wn + n16;
#pragma unroll
    for (int mf = 0; mf < 4; ++mf)
#pragma unroll
      for (int nf = 0; nf < 4; ++nf)
#pragma unroll
        for (int r = 0; r < 4; ++r)
          Cgate[(size_t)(erow0 + mf * 16 + r) * HIDDEN + ecol0 + nf * 16] = bf16hi(gelu_tanh(acc[mf][nf][r]));
    return;
  }

  // ---------------- scan body (R6, 1 wave; threads >= 64 exit) --------------
  if (threadIdx.x >= 64) return;
  __builtin_amdgcn_s_setprio(1);

  const int bh = blockIdx.x;
  const int b = bh / NH, h = bh % NH;
  const int lane = threadIdx.x;
  const int n = lane & 15, g16 = lane >> 4;
  const float inv64 = 1.0f / 64.0f;

  const unsigned short* XQb = (const unsigned short*)XQg + (size_t)b * SSEQ * HIDDEN + h * 64;
  const unsigned short* XKb = (const unsigned short*)XKg + (size_t)b * SSEQ * HIDDEN + h * 64;
  const unsigned short* XVb = (const unsigned short*)XVg + (size_t)b * SSEQ * HIDDEN + h * 64;
  unsigned short* Zb = (unsigned short*)Zg + (size_t)b * SSEQ * HIDDEN + h * 64;
  const float* lrp = lrpre + ((size_t)b * NH + h) * SSEQ;

  f32x4 W1acc[4][4];
#pragma unroll
  for (int db = 0; db < 4; ++db)
#pragma unroll
    for (int eb = 0; eb < 4; ++eb)
#pragma unroll
      for (int r = 0; r < 4; ++r)
        W1acc[db][eb][r] = W1g[(size_t)h * 4096 + (16 * db + 4 * g16 + r) * 64 + 16 * eb + n];

  float b1r[4], tnsr[4], tnbr[4];
#pragma unroll
  for (int eb = 0; eb < 4; ++eb) {
    const int e = h * 64 + 16 * eb + n;
    b1r[eb] = b1g[e]; tnsr[eb] = tnsg[e]; tnbr[eb] = tnbg[e];
  }
  const float tok_n = fmaxf(1.0f / (float)(n + 1) + lti[n], 0.0f);
  const float tok15 = __shfl(tok_n, 15, 64);

  // identity B-frags for the A-layout -> C-layout transpose MFMAs (see R4/R5).
  frag_u id0, id1;
  {
    const unsigned short onebf = (g16 == (n >> 2)) ? (unsigned short)0x3F80 : (unsigned short)0;
    const unsigned vsh = ((unsigned)onebf) << (16 * (n & 1));
    const unsigned lo = ((n & 2) == 0) ? vsh : 0u;
    const unsigned hi = ((n & 2) != 0) ? vsh : 0u;
    id0.u32[0] = lo; id0.u32[1] = hi; id0.u32[2] = 0; id0.u32[3] = 0;
    id1.u32[0] = 0;  id1.u32[1] = 0;  id1.u32[2] = lo; id1.u32[3] = hi;
  }
  frag_u onesA;
  onesA.u32[0] = 0x3F803F80u; onesA.u32[1] = 0x3F803F80u;
  onesA.u32[2] = 0x3F803F80u; onesA.u32[3] = 0x3F803F80u;

  int offA[2][2], offC[4][4];
#pragma unroll
  for (int c = 0; c < 2; ++c)
#pragma unroll
    for (int jg = 0; jg < 2; ++jg)
      offA[c][jg] = n * HIDDEN + 16 * (2 * c + jg) + 4 * g16;
#pragma unroll
  for (int blk = 0; blk < 4; ++blk)
#pragma unroll
    for (int r = 0; r < 4; ++r)
      offC[blk][r] = (4 * g16 + r) * HIDDEN + 16 * blk + n;

  auto load_mb = [&](ScanBuf& bf, int mb) {
    const size_t sb = (size_t)mb * (KMB * HIDDEN);
#pragma unroll
    for (int c = 0; c < 2; ++c)
#pragma unroll
      for (int jg = 0; jg < 2; ++jg) {
        bf.qa[c][jg] = *(const uint2*)(XQb + sb + offA[c][jg]);
        bf.ka[c][jg] = *(const uint2*)(XKb + sb + offA[c][jg]);
        bf.va[c][jg] = *(const uint2*)(XVb + sb + offA[c][jg]);
      }
    const float4 l4 = *(const float4*)(lrp + mb * KMB + 4 * g16);
    bf.lr[0] = l4.x; bf.lr[1] = l4.y; bf.lr[2] = l4.z; bf.lr[3] = l4.w;
  };

  auto compute_mb = [&](ScanBuf& bf, int mb) {
    const size_t sb = (size_t)mb * (KMB * HIDDEN);
    float etaj[4];
#pragma unroll
    for (int jj = 0; jj < 4; ++jj)
      etaj[jj] = 1.0f / (64.0f * (1.0f + __expf(-bf.lr[jj])));

    // W1 -> bf16 B-frags via packed perm cvt
    frag_u w1f[2][4];
#pragma unroll
    for (int c = 0; c < 2; ++c)
#pragma unroll
      for (int eb = 0; eb < 4; ++eb) {
        w1f[c][eb].u32[0] = pack_bf16(W1acc[2 * c][eb][0], W1acc[2 * c][eb][1]);
        w1f[c][eb].u32[1] = pack_bf16(W1acc[2 * c][eb][2], W1acc[2 * c][eb][3]);
        w1f[c][eb].u32[2] = pack_bf16(W1acc[2 * c + 1][eb][0], W1acc[2 * c + 1][eb][1]);
        w1f[c][eb].u32[3] = pack_bf16(W1acc[2 * c + 1][eb][2], W1acc[2 * c + 1][eb][3]);
      }
    frag_u kaf[2], qaf[2], vaf[2];
#pragma unroll
    for (int c = 0; c < 2; ++c) {
      kaf[c].u32[0] = bf.ka[c][0].x; kaf[c].u32[1] = bf.ka[c][0].y;
      kaf[c].u32[2] = bf.ka[c][1].x; kaf[c].u32[3] = bf.ka[c][1].y;
      qaf[c].u32[0] = bf.qa[c][0].x; qaf[c].u32[1] = bf.qa[c][0].y;
      qaf[c].u32[2] = bf.qa[c][1].x; qaf[c].u32[3] = bf.qa[c][1].y;
      vaf[c].u32[0] = bf.va[c][0].x; vaf[c].u32[1] = bf.va[c][0].y;
      vaf[c].u32[2] = bf.va[c][1].x; vaf[c].u32[3] = bf.va[c][1].y;
    }

    // A-layout -> C-layout transposes (exact).
    f32x4 z4; z4[0] = 0.f; z4[1] = 0.f; z4[2] = 0.f; z4[3] = 0.f;
    f32x4 qcf[4], kcf[4], vcf[4];
#pragma unroll
    for (int c = 0; c < 2; ++c) {
      qcf[2 * c]     = mfma16(qaf[c].v, id0.v, z4);
      qcf[2 * c + 1] = mfma16(qaf[c].v, id1.v, z4);
      kcf[2 * c]     = mfma16(kaf[c].v, id0.v, z4);
      kcf[2 * c + 1] = mfma16(kaf[c].v, id1.v, z4);
      vcf[2 * c]     = mfma16(vaf[c].v, id0.v, z4);
      vcf[2 * c + 1] = mfma16(vaf[c].v, id1.v, z4);
    }
    // ktf: K^T A-frags for the W1 update (exact repack of bf16 values).
    frag_u ktf[4];
#pragma unroll
    for (int mk = 0; mk < 4; ++mk) {
      ktf[mk].u32[0] = pack_bf16(kcf[mk][0], kcf[mk][1]);
      ktf[mk].u32[1] = pack_bf16(kcf[mk][2], kcf[mk][3]);
      ktf[mk].u32[2] = 0; ktf[mk].u32[3] = 0;
    }

    f32x4 zk[4], zq[4];
#pragma unroll
    for (int eb = 0; eb < 4; ++eb) {
      f32x4 init; init[0] = b1r[eb]; init[1] = b1r[eb]; init[2] = b1r[eb]; init[3] = b1r[eb];
      zk[eb] = init; zq[eb] = init;
    }
#pragma unroll
    for (int c = 0; c < 2; ++c)
#pragma unroll
      for (int eb = 0; eb < 4; ++eb) {
        zk[eb] = mfma16(kaf[c].v, w1f[c][eb].v, zk[eb]);
        zq[eb] = mfma16(qaf[c].v, w1f[c][eb].v, zq[eb]);
      }
    f32x4 st_; st_[0] = 0.f; st_[1] = 0.f; st_[2] = 0.f; st_[3] = 0.f;
    st_ = mfma16(kaf[0].v, qaf[0].v, st_);
    st_ = mfma16(kaf[1].v, qaf[1].v, st_);

    float s1[4], s2[4];
#pragma unroll
    for (int r = 0; r < 4; ++r) {
      s1[r] = zk[0][r] + zk[1][r] + zk[2][r] + zk[3][r];
      s2[r] = zk[0][r] * zk[0][r] + zk[1][r] * zk[1][r] + zk[2][r] * zk[2][r] + zk[3][r] * zk[3][r];
    }
#pragma unroll
    for (int r = 0; r < 4; ++r) { s1[r] = rsum16(s1[r]); s2[r] = rsum16(s2[r]); }
    float mr[4], rstd[4];
#pragma unroll
    for (int r = 0; r < 4; ++r) {
      mr[r] = s1[r] * inv64;
      rstd[r] = rsqrtf(s2[r] * inv64 - mr[r] * mr[r] + 1e-5f);
    }
    float xh[4][4], gx[4][4], t1[4] = {0.f, 0.f, 0.f, 0.f}, t2[4] = {0.f, 0.f, 0.f, 0.f};
#pragma unroll
    for (int eb = 0; eb < 4; ++eb)
#pragma unroll
      for (int r = 0; r < 4; ++r) {
        const float xh_ = (zk[eb][r] - mr[r]) * rstd[r];
        const float tg = vcf[eb][r] - kcf[eb][r];
        const float gx_ = (xh_ * tnsr[eb] + tnbr[eb] - tg) * tnsr[eb];
        xh[eb][r] = xh_; gx[eb][r] = gx_;
        t1[r] += gx_; t2[r] += gx_ * xh_;
      }
#pragma unroll
    for (int r = 0; r < 4; ++r) { t1[r] = rsum16(t1[r]); t2[r] = rsum16(t2[r]); }
    float g_[4][4];
#pragma unroll
    for (int eb = 0; eb < 4; ++eb)
#pragma unroll
      for (int r = 0; r < 4; ++r)
        g_[eb][r] = (gx[eb][r] - t1[r] * inv64 - xh[eb][r] * (t2[r] * inv64)) * rstd[r];

    frag_u gbf[4];
#pragma unroll
    for (int eb = 0; eb < 4; ++eb) {
      gbf[eb].u32[0] = pack_bf16(g_[eb][0], g_[eb][1]);
      gbf[eb].u32[1] = pack_bf16(g_[eb][2], g_[eb][3]);
      gbf[eb].u32[2] = 0; gbf[eb].u32[3] = 0;
    }
    frag_u coef;
    {
      float cf[4];
#pragma unroll
      for (int jj = 0; jj < 4; ++jj) {
        const int j = 4 * g16 + jj;
        cf[jj] = (j <= n) ? -tok_n * etaj[jj] * (1.0f + st_[jj]) : 0.0f;
      }
      coef.u32[0] = pack_bf16(cf[0], cf[1]);
      coef.u32[1] = pack_bf16(cf[2], cf[3]);
      coef.u32[2] = 0; coef.u32[3] = 0;
    }
    f32x4 zbv[4];
#pragma unroll
    for (int eb = 0; eb < 4; ++eb)
      zbv[eb] = mfma16(coef.v, gbf[eb].v, zq[eb]);

#pragma unroll
    for (int r = 0; r < 4; ++r) {
      s1[r] = zbv[0][r] + zbv[1][r] + zbv[2][r] + zbv[3][r];
      s2[r] = zbv[0][r] * zbv[0][r] + zbv[1][r] * zbv[1][r] + zbv[2][r] * zbv[2][r] + zbv[3][r] * zbv[3][r];
    }
#pragma unroll
    for (int r = 0; r < 4; ++r) { s1[r] = rsum16(s1[r]); s2[r] = rsum16(s2[r]); }
#pragma unroll
    for (int r = 0; r < 4; ++r) {
      mr[r] = s1[r] * inv64;
      rstd[r] = rsqrtf(s2[r] * inv64 - mr[r] * mr[r] + 1e-5f);
    }
#pragma unroll
    for (int eb = 0; eb < 4; ++eb)
#pragma unroll
      for (int r = 0; r < 4; ++r) {
        const float o = qcf[eb][r] + (zbv[eb][r] - mr[r]) * rstd[r] * tnsr[eb] + tnbr[eb];
        Zb[sb + offC[eb][r]] = bf16hi(o);
      }

    float lgv[4][4];
    frag_u lgf[4];
#pragma unroll
    for (int eb = 0; eb < 4; ++eb) {
#pragma unroll
      for (int jj = 0; jj < 4; ++jj) lgv[eb][jj] = -tok15 * etaj[jj] * g_[eb][jj];
      lgf[eb].u32[0] = pack_bf16(lgv[eb][0], lgv[eb][1]);
      lgf[eb].u32[1] = pack_bf16(lgv[eb][2], lgv[eb][3]);
      lgf[eb].u32[2] = 0; lgf[eb].u32[3] = 0;
    }
#pragma unroll
    for (int mk = 0; mk < 4; ++mk)
#pragma unroll
      for (int eb = 0; eb < 4; ++eb)
        W1acc[mk][eb] = mfma16(ktf[mk].v, lgf[eb].v, W1acc[mk][eb]);
    // b1 update: token-sum of lgf via ones-A MFMA (every output row identical).
#pragma unroll
    for (int eb = 0; eb < 4; ++eb) {
      f32x4 bs = mfma16(onesA.v, lgf[eb].v, z4);
      b1r[eb] += bs[0];
    }
  };

  ScanBuf Abuf, Bbuf;
  load_mb(Abuf, 0);
  for (int mb = 0; mb < NMB; mb += 2) {
    load_mb(Bbuf, mb + 1);
    compute_mb(Abuf, mb);
    if (mb + 2 < NMB) load_mb(Abuf, mb + 2);
    compute_mb(Bbuf, mb + 1);
  }
  __builtin_amdgcn_s_setprio(0);
}

// ---------------- K5: fused per-token LN stats + epilogue ----------------
// aout = ((Z - mu) * rstd * pns + pnb) * gate, one pass over Z.
__global__ __launch_bounds__(256) void stats_epi_kernel(
    const unsigned short* __restrict__ Zb, const unsigned short* __restrict__ gateb,
    const float* __restrict__ pns, const float* __restrict__ pnb,
    unsigned short* __restrict__ aout) {
  const int g = threadIdx.x >> 6, l = threadIdx.x & 63;
  const int t = blockIdx.x * 4 + g;
  const size_t base = (size_t)t * HIDDEN;
  // each lane: 3 x uint2 loads = 12 bf16, cols l*4 + 256*j
  uint2 z2[3];
  float zv[12];
  float s_ = 0.f;
#pragma unroll
  for (int j = 0; j < 3; ++j) {
    const int c = l * 4 + 256 * j;
    z2[j] = *(const uint2*)(Zb + base + c);
    zv[4 * j + 0] = bf2f((unsigned short)(z2[j].x & 0xffff));
    zv[4 * j + 1] = bf2f((unsigned short)(z2[j].x >> 16));
    zv[4 * j + 2] = bf2f((unsigned short)(z2[j].y & 0xffff));
    zv[4 * j + 3] = bf2f((unsigned short)(z2[j].y >> 16));
    s_ += zv[4 * j] + zv[4 * j + 1] + zv[4 * j + 2] + zv[4 * j + 3];
  }
  s_ = wave_sum(s_);
  const float m = s_ * (1.0f / 768.0f);
  float v_ = 0.f;
#pragma unroll
  for (int k = 0; k < 12; ++k) { const float d = zv[k] - m; v_ += d * d; }
  v_ = wave_sum(v_) * (1.0f / 768.0f);
  const float rstd = rsqrtf(v_ + 1e-5f);
#pragma unroll
  for (int j = 0; j < 3; ++j) {
    const int c = l * 4 + 256 * j;
    const uint2 g2 = *(const uint2*)(gateb + base + c);
    const float4 p4 = *(const float4*)(pns + c);
    const float4 q4 = *(const float4*)(pnb + c);
    const float o0 = ((zv[4 * j + 0] - m) * rstd * p4.x + q4.x) * bf2f((unsigned short)(g2.x & 0xffff));
    const float o1 = ((zv[4 * j + 1] - m) * rstd * p4.y + q4.y) * bf2f((unsigned short)(g2.x >> 16));
    const float o2 = ((zv[4 * j + 2] - m) * rstd * p4.z + q4.z) * bf2f((unsigned short)(g2.y & 0xffff));
    const float o3 = ((zv[4 * j + 3] - m) * rstd * p4.w + q4.w) * bf2f((unsigned short)(g2.y >> 16));
    uint2 r; r.x = pack_bf16(o0, o1); r.y = pack_bf16(o2, o3);
    *(uint2*)(aout + base + c) = r;
  }
}

// ---------------- launch ----------------
extern "C" void kernel_launch(void* const* d_in, const int* in_sizes, int n_in,
                              void* d_out, int out_size, void* d_ws, size_t ws_size,
                              hipStream_t stream) {
  const float* x   = (const float*)d_in[0];
  const float* wq  = (const float*)d_in[1];
  const float* wv  = (const float*)d_in[2];
  const float* wo  = (const float*)d_in[3];
  const float* wg  = (const float*)d_in[4];
  const float* cqw = (const float*)d_in[5];
  const float* cqb = (const float*)d_in[6];
  const float* ckw = (const float*)d_in[7];
  const float* ckb = (const float*)d_in[8];
  const float* lrw = (const float*)d_in[9];
  const float* lrb = (const float*)d_in[10];
  const float* lti = (const float*)d_in[11];
  const float* tns = (const float*)d_in[12];
  const float* tnb = (const float*)d_in[13];
  const float* pns = (const float*)d_in[14];
  const float* pnb = (const float*)d_in[15];
  const float* W1g = (const float*)d_in[16];
  const float* b1g = (const float*)d_in[17];
  float* out = (float*)d_out;

  // ws layout (bf16 slots, with aliasing): total ~309 MB
  // slot0: xb (input to GEMMs, incl. the in-fused gate GEMM) / aout (post-epi)
  // slot1: xqk (conv input, dead after convrope) / Z (scan output)
  unsigned short* zbuf = (unsigned short*)d_ws;
  unsigned short* xqk  = zbuf + NELT;
  unsigned short* xv   = xqk + NELT;
  unsigned short* gate = xv + NELT;
  unsigned short* xq   = gate + NELT;
  unsigned short* xk   = xq + NELT;
  unsigned short* wqT  = xk + NELT;
  unsigned short* wvT  = wqT + WELT;
  unsigned short* wgT  = wvT + WELT;
  unsigned short* woT  = wgT + WELT;
  float* lrpre = (float*)(woT + WELT);
  unsigned short* xb   = zbuf;   // slot0 pre-scan
  unsigned short* zOut = xqk;    // slot1 post-convrope
  unsigned short* aout = zbuf;   // slot0 post-scan

  cvtx_lrpre_kernel<<<(unsigned)(NTOK / 4), 256, 0, stream>>>(x, lrw, lrb, xb, lrpre);
  const dim3 wtGrid(24, 24, 4);
  cvt_wT4_kernel<<<wtGrid, 256, 0, stream>>>(wq, wv, wg, wo, wqT, wvT, wgT, woT);

  const dim3 dualGrid((unsigned)(NTOK / 128), HIDDEN / 128, 2);
  gemm_dual<<<dualGrid, 256, 0, stream>>>(xb, wqT, wvT, xqk, xv);
  convrope_kernel<<<(unsigned)(NTOK * 384 / 256), 256, 0, stream>>>(
      (const __hip_bfloat16*)xqk, cqw, cqb, ckw, ckb,
      (__hip_bfloat16*)xq, (__hip_bfloat16*)xk);
  fused_scan_gate<<<48 + 1536, 256, 0, stream>>>(
      (const __hip_bfloat16*)xq, (const __hip_bfloat16*)xk,
      (const __hip_bfloat16*)xv, lrpre, lti, tns, tnb, W1g, b1g,
      (__hip_bfloat16*)zOut, xb, wgT, gate);
  stats_epi_kernel<<<(unsigned)(NTOK / 4), 256, 0, stream>>>(zOut, gate, pns, pnb, aout);
  const dim3 gemmGrid((unsigned)(NTOK / 128), HIDDEN / 128);
  gemm_mfma<<<gemmGrid, 256, 0, stream>>>(aout, woT, (void*)out, 2);
}

// Round 15
// 1712.441 us; speedup vs baseline: 2.1267x; 1.0009x over previous
//
#include <hip/hip_runtime.h>
#include <hip/hip_bf16.h>
#include <math.h>

// Problem constants
#define BB 4
#define SSEQ 8192
#define HIDDEN 768
#define NH 12
#define DDIM 64
#define KMB 16
#define NMB 512
#define NTOK ((size_t)BB * SSEQ)          // 32768
#define NELT (NTOK * HIDDEN)              // 25,165,824
#define WELT (768 * 768)

typedef short bf16x8 __attribute__((ext_vector_type(8)));
typedef float f32x4 __attribute__((ext_vector_type(4)));

union frag_u {
  bf16x8 v;
  unsigned u32[4];
  unsigned short u16[8];
};

__device__ __forceinline__ f32x4 mfma16(bf16x8 a, bf16x8 b, f32x4 c) {
  return __builtin_amdgcn_mfma_f32_16x16x32_bf16(a, b, c, 0, 0, 0);
}

// ---------------- helpers ----------------
__device__ __forceinline__ float wave_sum(float v) {
#pragma unroll
  for (int off = 32; off > 0; off >>= 1) v += __shfl_xor(v, off, 64);
  return v;
}

// DPP row_ror fold-add: v += rotate_within_row16(v, N). VALU-only cross-lane.
template <int CTRL>
__device__ __forceinline__ float dpp_add(float v) {
  union { float f; int i; } a, b;
  a.f = v;
  b.i = __builtin_amdgcn_update_dpp(0, a.i, CTRL, 0xF, 0xF, true);
  return v + b.f;
}
// full sum across each row of 16 lanes; every lane gets the total.
__device__ __forceinline__ float rsum16(float v) {
  v = dpp_add<0x121>(v);  // row_ror:1
  v = dpp_add<0x122>(v);  // row_ror:2
  v = dpp_add<0x124>(v);  // row_ror:4
  v = dpp_add<0x128>(v);  // row_ror:8
  return v;
}

// round-half-up bf16 (ties differ from RNE only on exact .5 ulp; negligible)
__device__ __forceinline__ unsigned short bf16hi(float x) {
  union { float f; unsigned u; } a; a.f = x;
  return (unsigned short)((a.u + 0x8000u) >> 16);
}
// pack two floats -> (bf16(f1)<<16)|bf16(f0) in 3 VALU ops via v_perm_b32
__device__ __forceinline__ unsigned pack_bf16(float f0, float f1) {
  union { float f; unsigned u; } a, b; a.f = f0; b.f = f1;
  return __builtin_amdgcn_perm(b.u + 0x8000u, a.u + 0x8000u, 0x07060302u);
}
__device__ __forceinline__ float bf2f(unsigned short s) {
  union { unsigned u; float f; } a; a.u = ((unsigned)s) << 16; return a.f;
}
__device__ __forceinline__ float gelu_tanh(float x) {
  float x3 = x * x * x;
  return 0.5f * x * (1.0f + tanhf(0.7978845608028654f * (x + 0.044715f * x3)));
}

__device__ __forceinline__ void glds16(const void* g, void* l) {
  __builtin_amdgcn_global_load_lds(
      (const __attribute__((address_space(1))) void*)g,
      (__attribute__((address_space(3))) void*)l, 16, 0, 0);
}

// ---------------- K0a: fused x->xb (bf16) + lrpre ----------------
// One pass over x (f32): emits bf16 xb AND lrpre[b,h,s] = x.lr_w[h] + lr_b[h].
// Wave g owns token t = blockIdx*4+g; lane l owns cols l+64j, j=0..11.
__global__ __launch_bounds__(256) void cvtx_lrpre_kernel(
    const float* __restrict__ x, const float* __restrict__ lrw,
    const float* __restrict__ lrb, unsigned short* __restrict__ xb,
    float* __restrict__ lrpre) {
  const int g = threadIdx.x >> 6, l = threadIdx.x & 63;
  const int t = blockIdx.x * 4 + g;
  const float* xr = x + (size_t)t * HIDDEN;
  unsigned short* xw = xb + (size_t)t * HIDDEN;
  float xv[12];
#pragma unroll
  for (int j = 0; j < 12; ++j) xv[j] = xr[l + 64 * j];
#pragma unroll
  for (int j = 0; j < 12; ++j) xw[l + 64 * j] = bf16hi(xv[j]);
  const int b = t >> 13, s = t & (SSEQ - 1);
  for (int h = 0; h < NH; ++h) {
    const float* wr = lrw + (size_t)h * HIDDEN;
    float a = 0.f;
#pragma unroll
    for (int j = 0; j < 12; ++j) a += xv[j] * wr[l + 64 * j];
    a = wave_sum(a);
    if (l == 0) lrpre[((size_t)b * NH + h) * SSEQ + s] = a + lrb[h];
  }
}

// ---------------- K0b: 4x W (768x768 f32) -> W^T (bf16), one dispatch --------
__global__ __launch_bounds__(256) void cvt_wT4_kernel(
    const float* __restrict__ W0, const float* __restrict__ W1,
    const float* __restrict__ W2, const float* __restrict__ W3,
    unsigned short* __restrict__ D0, unsigned short* __restrict__ D1,
    unsigned short* __restrict__ D2, unsigned short* __restrict__ D3) {
  const float* W; unsigned short* WT;
  if (blockIdx.z == 0)      { W = W0; WT = D0; }
  else if (blockIdx.z == 1) { W = W1; WT = D1; }
  else if (blockIdx.z == 2) { W = W2; WT = D2; }
  else                      { W = W3; WT = D3; }
  __shared__ float tile[32][33];
  const int tx = threadIdx.x & 31, ty = threadIdx.x >> 5;  // ty 0..7
  const int k0 = blockIdx.x * 32, n0 = blockIdx.y * 32;
#pragma unroll
  for (int r = 0; r < 4; ++r)
    tile[ty + 8 * r][tx] = W[(size_t)(k0 + ty + 8 * r) * 768 + n0 + tx];
  __syncthreads();
#pragma unroll
  for (int r = 0; r < 4; ++r)
    WT[(size_t)(n0 + ty + 8 * r) * 768 + k0 + tx] = bf16hi(tile[tx][ty + 8 * r]);
}

// ---------------- K0c: RoPE cos/sin table  tab[t][f] = (cos,sin)(t*invf) ------
__global__ __launch_bounds__(256) void ropetab_kernel(float2* __restrict__ tab) {
  const int idx = blockIdx.x * 256 + threadIdx.x;   // over SSEQ*32
  const int t = idx >> 5, f = idx & 31;
  const float invf = expf(-(float)f * 0.28782313662425572f);  // ln(10000)/32
  float sn, cs;
  sincosf((float)t * invf, &sn, &cs);
  tab[idx] = make_float2(cs, sn);
}

// ---------------- K1: MFMA GEMM  C[M,768] = A[M,768] @ BT[768,768]^T ------------
// m97 structure: 128x128 tile, BK=32, 256 thr (4 waves 2x2), global_load_lds w16.
// mode: 0 = bf16 out, 1 = bf16+gelu out, 2 = f32 out
__global__ __launch_bounds__(256) void gemm_mfma(
    const unsigned short* __restrict__ A, const unsigned short* __restrict__ BT,
    void* __restrict__ Cout, int mode) {
  __shared__ __align__(16) unsigned short Asl[128 * 32];
  __shared__ __align__(16) unsigned short Bsl[128 * 32];
  const int tid = threadIdx.x;
  const int wave = tid >> 6, lane = tid & 63;
  const int n16 = lane & 15, g16 = lane >> 4;
  const int wm = (wave >> 1) * 64, wn = (wave & 1) * 64;
  const int m0 = blockIdx.x * 128, n0 = blockIdx.y * 128;

  const int srow = tid >> 2;            // 0..63
  const int sseg = (tid & 3) * 8;       // k-element offset

  const unsigned short* aSrc0 = A + (size_t)(m0 + srow) * 768 + sseg;
  const unsigned short* aSrc1 = A + (size_t)(m0 + 64 + srow) * 768 + sseg;
  const unsigned short* bSrc0 = BT + (size_t)(n0 + srow) * 768 + sseg;
  const unsigned short* bSrc1 = BT + (size_t)(n0 + 64 + srow) * 768 + sseg;
  char* aDst0 = (char*)Asl + wave * 1024;
  char* aDst1 = (char*)Asl + 4096 + wave * 1024;
  char* bDst0 = (char*)Bsl + wave * 1024;
  char* bDst1 = (char*)Bsl + 4096 + wave * 1024;

  f32x4 acc[4][4];
#pragma unroll
  for (int i = 0; i < 4; ++i)
#pragma unroll
    for (int j = 0; j < 4; ++j) { acc[i][j][0] = 0.f; acc[i][j][1] = 0.f; acc[i][j][2] = 0.f; acc[i][j][3] = 0.f; }

  for (int k0 = 0; k0 < 768; k0 += 32) {
    __syncthreads();
    glds16(aSrc0 + k0, aDst0);
    glds16(aSrc1 + k0, aDst1);
    glds16(bSrc0 + k0, bDst0);
    glds16(bSrc1 + k0, bDst1);
    __syncthreads();
    bf16x8 af[4], bfr[4];
#pragma unroll
    for (int mf = 0; mf < 4; ++mf)
      af[mf] = *(const bf16x8*)(Asl + (wm + mf * 16 + n16) * 32 + g16 * 8);
#pragma unroll
    for (int nf = 0; nf < 4; ++nf)
      bfr[nf] = *(const bf16x8*)(Bsl + (wn + nf * 16 + n16) * 32 + g16 * 8);
#pragma unroll
    for (int mf = 0; mf < 4; ++mf)
#pragma unroll
      for (int nf = 0; nf < 4; ++nf)
        acc[mf][nf] = mfma16(af[mf], bfr[nf], acc[mf][nf]);
  }

  const int erow0 = m0 + wm + 4 * g16;
  const int ecol0 = n0 + wn + n16;
  if (mode == 2) {
    float* C = (float*)Cout;
#pragma unroll
    for (int mf = 0; mf < 4; ++mf)
#pragma unroll
      for (int nf = 0; nf < 4; ++nf)
#pragma unroll
        for (int r = 0; r < 4; ++r)
          C[(size_t)(erow0 + mf * 16 + r) * HIDDEN + ecol0 + nf * 16] = acc[mf][nf][r];
  } else if (mode == 1) {
    unsigned short* C = (unsigned short*)Cout;
#pragma unroll
    for (int mf = 0; mf < 4; ++mf)
#pragma unroll
      for (int nf = 0; nf < 4; ++nf)
#pragma unroll
        for (int r = 0; r < 4; ++r)
          C[(size_t)(erow0 + mf * 16 + r) * HIDDEN + ecol0 + nf * 16] = bf16hi(gelu_tanh(acc[mf][nf][r]));
  } else {
    unsigned short* C = (unsigned short*)Cout;
#pragma unroll
    for (int mf = 0; mf < 4; ++mf)
#pragma unroll
      for (int nf = 0; nf < 4; ++nf)
#pragma unroll
        for (int r = 0; r < 4; ++r)
          C[(size_t)(erow0 + mf * 16 + r) * HIDDEN + ecol0 + nf * 16] = bf16hi(acc[mf][nf][r]);
  }
}

// ---------------- K1b: dual GEMM (xqk + xv in one dispatch, z selects) --------
__global__ __launch_bounds__(256) void gemm_dual(
    const unsigned short* __restrict__ A,
    const unsigned short* __restrict__ BT0, const unsigned short* __restrict__ BT1,
    unsigned short* __restrict__ C0, unsigned short* __restrict__ C1) {
  const unsigned short* BT; unsigned short* C;
  if (blockIdx.z == 0) { BT = BT0; C = C0; } else { BT = BT1; C = C1; }
  __shared__ __align__(16) unsigned short Asl[128 * 32];
  __shared__ __align__(16) unsigned short Bsl[128 * 32];
  const int tid = threadIdx.x;
  const int wave = tid >> 6, lane = tid & 63;
  const int n16 = lane & 15, g16 = lane >> 4;
  const int wm = (wave >> 1) * 64, wn = (wave & 1) * 64;
  const int m0 = blockIdx.x * 128, n0 = blockIdx.y * 128;

  const int srow = tid >> 2;
  const int sseg = (tid & 3) * 8;

  const unsigned short* aSrc0 = A + (size_t)(m0 + srow) * 768 + sseg;
  const unsigned short* aSrc1 = A + (size_t)(m0 + 64 + srow) * 768 + sseg;
  const unsigned short* bSrc0 = BT + (size_t)(n0 + srow) * 768 + sseg;
  const unsigned short* bSrc1 = BT + (size_t)(n0 + 64 + srow) * 768 + sseg;
  char* aDst0 = (char*)Asl + wave * 1024;
  char* aDst1 = (char*)Asl + 4096 + wave * 1024;
  char* bDst0 = (char*)Bsl + wave * 1024;
  char* bDst1 = (char*)Bsl + 4096 + wave * 1024;

  f32x4 acc[4][4];
#pragma unroll
  for (int i = 0; i < 4; ++i)
#pragma unroll
    for (int j = 0; j < 4; ++j) { acc[i][j][0] = 0.f; acc[i][j][1] = 0.f; acc[i][j][2] = 0.f; acc[i][j][3] = 0.f; }

  for (int k0 = 0; k0 < 768; k0 += 32) {
    __syncthreads();
    glds16(aSrc0 + k0, aDst0);
    glds16(aSrc1 + k0, aDst1);
    glds16(bSrc0 + k0, bDst0);
    glds16(bSrc1 + k0, bDst1);
    __syncthreads();
    bf16x8 af[4], bfr[4];
#pragma unroll
    for (int mf = 0; mf < 4; ++mf)
      af[mf] = *(const bf16x8*)(Asl + (wm + mf * 16 + n16) * 32 + g16 * 8);
#pragma unroll
    for (int nf = 0; nf < 4; ++nf)
      bfr[nf] = *(const bf16x8*)(Bsl + (wn + nf * 16 + n16) * 32 + g16 * 8);
#pragma unroll
    for (int mf = 0; mf < 4; ++mf)
#pragma unroll
      for (int nf = 0; nf < 4; ++nf)
        acc[mf][nf] = mfma16(af[mf], bfr[nf], acc[mf][nf]);
  }

  const int erow0 = m0 + wm + 4 * g16;
  const int ecol0 = n0 + wn + n16;
#pragma unroll
  for (int mf = 0; mf < 4; ++mf)
#pragma unroll
    for (int nf = 0; nf < 4; ++nf)
#pragma unroll
      for (int r = 0; r < 4; ++r)
        C[(size_t)(erow0 + mf * 16 + r) * HIDDEN + ecol0 + nf * 16] = bf16hi(acc[mf][nf][r]);
}

// ---------------- K3: conv (causal) + RoPE (table + vectorized taps) ----------
__global__ __launch_bounds__(256) void convrope_kernel(
    const unsigned short* __restrict__ xqk,
    const float* __restrict__ cqw, const float* __restrict__ cqb,
    const float* __restrict__ ckw, const float* __restrict__ ckb,
    const float2* __restrict__ tab,
    __hip_bfloat16* __restrict__ XQ, __hip_bfloat16* __restrict__ XK) {
  const size_t gid = (size_t)blockIdx.x * 256 + threadIdx.x;  // over NTOK*384
  const int p = (int)(gid % 384);
  const size_t bt = gid / 384;
  const int t = (int)(bt & (SSEQ - 1));
  const int c0 = 2 * p, c1 = c0 + 1;
  const float2 qb2 = *(const float2*)(cqb + c0);
  const float2 kb2 = *(const float2*)(ckb + c0);
  float q0 = qb2.x, q1 = qb2.y, k0v = kb2.x, k1v = kb2.y;
#pragma unroll
  for (int kk = 0; kk < 4; ++kk) {
    const int tp = t - 4 + kk;
    if (tp >= 0) {
      const unsigned xp = *(const unsigned*)(xqk + (bt - t + tp) * HIDDEN + c0);
      const float x0 = bf2f((unsigned short)(xp & 0xffff));
      const float x1 = bf2f((unsigned short)(xp >> 16));
      const float2 qw2 = *(const float2*)(cqw + kk * HIDDEN + c0);
      const float2 kw2 = *(const float2*)(ckw + kk * HIDDEN + c0);
      q0  += qw2.x * x0;  q1  += qw2.y * x1;
      k0v += kw2.x * x0;  k1v += kw2.y * x1;
    }
  }
  const float2 cssn = tab[t * 32 + (p & 31)];
  const float cs = cssn.x, sn = cssn.y;
  const size_t o = bt * HIDDEN;
  XQ[o + c0] = __float2bfloat16(q0 * cs - q1 * sn);
  XQ[o + c1] = __float2bfloat16(q0 * sn + q1 * cs);
  XK[o + c0] = __float2bfloat16(k0v * cs - k1v * sn);
  XK[o + c1] = __float2bfloat16(k0v * sn + k1v * cs);
}

// ---------------- K4: FUSED scan (blocks 0..47) + gate GEMM (blocks 48..1583) ----
// R13 verified: 1216us fused, total 1780us, absmax .03125. Unchanged.
struct ScanBuf {
  uint2 qa[2][2], ka[2][2], va[2][2];
  float lr[4];
};

__global__ __launch_bounds__(256) void fused_scan_gate(
    const __hip_bfloat16* __restrict__ XQg, const __hip_bfloat16* __restrict__ XKg,
    const __hip_bfloat16* __restrict__ XVg, const float* __restrict__ lrpre,
    const float* __restrict__ lti, const float* __restrict__ tnsg,
    const float* __restrict__ tnbg, const float* __restrict__ W1g,
    const float* __restrict__ b1g, __hip_bfloat16* __restrict__ Zg,
    const unsigned short* __restrict__ A, const unsigned short* __restrict__ BT,
    unsigned short* __restrict__ Cgate) {
  if (blockIdx.x >= 48) {
    // ---------------- gate GEMM body (m97 structure, gelu epilogue) ----------
    __shared__ __align__(16) unsigned short Asl[128 * 32];
    __shared__ __align__(16) unsigned short Bsl[128 * 32];
    const int bid = blockIdx.x - 48;          // 0..1535
    const int tid = threadIdx.x;
    const int wave = tid >> 6, lane = tid & 63;
    const int n16 = lane & 15, g16 = lane >> 4;
    const int wm = (wave >> 1) * 64, wn = (wave & 1) * 64;
    const int m0 = (bid & 255) * 128, n0 = (bid >> 8) * 128;

    const int srow = tid >> 2;
    const int sseg = (tid & 3) * 8;

    const unsigned short* aSrc0 = A + (size_t)(m0 + srow) * 768 + sseg;
    const unsigned short* aSrc1 = A + (size_t)(m0 + 64 + srow) * 768 + sseg;
    const unsigned short* bSrc0 = BT + (size_t)(n0 + srow) * 768 + sseg;
    const unsigned short* bSrc1 = BT + (size_t)(n0 + 64 + srow) * 768 + sseg;
    char* aDst0 = (char*)Asl + wave * 1024;
    char* aDst1 = (char*)Asl + 4096 + wave * 1024;
    char* bDst0 = (char*)Bsl + wave * 1024;
    char* bDst1 = (char*)Bsl + 4096 + wave * 1024;

    f32x4 acc[4][4];
#pragma unroll
    for (int i = 0; i < 4; ++i)
#pragma unroll
      for (int j = 0; j < 4; ++j) { acc[i][j][0] = 0.f; acc[i][j][1] = 0.f; acc[i][j][2] = 0.f; acc[i][j][3] = 0.f; }

    for (int k0 = 0; k0 < 768; k0 += 32) {
      __syncthreads();
      glds16(aSrc0 + k0, aDst0);
      glds16(aSrc1 + k0, aDst1);
      glds16(bSrc0 + k0, bDst0);
      glds16(bSrc1 + k0, bDst1);
      __syncthreads();
      bf16x8 af[4], bfr[4];
#pragma unroll
      for (int mf = 0; mf < 4; ++mf)
        af[mf] = *(const bf16x8*)(Asl + (wm + mf * 16 + n16) * 32 + g16 * 8);
#pragma unroll
      for (int nf = 0; nf < 4; ++nf)
        bfr[nf] = *(const bf16x8*)(Bsl + (wn + nf * 16 + n16) * 32 + g16 * 8);
#pragma unroll
      for (int mf = 0; mf < 4; ++mf)
#pragma unroll
        for (int nf = 0; nf < 4; ++nf)
          acc[mf][nf] = mfma16(af[mf], bfr[nf], acc[mf][nf]);
    }

    const int erow0 = m0 + wm + 4 * g16;
    const int ecol0 = n0 + wn + n16;
#pragma unroll
    for (int mf = 0; mf < 4; ++mf)
#pragma unroll
      for (int nf = 0; nf < 4; ++nf)
#pragma unroll
        for (int r = 0; r < 4; ++r)
          Cgate[(size_t)(erow0 + mf * 16 + r) * HIDDEN + ecol0 + nf * 16] = bf16hi(gelu_tanh(acc[mf][nf][r]));
    return;
  }

  // ---------------- scan body (R6, 1 wave; threads >= 64 exit) --------------
  if (threadIdx.x >= 64) return;
  __builtin_amdgcn_s_setprio(1);

  const int bh = blockIdx.x;
  const int b = bh / NH, h = bh % NH;
  const int lane = threadIdx.x;
  const int n = lane & 15, g16 = lane >> 4;
  const float inv64 = 1.0f / 64.0f;

  const unsigned short* XQb = (const unsigned short*)XQg + (size_t)b * SSEQ * HIDDEN + h * 64;
  const unsigned short* XKb = (const unsigned short*)XKg + (size_t)b * SSEQ * HIDDEN + h * 64;
  const unsigned short* XVb = (const unsigned short*)XVg + (size_t)b * SSEQ * HIDDEN + h * 64;
  unsigned short* Zb = (unsigned short*)Zg + (size_t)b * SSEQ * HIDDEN + h * 64;
  const float* lrp = lrpre + ((size_t)b * NH + h) * SSEQ;

  f32x4 W1acc[4][4];
#pragma unroll
  for (int db = 0; db < 4; ++db)
#pragma unroll
    for (int eb = 0; eb < 4; ++eb)
#pragma unroll
      for (int r = 0; r < 4; ++r)
        W1acc[db][eb][r] = W1g[(size_t)h * 4096 + (16 * db + 4 * g16 + r) * 64 + 16 * eb + n];

  float b1r[4], tnsr[4], tnbr[4];
#pragma unroll
  for (int eb = 0; eb < 4; ++eb) {
    const int e = h * 64 + 16 * eb + n;
    b1r[eb] = b1g[e]; tnsr[eb] = tnsg[e]; tnbr[eb] = tnbg[e];
  }
  const float tok_n = fmaxf(1.0f / (float)(n + 1) + lti[n], 0.0f);
  const float tok15 = __shfl(tok_n, 15, 64);

  // identity B-frags for the A-layout -> C-layout transpose MFMAs (see R4/R5).
  frag_u id0, id1;
  {
    const unsigned short onebf = (g16 == (n >> 2)) ? (unsigned short)0x3F80 : (unsigned short)0;
    const unsigned vsh = ((unsigned)onebf) << (16 * (n & 1));
    const unsigned lo = ((n & 2) == 0) ? vsh : 0u;
    const unsigned hi = ((n & 2) != 0) ? vsh : 0u;
    id0.u32[0] = lo; id0.u32[1] = hi; id0.u32[2] = 0; id0.u32[3] = 0;
    id1.u32[0] = 0;  id1.u32[1] = 0;  id1.u32[2] = lo; id1.u32[3] = hi;
  }
  frag_u onesA;
  onesA.u32[0] = 0x3F803F80u; onesA.u32[1] = 0x3F803F80u;
  onesA.u32[2] = 0x3F803F80u; onesA.u32[3] = 0x3F803F80u;

  int offA[2][2], offC[4][4];
#pragma unroll
  for (int c = 0; c < 2; ++c)
#pragma unroll
    for (int jg = 0; jg < 2; ++jg)
      offA[c][jg] = n * HIDDEN + 16 * (2 * c + jg) + 4 * g16;
#pragma unroll
  for (int blk = 0; blk < 4; ++blk)
#pragma unroll
    for (int r = 0; r < 4; ++r)
      offC[blk][r] = (4 * g16 + r) * HIDDEN + 16 * blk + n;

  auto load_mb = [&](ScanBuf& bf, int mb) {
    const size_t sb = (size_t)mb * (KMB * HIDDEN);
#pragma unroll
    for (int c = 0; c < 2; ++c)
#pragma unroll
      for (int jg = 0; jg < 2; ++jg) {
        bf.qa[c][jg] = *(const uint2*)(XQb + sb + offA[c][jg]);
        bf.ka[c][jg] = *(const uint2*)(XKb + sb + offA[c][jg]);
        bf.va[c][jg] = *(const uint2*)(XVb + sb + offA[c][jg]);
      }
    const float4 l4 = *(const float4*)(lrp + mb * KMB + 4 * g16);
    bf.lr[0] = l4.x; bf.lr[1] = l4.y; bf.lr[2] = l4.z; bf.lr[3] = l4.w;
  };

  auto compute_mb = [&](ScanBuf& bf, int mb) {
    const size_t sb = (size_t)mb * (KMB * HIDDEN);
    float etaj[4];
#pragma unroll
    for (int jj = 0; jj < 4; ++jj)
      etaj[jj] = 1.0f / (64.0f * (1.0f + __expf(-bf.lr[jj])));

    // W1 -> bf16 B-frags via packed perm cvt
    frag_u w1f[2][4];
#pragma unroll
    for (int c = 0; c < 2; ++c)
#pragma unroll
      for (int eb = 0; eb < 4; ++eb) {
        w1f[c][eb].u32[0] = pack_bf16(W1acc[2 * c][eb][0], W1acc[2 * c][eb][1]);
        w1f[c][eb].u32[1] = pack_bf16(W1acc[2 * c][eb][2], W1acc[2 * c][eb][3]);
        w1f[c][eb].u32[2] = pack_bf16(W1acc[2 * c + 1][eb][0], W1acc[2 * c + 1][eb][1]);
        w1f[c][eb].u32[3] = pack_bf16(W1acc[2 * c + 1][eb][2], W1acc[2 * c + 1][eb][3]);
      }
    frag_u kaf[2], qaf[2], vaf[2];
#pragma unroll
    for (int c = 0; c < 2; ++c) {
      kaf[c].u32[0] = bf.ka[c][0].x; kaf[c].u32[1] = bf.ka[c][0].y;
      kaf[c].u32[2] = bf.ka[c][1].x; kaf[c].u32[3] = bf.ka[c][1].y;
      qaf[c].u32[0] = bf.qa[c][0].x; qaf[c].u32[1] = bf.qa[c][0].y;
      qaf[c].u32[2] = bf.qa[c][1].x; qaf[c].u32[3] = bf.qa[c][1].y;
      vaf[c].u32[0] = bf.va[c][0].x; vaf[c].u32[1] = bf.va[c][0].y;
      vaf[c].u32[2] = bf.va[c][1].x; vaf[c].u32[3] = bf.va[c][1].y;
    }

    // A-layout -> C-layout transposes (exact).
    f32x4 z4; z4[0] = 0.f; z4[1] = 0.f; z4[2] = 0.f; z4[3] = 0.f;
    f32x4 qcf[4], kcf[4], vcf[4];
#pragma unroll
    for (int c = 0; c < 2; ++c) {
      qcf[2 * c]     = mfma16(qaf[c].v, id0.v, z4);
      qcf[2 * c + 1] = mfma16(qaf[c].v, id1.v, z4);
      kcf[2 * c]     = mfma16(kaf[c].v, id0.v, z4);
      kcf[2 * c + 1] = mfma16(kaf[c].v, id1.v, z4);
      vcf[2 * c]     = mfma16(vaf[c].v, id0.v, z4);
      vcf[2 * c + 1] = mfma16(vaf[c].v, id1.v, z4);
    }
    // ktf: K^T A-frags for the W1 update (exact repack of bf16 values).
    frag_u ktf[4];
#pragma unroll
    for (int mk = 0; mk < 4; ++mk) {
      ktf[mk].u32[0] = pack_bf16(kcf[mk][0], kcf[mk][1]);
      ktf[mk].u32[1] = pack_bf16(kcf[mk][2], kcf[mk][3]);
      ktf[mk].u32[2] = 0; ktf[mk].u32[3] = 0;
    }

    f32x4 zk[4], zq[4];
#pragma unroll
    for (int eb = 0; eb < 4; ++eb) {
      f32x4 init; init[0] = b1r[eb]; init[1] = b1r[eb]; init[2] = b1r[eb]; init[3] = b1r[eb];
      zk[eb] = init; zq[eb] = init;
    }
#pragma unroll
    for (int c = 0; c < 2; ++c)
#pragma unroll
      for (int eb = 0; eb < 4; ++eb) {
        zk[eb] = mfma16(kaf[c].v, w1f[c][eb].v, zk[eb]);
        zq[eb] = mfma16(qaf[c].v, w1f[c][eb].v, zq[eb]);
      }
    f32x4 st_; st_[0] = 0.f; st_[1] = 0.f; st_[2] = 0.f; st_[3] = 0.f;
    st_ = mfma16(kaf[0].v, qaf[0].v, st_);
    st_ = mfma16(kaf[1].v, qaf[1].v, st_);

    float s1[4], s2[4];
#pragma unroll
    for (int r = 0; r < 4; ++r) {
      s1[r] = zk[0][r] + zk[1][r] + zk[2][r] + zk[3][r];
      s2[r] = zk[0][r] * zk[0][r] + zk[1][r] * zk[1][r] + zk[2][r] * zk[2][r] + zk[3][r] * zk[3][r];
    }
#pragma unroll
    for (int r = 0; r < 4; ++r) { s1[r] = rsum16(s1[r]); s2[r] = rsum16(s2[r]); }
    float mr[4], rstd[4];
#pragma unroll
    for (int r = 0; r < 4; ++r) {
      mr[r] = s1[r] * inv64;
      rstd[r] = rsqrtf(s2[r] * inv64 - mr[r] * mr[r] + 1e-5f);
    }
    float xh[4][4], gx[4][4], t1[4] = {0.f, 0.f, 0.f, 0.f}, t2[4] = {0.f, 0.f, 0.f, 0.f};
#pragma unroll
    for (int eb = 0; eb < 4; ++eb)
#pragma unroll
      for (int r = 0; r < 4; ++r) {
        const float xh_ = (zk[eb][r] - mr[r]) * rstd[r];
        const float tg = vcf[eb][r] - kcf[eb][r];
        const float gx_ = (xh_ * tnsr[eb] + tnbr[eb] - tg) * tnsr[eb];
        xh[eb][r] = xh_; gx[eb][r] = gx_;
        t1[r] += gx_; t2[r] += gx_ * xh_;
      }
#pragma unroll
    for (int r = 0; r < 4; ++r) { t1[r] = rsum16(t1[r]); t2[r] = rsum16(t2[r]); }
    float g_[4][4];
#pragma unroll
    for (int eb = 0; eb < 4; ++eb)
#pragma unroll
      for (int r = 0; r < 4; ++r)
        g_[eb][r] = (gx[eb][r] - t1[r] * inv64 - xh[eb][r] * (t2[r] * inv64)) * rstd[r];

    frag_u gbf[4];
#pragma unroll
    for (int eb = 0; eb < 4; ++eb) {
      gbf[eb].u32[0] = pack_bf16(g_[eb][0], g_[eb][1]);
      gbf[eb].u32[1] = pack_bf16(g_[eb][2], g_[eb][3]);
      gbf[eb].u32[2] = 0; gbf[eb].u32[3] = 0;
    }
    frag_u coef;
    {
      float cf[4];
#pragma unroll
      for (int jj = 0; jj < 4; ++jj) {
        const int j = 4 * g16 + jj;
        cf[jj] = (j <= n) ? -tok_n * etaj[jj] * (1.0f + st_[jj]) : 0.0f;
      }
      coef.u32[0] = pack_bf16(cf[0], cf[1]);
      coef.u32[1] = pack_bf16(cf[2], cf[3]);
      coef.u32[2] = 0; coef.u32[3] = 0;
    }
    f32x4 zbv[4];
#pragma unroll
    for (int eb = 0; eb < 4; ++eb)
      zbv[eb] = mfma16(coef.v, gbf[eb].v, zq[eb]);

#pragma unroll
    for (int r = 0; r < 4; ++r) {
      s1[r] = zbv[0][r] + zbv[1][r] + zbv[2][r] + zbv[3][r];
      s2[r] = zbv[0][r] * zbv[0][r] + zbv[1][r] * zbv[1][r] + zbv[2][r] * zbv[2][r] + zbv[3][r] * zbv[3][r];
    }
#pragma unroll
    for (int r = 0; r < 4; ++r) { s1[r] = rsum16(s1[r]); s2[r] = rsum16(s2[r]); }
#pragma unroll
    for (int r = 0; r < 4; ++r) {
      mr[r] = s1[r] * inv64;
      rstd[r] = rsqrtf(s2[r] * inv64 - mr[r] * mr[r] + 1e-5f);
    }
#pragma unroll
    for (int eb = 0; eb < 4; ++eb)
#pragma unroll
      for (int r = 0; r < 4; ++r) {
        const float o = qcf[eb][r] + (zbv[eb][r] - mr[r]) * rstd[r] * tnsr[eb] + tnbr[eb];
        Zb[sb + offC[eb][r]] = bf16hi(o);
      }

    float lgv[4][4];
    frag_u lgf[4];
#pragma unroll
    for (int eb = 0; eb < 4; ++eb) {
#pragma unroll
      for (int jj = 0; jj < 4; ++jj) lgv[eb][jj] = -tok15 * etaj[jj] * g_[eb][jj];
      lgf[eb].u32[0] = pack_bf16(lgv[eb][0], lgv[eb][1]);
      lgf[eb].u32[1] = pack_bf16(lgv[eb][2], lgv[eb][3]);
      lgf[eb].u32[2] = 0; lgf[eb].u32[3] = 0;
    }
#pragma unroll
    for (int mk = 0; mk < 4; ++mk)
#pragma unroll
      for (int eb = 0; eb < 4; ++eb)
        W1acc[mk][eb] = mfma16(ktf[mk].v, lgf[eb].v, W1acc[mk][eb]);
    // b1 update: token-sum of lgf via ones-A MFMA (every output row identical).
#pragma unroll
    for (int eb = 0; eb < 4; ++eb) {
      f32x4 bs = mfma16(onesA.v, lgf[eb].v, z4);
      b1r[eb] += bs[0];
    }
  };

  ScanBuf Abuf, Bbuf;
  load_mb(Abuf, 0);
  for (int mb = 0; mb < NMB; mb += 2) {
    load_mb(Bbuf, mb + 1);
    compute_mb(Abuf, mb);
    if (mb + 2 < NMB) load_mb(Abuf, mb + 2);
    compute_mb(Bbuf, mb + 1);
  }
  __builtin_amdgcn_s_setprio(0);
}

// ---------------- K5: fused per-token LN stats + epilogue ----------------
// aout = ((Z - mu) * rstd * pns + pnb) * gate, one pass over Z.
__global__ __launch_bounds__(256) void stats_epi_kernel(
    const unsigned short* __restrict__ Zb, const unsigned short* __restrict__ gateb,
    const float* __restrict__ pns, const float* __restrict__ pnb,
    unsigned short* __restrict__ aout) {
  const int g = threadIdx.x >> 6, l = threadIdx.x & 63;
  const int t = blockIdx.x * 4 + g;
  const size_t base = (size_t)t * HIDDEN;
  // each lane: 3 x uint2 loads = 12 bf16, cols l*4 + 256*j
  uint2 z2[3];
  float zv[12];
  float s_ = 0.f;
#pragma unroll
  for (int j = 0; j < 3; ++j) {
    const int c = l * 4 + 256 * j;
    z2[j] = *(const uint2*)(Zb + base + c);
    zv[4 * j + 0] = bf2f((unsigned short)(z2[j].x & 0xffff));
    zv[4 * j + 1] = bf2f((unsigned short)(z2[j].x >> 16));
    zv[4 * j + 2] = bf2f((unsigned short)(z2[j].y & 0xffff));
    zv[4 * j + 3] = bf2f((unsigned short)(z2[j].y >> 16));
    s_ += zv[4 * j] + zv[4 * j + 1] + zv[4 * j + 2] + zv[4 * j + 3];
  }
  s_ = wave_sum(s_);
  const float m = s_ * (1.0f / 768.0f);
  float v_ = 0.f;
#pragma unroll
  for (int k = 0; k < 12; ++k) { const float d = zv[k] - m; v_ += d * d; }
  v_ = wave_sum(v_) * (1.0f / 768.0f);
  const float rstd = rsqrtf(v_ + 1e-5f);
#pragma unroll
  for (int j = 0; j < 3; ++j) {
    const int c = l * 4 + 256 * j;
    const uint2 g2 = *(const uint2*)(gateb + base + c);
    const float4 p4 = *(const float4*)(pns + c);
    const float4 q4 = *(const float4*)(pnb + c);
    const float o0 = ((zv[4 * j + 0] - m) * rstd * p4.x + q4.x) * bf2f((unsigned short)(g2.x & 0xffff));
    const float o1 = ((zv[4 * j + 1] - m) * rstd * p4.y + q4.y) * bf2f((unsigned short)(g2.x >> 16));
    const float o2 = ((zv[4 * j + 2] - m) * rstd * p4.z + q4.z) * bf2f((unsigned short)(g2.y & 0xffff));
    const float o3 = ((zv[4 * j + 3] - m) * rstd * p4.w + q4.w) * bf2f((unsigned short)(g2.y >> 16));
    uint2 r; r.x = pack_bf16(o0, o1); r.y = pack_bf16(o2, o3);
    *(uint2*)(aout + base + c) = r;
  }
}

// ---------------- launch ----------------
extern "C" void kernel_launch(void* const* d_in, const int* in_sizes, int n_in,
                              void* d_out, int out_size, void* d_ws, size_t ws_size,
                              hipStream_t stream) {
  const float* x   = (const float*)d_in[0];
  const float* wq  = (const float*)d_in[1];
  const float* wv  = (const float*)d_in[2];
  const float* wo  = (const float*)d_in[3];
  const float* wg  = (const float*)d_in[4];
  const float* cqw = (const float*)d_in[5];
  const float* cqb = (const float*)d_in[6];
  const float* ckw = (const float*)d_in[7];
  const float* ckb = (const float*)d_in[8];
  const float* lrw = (const float*)d_in[9];
  const float* lrb = (const float*)d_in[10];
  const float* lti = (const float*)d_in[11];
  const float* tns = (const float*)d_in[12];
  const float* tnb = (const float*)d_in[13];
  const float* pns = (const float*)d_in[14];
  const float* pnb = (const float*)d_in[15];
  const float* W1g = (const float*)d_in[16];
  const float* b1g = (const float*)d_in[17];
  float* out = (float*)d_out;

  // ws layout (bf16 slots, with aliasing): total ~309 MB
  // slot0: xb (input to GEMMs, incl. the in-fused gate GEMM) / aout (post-epi)
  // slot1: xqk (conv input, dead after convrope) / Z (scan output)
  unsigned short* zbuf = (unsigned short*)d_ws;
  unsigned short* xqk  = zbuf + NELT;
  unsigned short* xv   = xqk + NELT;
  unsigned short* gate = xv + NELT;
  unsigned short* xq   = gate + NELT;
  unsigned short* xk   = xq + NELT;
  unsigned short* wqT  = xk + NELT;
  unsigned short* wvT  = wqT + WELT;
  unsigned short* wgT  = wvT + WELT;
  unsigned short* woT  = wgT + WELT;
  float* lrpre = (float*)(woT + WELT);
  float* ropetab = lrpre + (size_t)BB * NH * SSEQ;   // SSEQ*32 float2 = 2MB
  unsigned short* xb   = zbuf;   // slot0 pre-scan
  unsigned short* zOut = xqk;    // slot1 post-convrope
  unsigned short* aout = zbuf;   // slot0 post-scan

  ropetab_kernel<<<(unsigned)(SSEQ * 32 / 256), 256, 0, stream>>>((float2*)ropetab);
  cvtx_lrpre_kernel<<<(unsigned)(NTOK / 4), 256, 0, stream>>>(x, lrw, lrb, xb, lrpre);
  const dim3 wtGrid(24, 24, 4);
  cvt_wT4_kernel<<<wtGrid, 256, 0, stream>>>(wq, wv, wg, wo, wqT, wvT, wgT, woT);

  const dim3 dualGrid((unsigned)(NTOK / 128), HIDDEN / 128, 2);
  gemm_dual<<<dualGrid, 256, 0, stream>>>(xb, wqT, wvT, xqk, xv);
  convrope_kernel<<<(unsigned)(NTOK * 384 / 256), 256, 0, stream>>>(
      xqk, cqw, cqb, ckw, ckb, (const float2*)ropetab,
      (__hip_bfloat16*)xq, (__hip_bfloat16*)xk);
  fused_scan_gate<<<48 + 1536, 256, 0, stream>>>(
      (const __hip_bfloat16*)xq, (const __hip_bfloat16*)xk,
      (const __hip_bfloat16*)xv, lrpre, lti, tns, tnb, W1g, b1g,
      (__hip_bfloat16*)zOut, xb, wgT, gate);
  stats_epi_kernel<<<(unsigned)(NTOK / 4), 256, 0, stream>>>(zOut, gate, pns, pnb, aout);
  const dim3 gemmGrid((unsigned)(NTOK / 128), HIDDEN / 128);
  gemm_mfma<<<gemmGrid, 256, 0, stream>>>(aout, woT, (void*)out, 2);
}